// Round 5
// baseline (407.023 us; speedup 1.0000x reference)
//
#include <hip/hip_runtime.h>
#include <math.h>

// ---------------------------------------------------------------------------
// VoxelMlp forward, round 12:
//  - fused: REVERT to r9 structure (154.5µs known-best). r10/r11 post-mortem:
//    one-buffer rotation's mid-phase barriers + 192-shuffle in-register dx
//    cost more than the occupancy they bought (163µs @ 40% occ vs 154.5 @ 29%).
//  - prep: transpose_big + pool1 + pool2 merged into ONE trans_pool_kernel
//    (512 blocks x 16^3 voxels): feature read once, G + p2 + p4 produced via
//    LDS f32 accumulation. Kills pool1's 50MB G re-read, pool2's p2 re-read,
//    and 2 launch gaps. Pool sums now use pre-round f32 (closer to ref).
//    Small-ws path: MODE 1 (reads bf16 G) merges pool1+pool2.
// ---------------------------------------------------------------------------

#define N_RAYS 4096
#define ACT_SHIFT_F (-4.595119850134589f)
#define LOG1EM10 (-23.025850929940457f)
#define GV 2097152            // 128^3
#define GVH 1048576           // 128^3 / 2

typedef __attribute__((ext_vector_type(8))) short bf16x8;
typedef __attribute__((ext_vector_type(4))) float f32x4;
#define MFMA16(a, b, c) __builtin_amdgcn_mfma_f32_16x16x32_bf16(a, b, c, 0, 0, 0)

__device__ __forceinline__ short bf16r(float f) {   // RNE f32 -> bf16
    unsigned int u = __float_as_uint(f);
    u += 0x7FFF + ((u >> 16) & 1);
    return (short)(u >> 16);
}
__device__ __forceinline__ float bf2f(unsigned short s) {
    return __uint_as_float(((unsigned int)s) << 16);
}
__device__ __forceinline__ uint2 pack4(float4 x) {
    const unsigned a = (unsigned short)bf16r(x.x), b = (unsigned short)bf16r(x.y);
    const unsigned c = (unsigned short)bf16r(x.z), d = (unsigned short)bf16r(x.w);
    return make_uint2(a | (b << 16), c | (d << 16));
}

// store 4 voxels x 12 bf16 channels (96 B) as 6 uint4
__device__ __forceinline__ void store_vox4(short* __restrict__ dst,
                                           const unsigned short us[4][12]) {
    unsigned w[24];
#pragma unroll
    for (int j = 0; j < 24; j++) {
        const int a = (2 * j) / 12, ca = (2 * j) % 12;
        const int b = (2 * j + 1) / 12, cb = (2 * j + 1) % 12;
        w[j] = (unsigned)us[a][ca] | ((unsigned)us[b][cb] << 16);
    }
    uint4* o = (uint4*)dst;
#pragma unroll
    for (int t = 0; t < 6; t++)
        o[t] = make_uint4(w[4 * t], w[4 * t + 1], w[4 * t + 2], w[4 * t + 3]);
}

// accumulate w * (12 bf16 channels) from channel-last grid
__device__ __forceinline__ void acc12(const short* __restrict__ g, int vox, float w,
                                      float* __restrict__ feat) {
    const ushort4* qp = (const ushort4*)(g + (size_t)vox * 12);
    const ushort4 a = qp[0], b = qp[1], c = qp[2];
    feat[0] += w * bf2f(a.x); feat[1] += w * bf2f(a.y); feat[2]  += w * bf2f(a.z); feat[3]  += w * bf2f(a.w);
    feat[4] += w * bf2f(b.x); feat[5] += w * bf2f(b.y); feat[6]  += w * bf2f(b.z); feat[7]  += w * bf2f(b.w);
    feat[8] += w * bf2f(c.x); feat[9] += w * bf2f(c.y); feat[10] += w * bf2f(c.z); feat[11] += w * bf2f(c.w);
}

// ---------------------------------------------------------------------------
// pack weights (blocks 0..287) + timenet/bias-fold (block 288).
// ---------------------------------------------------------------------------
__global__ __launch_bounds__(256) void pack_timenet_kernel(
    const float* __restrict__ dt_w0, const float* __restrict__ dt_w1,
    const float* __restrict__ fn_w0, const float* __restrict__ dec_wf,
    const float* __restrict__ dec_w0,
    const float* __restrict__ ft,
    const float* __restrict__ tw0, const float* __restrict__ tb0,
    const float* __restrict__ tw1, const float* __restrict__ tb1,
    const float* __restrict__ dt_b0,
    short* __restrict__ dt0h, short* __restrict__ dt0l,
    short* __restrict__ dt1h, short* __restrict__ dt1l,
    short* __restrict__ fnw, short* __restrict__ dwf, short* __restrict__ dw0,
    float* __restrict__ be0)
{
    const int tid = threadIdx.x;
    if (blockIdx.x == 288) {
        __shared__ float sh[128];
        __shared__ float stf[60];
        const float t = ft[0];
        float te[9];
        te[0] = t;
        float fr = 1.f;
#pragma unroll
        for (int f = 0; f < 4; f++) {
            te[1 + f] = __sinf(t * fr);
            te[5 + f] = __cosf(t * fr);
            fr *= 2.f;
        }
        if (tid < 128) {
            float acc = tb0[tid];
#pragma unroll
            for (int k = 0; k < 9; k++) acc = fmaf(te[k], tw0[k * 128 + tid], acc);
            sh[tid] = fmaxf(acc, 0.f);
        }
        __syncthreads();
        if (tid < 60) {
            float acc = tb1[tid];
            for (int k = 0; k < 128; k++) acc = fmaf(sh[k], tw1[k * 60 + tid], acc);
            stf[tid] = acc;
        }
        __syncthreads();
        if (tid < 128) {
            float acc = dt_b0[tid];
            for (int k = 0; k < 60; k++) acc = fmaf(stf[k], dt_w0[(27 + k) * 128 + tid], acc);
            be0[tid] = acc;
        }
        return;
    }
    const int id = blockIdx.x * 256 + tid;   // < 73728
    const float* W; short* dh; short* dl = nullptr; int In, KT, Out, e;
    if (id < 4096)       { W = dt_w0;  dh = dt0h; dl = dt0l; In = 27;  KT = 1; Out = 128; e = id; }
    else if (id < 20480) { W = dt_w1;  dh = dt1h; dl = dt1l; In = 128; KT = 4; Out = 128; e = id - 4096; }
    else if (id < 49152) { W = fn_w0;  dh = fnw;             In = 207; KT = 7; Out = 128; e = id - 20480; }
    else if (id < 65536) { W = dec_wf; dh = dwf;             In = 128; KT = 4; Out = 128; e = id - 49152; }
    else                 { W = dec_w0; dh = dw0;             In = 128; KT = 4; Out = 64;  e = id - 65536; }
    const int j = e & 7, lane = (e >> 3) & 63, rest = e >> 9;
    const int kt = rest % KT, nt = rest / KT;
    const int n = nt * 16 + (lane & 15);
    const int k = kt * 32 + (lane >> 4) * 8 + j;
    const float v = (k < In) ? W[k * Out + n] : 0.f;
    const short hi = bf16r(v);
    dh[e] = hi;
    if (dl) dl[e] = bf16r(v - bf2f((unsigned short)hi));
}

// ---------------------------------------------------------------------------
// SMALL-ws: bounce-compact (4 elems/thread) + 2-pass in-place transpose (4/thr)
// ---------------------------------------------------------------------------
__global__ __launch_bounds__(256) void compact_kernel(
    const float* __restrict__ f, short* __restrict__ B1, short* __restrict__ B2)
{
    const int id = (blockIdx.x * 256 + threadIdx.x) * 4;   // < 9437184
    if (id < 3 * GV) {
        *(uint2*)(B1 + id) = pack4(*(const float4*)(f + id));
    } else {
        const int e = id - 3 * GV;
        const int c = e >> 20;
        const int v2 = e & (GVH - 1);
        *(uint2*)(B2 + e) = pack4(*(const float4*)(f + (size_t)(3 + c) * GV + GVH + v2));
    }
}

__global__ __launch_bounds__(256) void transpose_kernel(
    const float* __restrict__ f, const short* __restrict__ B1,
    const short* __restrict__ B2, short* __restrict__ G, int pass)
{
    const int idx = (blockIdx.x * 256 + threadIdx.x) * 4;  // < GVH
    const int v = pass * GVH + idx;
    unsigned short us[4][12];
#pragma unroll
    for (int c = 0; c < 3; c++) {
        const uint2 b = *(const uint2*)(B1 + c * GV + v);
        us[0][c] = (unsigned short)(b.x & 0xFFFF); us[1][c] = (unsigned short)(b.x >> 16);
        us[2][c] = (unsigned short)(b.y & 0xFFFF); us[3][c] = (unsigned short)(b.y >> 16);
    }
    if (pass == 0) {
#pragma unroll
        for (int c = 3; c < 12; c++) {
            const float4 x = *(const float4*)(f + (size_t)c * GV + v);
            us[0][c] = (unsigned short)bf16r(x.x);
            us[1][c] = (unsigned short)bf16r(x.y);
            us[2][c] = (unsigned short)bf16r(x.z);
            us[3][c] = (unsigned short)bf16r(x.w);
        }
    } else {
#pragma unroll
        for (int c = 3; c < 6; c++) {
            const uint2 b = *(const uint2*)(B2 + (c - 3) * GVH + idx);
            us[0][c] = (unsigned short)(b.x & 0xFFFF); us[1][c] = (unsigned short)(b.x >> 16);
            us[2][c] = (unsigned short)(b.y & 0xFFFF); us[3][c] = (unsigned short)(b.y >> 16);
        }
#pragma unroll
        for (int c = 6; c < 12; c++) {
            const float4 x = *(const float4*)(f + (size_t)c * GV + v);
            us[0][c] = (unsigned short)bf16r(x.x);
            us[1][c] = (unsigned short)bf16r(x.y);
            us[2][c] = (unsigned short)bf16r(x.z);
            us[3][c] = (unsigned short)bf16r(x.w);
        }
    }
    store_vox4(G + (size_t)v * 12, us);
}

// ---------------------------------------------------------------------------
// merged transpose + pool chain. 512 blocks, each owns a 16^3 voxel cube:
// MODE 0: read f32 feature (channel-first), write bf16 G + p2 + p4.
// MODE 1: read bf16 G (channel-last), write p2 + p4 only (small-ws path).
// p2 partials accumulated in LDS f32 (pre-round sums, closer to reference).
// ---------------------------------------------------------------------------
template<int MODE>
__global__ __launch_bounds__(256) void trans_pool_kernel(
    const float* __restrict__ f, const short* __restrict__ Gin,
    short* __restrict__ G, short* __restrict__ p2, short* __restrict__ p4)
{
    __shared__ float sP2[512 * 12];   // 24576 B
    __shared__ float sP4[64 * 12];    // 3072 B
    const int tid = threadIdx.x;
    const int b = blockIdx.x;         // 512
    const int bz = b & 7, by = (b >> 3) & 7, bx = b >> 6;
    for (int i = tid; i < 512 * 12; i += 256) sP2[i] = 0.f;
    for (int i = tid; i < 64 * 12; i += 256) sP4[i] = 0.f;
    __syncthreads();
#pragma unroll
    for (int it = 0; it < 4; it++) {
        const int vg = it * 256 + tid;           // 0..1023 (4-voxel groups)
        const int z4 = (vg & 3) * 4;             // 0,4,8,12
        const int y  = (vg >> 2) & 15;
        const int x  = vg >> 6;
        const int gx = bx * 16 + x, gy = by * 16 + y, gz = bz * 16 + z4;
        const int v = (gx * 128 + gy) * 128 + gz;
        float zp[2][12];
        if (MODE == 0) {
            unsigned short us[4][12];
#pragma unroll
            for (int c = 0; c < 12; c++) {
                const float4 w = *(const float4*)(f + (size_t)c * GV + v);
                us[0][c] = (unsigned short)bf16r(w.x);
                us[1][c] = (unsigned short)bf16r(w.y);
                us[2][c] = (unsigned short)bf16r(w.z);
                us[3][c] = (unsigned short)bf16r(w.w);
                zp[0][c] = w.x + w.y;
                zp[1][c] = w.z + w.w;
            }
            store_vox4(G + (size_t)v * 12, us);
        } else {
            const uint4* R = (const uint4*)(Gin + (size_t)v * 12);
            uint4 U[6];
#pragma unroll
            for (int t = 0; t < 6; t++) U[t] = R[t];
            const unsigned* W = (const unsigned*)U;   // 48 shorts: vox k ch c at k*12+c
#pragma unroll
            for (int zz = 0; zz < 2; zz++)
#pragma unroll
                for (int c = 0; c < 12; c++) {
                    const int s0 = (2 * zz) * 12 + c, s1 = (2 * zz + 1) * 12 + c;
                    const unsigned u0 = W[s0 >> 1], u1 = W[s1 >> 1];
                    zp[zz][c] = bf2f((unsigned short)((s0 & 1) ? (u0 >> 16) : (u0 & 0xFFFF)))
                              + bf2f((unsigned short)((s1 & 1) ? (u1 >> 16) : (u1 & 0xFFFF)));
                }
        }
        const int px = x >> 1, py = y >> 1, pz0 = z4 >> 1;
#pragma unroll
        for (int zz = 0; zz < 2; zz++) {
            float* cell = &sP2[((px * 8 + py) * 8 + pz0 + zz) * 12];
#pragma unroll
            for (int c = 0; c < 12; c++) atomicAdd(&cell[c], zp[zz][c]);
        }
    }
    __syncthreads();
    // p2: 512 cells, 2/thread (z-fastest) -> global + p4 LDS accumulation
#pragma unroll
    for (int cc = 0; cc < 2; cc++) {
        const int cell = tid * 2 + cc;
        const int pz = cell & 7, py = (cell >> 3) & 7, px = cell >> 6;
        float vals[12];
#pragma unroll
        for (int c = 0; c < 12; c++) vals[c] = sP2[cell * 12 + c] * 0.125f;
        const int gp = ((bx * 8 + px) * 64 + by * 8 + py) * 64 + bz * 8 + pz;
        unsigned w6[6];
#pragma unroll
        for (int t = 0; t < 6; t++)
            w6[t] = (unsigned)(unsigned short)bf16r(vals[2 * t]) |
                    ((unsigned)(unsigned short)bf16r(vals[2 * t + 1]) << 16);
        uint2* o = (uint2*)(p2 + (size_t)gp * 12);
        o[0] = make_uint2(w6[0], w6[1]);
        o[1] = make_uint2(w6[2], w6[3]);
        o[2] = make_uint2(w6[4], w6[5]);
        float* c4 = &sP4[(((px >> 1) * 4 + (py >> 1)) * 4 + (pz >> 1)) * 12];
#pragma unroll
        for (int c = 0; c < 12; c++) atomicAdd(&c4[c], vals[c]);
    }
    __syncthreads();
    if (tid < 64) {
        const int pz = tid & 3, py = (tid >> 2) & 3, px = tid >> 4;
        const int cell = (px * 4 + py) * 4 + pz;
        const int gp = ((bx * 4 + px) * 32 + by * 4 + py) * 32 + bz * 4 + pz;
        unsigned w6[6];
#pragma unroll
        for (int t = 0; t < 6; t++) {
            const float a = sP4[cell * 12 + 2 * t] * 0.125f;
            const float b2 = sP4[cell * 12 + 2 * t + 1] * 0.125f;
            w6[t] = (unsigned)(unsigned short)bf16r(a) |
                    ((unsigned)(unsigned short)bf16r(b2) << 16);
        }
        uint2* o = (uint2*)(p4 + (size_t)gp * 12);
        o[0] = make_uint2(w6[0], w6[1]);
        o[1] = make_uint2(w6[2], w6[3]);
        o[2] = make_uint2(w6[4], w6[5]);
    }
}

// ---------------------------------------------------------------------------
// fused (r9 structure): emb -> deform L1/L2 MFMA -> dx -> density+scan |
// gathers -> featurenet -> decoder MFMA -> composite.
// Block = 1 ray, 256 thr, LDS 53760 B -> 3 blocks/CU; VGPRs to ~170 free.
// ---------------------------------------------------------------------------
__global__ __launch_bounds__(256, 3) void fused_kernel(
    const float* __restrict__ ray_pts, const float* __restrict__ viewdirs,
    const float* __restrict__ be0,
    const short* __restrict__ dt0h, const short* __restrict__ dt0l,
    const short* __restrict__ dt1h, const short* __restrict__ dt1l,
    const float* __restrict__ dt_b1,
    const float* __restrict__ dt_wo, const float* __restrict__ dt_bo,
    const float* __restrict__ density,
    const short* __restrict__ g0, const short* __restrict__ p2g, const short* __restrict__ p4g,
    const short* __restrict__ fnw, const float* __restrict__ fn_b0,
    const short* __restrict__ dwf, const float* __restrict__ dec_bf,
    const short* __restrict__ dw0, const float* __restrict__ dec_b0,
    const float* __restrict__ dec_w0, const float* __restrict__ dec_w1,
    const float* __restrict__ dec_b1,
    float* __restrict__ out)
{
    // sA: emb (stride 72) -> h2 f32 (stride 132 f32) -> X (232) -> fl (136)
    // sB: h1 (stride 132) -> hf (stride 132) -> h2dec (stride 72) + sDw stage
    __shared__ __align__(16) short sA[16896];   // 33792 B
    __shared__ __align__(16) short sB[8448];    // 16896 B
    __shared__ float sWo[387];                  // dt_wo + dt_bo
    __shared__ float sSm[256];                  // [p*4+d]: pts_d xyz, d=3: weight
    __shared__ float sBe3[64];                  // folded decoder-L0 bias
    __shared__ float sAiv[1];

    const int tid = threadIdx.x;
    const int r = blockIdx.x;
    const int p0g = r * 64;
    const int lane = tid & 63, wv = tid >> 6;
    const int l15 = lane & 15, q = lane >> 4;
    const int ntb = wv * 2;

    // ---- phase 0: preloads + folded decoder bias + deform embedding ----
    for (int i = tid; i < 384; i += 256) sWo[i] = dt_wo[i];
    if (tid < 3) sWo[384 + tid] = dt_bo[tid];
    if (tid < 64) {   // be3[n] = dec_b0[n] + vemb . dec_w0[128:149][n]
        const float v0 = viewdirs[r * 3], v1 = viewdirs[r * 3 + 1], v2 = viewdirs[r * 3 + 2];
        const float vv[3] = { v0, v1, v2 };
        float ve[21];
        ve[0] = v0; ve[1] = v1; ve[2] = v2;
#pragma unroll
        for (int d = 0; d < 3; d++) {
            float fq = 1.f;
#pragma unroll
            for (int f = 0; f < 3; f++) {
                ve[3 + d * 3 + f]  = __sinf(vv[d] * fq);
                ve[12 + d * 3 + f] = __cosf(vv[d] * fq);
                fq *= 2.f;
            }
        }
        float acc = dec_b0[tid];
#pragma unroll
        for (int k = 0; k < 21; k++) acc = fmaf(ve[k], dec_w0[(128 + k) * 64 + tid], acc);
        sBe3[tid] = acc;
    }
    {   // deform emb: thread (p=lane, grp=wv) -> cols wv*8..wv*8+7 (hi) / +32 (lo)
        const int p = lane;
        const int gp = p0g + p;
        const float pt[3] = { ray_pts[gp * 3], ray_pts[gp * 3 + 1], ray_pts[gp * 3 + 2] };
        float vals[8];
#pragma unroll
        for (int j = 0; j < 8; j++) {
            const int c = wv * 8 + j;
            float v;
            if (c < 3)       v = pt[c];
            else if (c < 15) { const int e = c - 3;  v = __sinf(pt[e >> 2] * (float)(1 << (e & 3))); }
            else if (c < 27) { const int e = c - 15; v = __cosf(pt[e >> 2] * (float)(1 << (e & 3))); }
            else             v = 0.f;
            vals[j] = v;
        }
        bf16x8 hi, lo;
#pragma unroll
        for (int j = 0; j < 8; j++) {
            const short h = bf16r(vals[j]);
            hi[j] = h;
            lo[j] = bf16r(vals[j] - bf2f((unsigned short)h));
        }
        *(bf16x8*)(sA + p * 72 + wv * 8) = hi;
        *(bf16x8*)(sA + p * 72 + 32 + wv * 8) = lo;
    }
    __syncthreads();

    // ---- phase 1: deform L1  K=32, wave covers nt {ntb,ntb+1}, 4 m-tiles ----
    {
        f32x4 acc[4][2];
#pragma unroll
        for (int mt = 0; mt < 4; mt++)
#pragma unroll
            for (int n2 = 0; n2 < 2; n2++) acc[mt][n2] = (f32x4){0.f, 0.f, 0.f, 0.f};
        bf16x8 bh[2], bl[2];
#pragma unroll
        for (int n2 = 0; n2 < 2; n2++) {
            bh[n2] = *(const bf16x8*)(dt0h + ((ntb + n2) * 64 + lane) * 8);
            bl[n2] = *(const bf16x8*)(dt0l + ((ntb + n2) * 64 + lane) * 8);
        }
#pragma unroll
        for (int mt = 0; mt < 4; mt++) {
            const bf16x8 ah = *(const bf16x8*)(sA + (mt * 16 + l15) * 72 + q * 8);
            const bf16x8 al = *(const bf16x8*)(sA + (mt * 16 + l15) * 72 + 32 + q * 8);
#pragma unroll
            for (int n2 = 0; n2 < 2; n2++) {
                acc[mt][n2] = MFMA16(ah, bh[n2], acc[mt][n2]);
                acc[mt][n2] = MFMA16(al, bh[n2], acc[mt][n2]);
                acc[mt][n2] = MFMA16(ah, bl[n2], acc[mt][n2]);
            }
        }
#pragma unroll
        for (int n2 = 0; n2 < 2; n2++) {
            const int n0 = (ntb + n2) * 16 + l15;
            const float bv = be0[n0];
#pragma unroll
            for (int mt = 0; mt < 4; mt++)
#pragma unroll
                for (int rg = 0; rg < 4; rg++)
                    sB[(mt * 16 + q * 4 + rg) * 132 + n0] =
                        bf16r(fmaxf(acc[mt][n2][rg] + bv, 0.f));
        }
    }
    __syncthreads();

    // ---- phase 2: deform L2  K=128 (4 kt), weight-residual split; f32 -> sA ----
    {
        bf16x8 bh[4][2], bl[4][2];
#pragma unroll
        for (int kt = 0; kt < 4; kt++)
#pragma unroll
            for (int n2 = 0; n2 < 2; n2++) {
                bh[kt][n2] = *(const bf16x8*)(dt1h + (((ntb + n2) * 4 + kt) * 64 + lane) * 8);
                bl[kt][n2] = *(const bf16x8*)(dt1l + (((ntb + n2) * 4 + kt) * 64 + lane) * 8);
            }
        f32x4 acc[4][2];
#pragma unroll
        for (int mt = 0; mt < 4; mt++)
#pragma unroll
            for (int n2 = 0; n2 < 2; n2++) acc[mt][n2] = (f32x4){0.f, 0.f, 0.f, 0.f};
#pragma unroll
        for (int kt = 0; kt < 4; kt++) {
            bf16x8 a[4];
#pragma unroll
            for (int mt = 0; mt < 4; mt++)
                a[mt] = *(const bf16x8*)(sB + (mt * 16 + l15) * 132 + (kt * 4 + q) * 8);
#pragma unroll
            for (int n2 = 0; n2 < 2; n2++) {
#pragma unroll
                for (int mt = 0; mt < 4; mt++) {
                    acc[mt][n2] = MFMA16(a[mt], bh[kt][n2], acc[mt][n2]);
                    acc[mt][n2] = MFMA16(a[mt], bl[kt][n2], acc[mt][n2]);
                }
            }
        }
        float* sF = (float*)sA;
#pragma unroll
        for (int n2 = 0; n2 < 2; n2++) {
            const int n0 = (ntb + n2) * 16 + l15;
            const float bv = dt_b1[n0];
#pragma unroll
            for (int mt = 0; mt < 4; mt++)
#pragma unroll
                for (int rg = 0; rg < 4; rg++)
                    sF[(mt * 16 + q * 4 + rg) * 132 + n0] = fmaxf(acc[mt][n2][rg] + bv, 0.f);
        }
    }
    __syncthreads();

    // ---- phase 3a: dx (192 threads: 64 pts x 3 dims) -> pts_d to sSm ----
    if (tid < 192) {
        const int p = tid & 63, d = tid >> 6;
        const float* sF = (const float*)sA;
        float a = sWo[384 + d];
        for (int k = 0; k < 128; k += 4) {
            const float4 h = *(const float4*)&sF[p * 132 + k];
            a += h.x * sWo[k * 3 + d] + h.y * sWo[(k + 1) * 3 + d]
               + h.z * sWo[(k + 2) * 3 + d] + h.w * sWo[(k + 3) * 3 + d];
        }
        sSm[p * 4 + d] = ray_pts[(p0g + p) * 3 + d] + a;
    }
    __syncthreads();

    // ---- phase 3b: wave0 = density+alpha+scan+pts-emb; waves1-3 = gathers ----
    {
        const int p = lane;
        const float pd[3] = { sSm[p * 4], sSm[p * 4 + 1], sSm[p * 4 + 2] };
        if (wv == 0) {
            int i0[3]; float fr[3];
#pragma unroll
            for (int d = 0; d < 3; d++) {
                float t = (pd[d] + 1.f) * 63.5f;
                t = fminf(fmaxf(t, 0.f), 127.f - 1e-4f);
                const int i = (int)t;
                i0[d] = i; fr[d] = t - (float)i;
            }
            float dens = 0.f;
#pragma unroll
            for (int dx = 0; dx < 2; dx++)
#pragma unroll
                for (int dy = 0; dy < 2; dy++) {
                    const float wxy = (dx ? fr[0] : 1.f - fr[0]) * (dy ? fr[1] : 1.f - fr[1]);
                    const float* b = &density[((i0[0] + dx) * 128 + i0[1] + dy) * 128 + i0[2]];
                    dens += wxy * ((1.f - fr[2]) * b[0] + fr[2] * b[1]);
                }
            const float xs = dens + ACT_SHIFT_F;
            const float sp = fmaxf(xs, 0.f) + __logf(1.f + __expf(-fabsf(xs)));
            const float alpha = 1.f - __expf(-sp * 0.5f);
            const float lm = fmaxf(-sp * 0.5f, LOG1EM10);
            float v = lm;
#pragma unroll
            for (int d = 1; d < 64; d <<= 1) {
                const float o = __shfl_up(v, d);
                if (p >= d) v += o;
            }
            sSm[p * 4 + 3] = alpha * __expf(v - lm);
            if (p == 63) sAiv[0] = __expf(v);
            // pts_d embedding -> X cols 180..206, zero pad 207..223
            sA[p * 232 + 180] = bf16r(pd[0]);
            sA[p * 232 + 181] = bf16r(pd[1]);
            sA[p * 232 + 182] = bf16r(pd[2]);
#pragma unroll
            for (int d = 0; d < 3; d++) {
                float sv = __sinf(pd[d]), cv = __cosf(pd[d]);
#pragma unroll
                for (int f = 0; f < 4; f++) {
                    sA[p * 232 + 183 + d * 4 + f] = bf16r(sv);
                    sA[p * 232 + 195 + d * 4 + f] = bf16r(cv);
                    const float ns = 2.f * sv * cv;
                    cv = 1.f - 2.f * sv * sv;      // cos(2t) = 1 - 2 sin^2 t
                    sv = ns;                        // sin(2t) = 2 sin t cos t
                }
            }
            sA[p * 232 + 207] = 0;
            const bf16x8 zv = { 0, 0, 0, 0, 0, 0, 0, 0 };
            *(bf16x8*)(sA + p * 232 + 208) = zv;
            *(bf16x8*)(sA + p * 232 + 216) = zv;
        } else {
            const int s = wv - 1;
            const int n = (s == 0) ? 128 : ((s == 1) ? 64 : 32);
            const short* g = (s == 0) ? g0 : ((s == 1) ? p2g : p4g);
            const float dim = (float)(n - 1);
            int i0[3]; float fr[3];
#pragma unroll
            for (int d = 0; d < 3; d++) {
                float t = (pd[d] + 1.f) * 0.5f * dim;
                t = fminf(fmaxf(t, 0.f), dim - 1e-4f);
                const int i = (int)t;
                i0[d] = i; fr[d] = t - (float)i;
            }
            float feat[12];
#pragma unroll
            for (int c = 0; c < 12; c++) feat[c] = 0.f;
#pragma unroll
            for (int dx = 0; dx < 2; dx++)
#pragma unroll
                for (int dy = 0; dy < 2; dy++)
#pragma unroll
                    for (int dz = 0; dz < 2; dz++) {
                        const float wc = (dx ? fr[0] : 1.f - fr[0]) *
                                         (dy ? fr[1] : 1.f - fr[1]) *
                                         (dz ? fr[2] : 1.f - fr[2]);
                        const int vox = ((i0[0] + dx) * n + i0[1] + dy) * n + i0[2] + dz;
                        acc12(g, vox, wc, feat);
                    }
#pragma unroll
            for (int c = 0; c < 12; c++) {
                const float v = feat[c];
                const int j = s * 12 + c;
                sA[p * 232 + j] = bf16r(v);
                const float sv = __sinf(v), cv = __cosf(v);
                const unsigned s1 = (unsigned short)bf16r(sv);
                const unsigned s2 = (unsigned short)bf16r(2.f * sv * cv);
                const unsigned c1 = (unsigned short)bf16r(cv);
                const unsigned c2 = (unsigned short)bf16r(1.f - 2.f * sv * sv);
                *(unsigned*)(sA + p * 232 + 36 + 2 * j)  = s1 | (s2 << 16);
                *(unsigned*)(sA + p * 232 + 108 + 2 * j) = c1 | (c2 << 16);
            }
        }
    }
    __syncthreads();

    // ---- phase 4: featurenet  K=224 (7 kt), relu -> sB (stride 132) ----
    {
        bf16x8 b[7][2];
#pragma unroll
        for (int kt = 0; kt < 7; kt++)
#pragma unroll
            for (int n2 = 0; n2 < 2; n2++)
                b[kt][n2] = *(const bf16x8*)(fnw + (((ntb + n2) * 7 + kt) * 64 + lane) * 8);
        f32x4 acc[4][2];
#pragma unroll
        for (int mt = 0; mt < 4; mt++)
#pragma unroll
            for (int n2 = 0; n2 < 2; n2++) acc[mt][n2] = (f32x4){0.f, 0.f, 0.f, 0.f};
#pragma unroll
        for (int kt = 0; kt < 7; kt++) {
            bf16x8 a[4];
#pragma unroll
            for (int mt = 0; mt < 4; mt++)
                a[mt] = *(const bf16x8*)(sA + (mt * 16 + l15) * 232 + (kt * 4 + q) * 8);
#pragma unroll
            for (int n2 = 0; n2 < 2; n2++) {
#pragma unroll
                for (int mt = 0; mt < 4; mt++) acc[mt][n2] = MFMA16(a[mt], b[kt][n2], acc[mt][n2]);
            }
        }
#pragma unroll
        for (int n2 = 0; n2 < 2; n2++) {
            const int n0 = (ntb + n2) * 16 + l15;
            const float bv = fn_b0[n0];
#pragma unroll
            for (int mt = 0; mt < 4; mt++)
#pragma unroll
                for (int rg = 0; rg < 4; rg++)
                    sB[(mt * 16 + q * 4 + rg) * 132 + n0] = bf16r(fmaxf(acc[mt][n2][rg] + bv, 0.f));
        }
    }
    __syncthreads();

    // ---- phase 5: dec_wf  K=128 (4 kt), no relu -> sA (stride 136) ----
    {
        bf16x8 b[4][2];
#pragma unroll
        for (int kt = 0; kt < 4; kt++)
#pragma unroll
            for (int n2 = 0; n2 < 2; n2++)
                b[kt][n2] = *(const bf16x8*)(dwf + (((ntb + n2) * 4 + kt) * 64 + lane) * 8);
        f32x4 acc[4][2];
#pragma unroll
        for (int mt = 0; mt < 4; mt++)
#pragma unroll
            for (int n2 = 0; n2 < 2; n2++) acc[mt][n2] = (f32x4){0.f, 0.f, 0.f, 0.f};
#pragma unroll
        for (int kt = 0; kt < 4; kt++) {
            bf16x8 a[4];
#pragma unroll
            for (int mt = 0; mt < 4; mt++)
                a[mt] = *(const bf16x8*)(sB + (mt * 16 + l15) * 132 + (kt * 4 + q) * 8);
#pragma unroll
            for (int n2 = 0; n2 < 2; n2++) {
#pragma unroll
                for (int mt = 0; mt < 4; mt++) acc[mt][n2] = MFMA16(a[mt], b[kt][n2], acc[mt][n2]);
            }
        }
#pragma unroll
        for (int n2 = 0; n2 < 2; n2++) {
            const int n0 = (ntb + n2) * 16 + l15;
            const float bv = dec_bf[n0];
#pragma unroll
            for (int mt = 0; mt < 4; mt++)
#pragma unroll
                for (int rg = 0; rg < 4; rg++)
                    sA[(mt * 16 + q * 4 + rg) * 136 + n0] = bf16r(acc[mt][n2][rg] + bv);
        }
    }
    __syncthreads();

    // ---- phase 6: dec_w0  K=128 (vemb folded in sBe3), N=64 (1 nt/wave);
    //      also stage dec_w1/dec_b1 into dead sB space [short 4608..] ----
    {
        float* sDw = (float*)sB + 2304;   // byte 9216, beyond h2dec (4608 shorts)
        for (int i = tid; i < 195; i += 256)
            sDw[i] = (i < 192) ? dec_w1[i] : dec_b1[i - 192];
        bf16x8 b[4];
#pragma unroll
        for (int kt = 0; kt < 4; kt++)
            b[kt] = *(const bf16x8*)(dw0 + ((wv * 4 + kt) * 64 + lane) * 8);
        f32x4 acc[4];
#pragma unroll
        for (int mt = 0; mt < 4; mt++) acc[mt] = (f32x4){0.f, 0.f, 0.f, 0.f};
#pragma unroll
        for (int kt = 0; kt < 4; kt++) {
            bf16x8 a[4];
#pragma unroll
            for (int mt = 0; mt < 4; mt++)
                a[mt] = *(const bf16x8*)(sA + (mt * 16 + l15) * 136 + (kt * 4 + q) * 8);
#pragma unroll
            for (int mt = 0; mt < 4; mt++) acc[mt] = MFMA16(a[mt], b[kt], acc[mt]);
        }
        const int n0 = wv * 16 + l15;
        const float bv = sBe3[n0];
#pragma unroll
        for (int mt = 0; mt < 4; mt++)
#pragma unroll
            for (int rg = 0; rg < 4; rg++)
                sB[(mt * 16 + q * 4 + rg) * 72 + n0] = bf16r(fmaxf(acc[mt][rg] + bv, 0.f));
    }
    __syncthreads();

    // ---- phase 7: 64->3, sigmoid, weight, wave-reduce, store ----
    if (tid < 64) {
        const int p = tid;
        const float* sDw = (const float*)sB + 2304;
        float a0 = sDw[192], a1 = sDw[193], a2 = sDw[194];
#pragma unroll
        for (int g = 0; g < 8; g++) {
            const bf16x8 h = *(const bf16x8*)(sB + p * 72 + g * 8);
#pragma unroll
            for (int j = 0; j < 8; j++) {
                const float f = bf2f((unsigned short)h[j]);
                const int k = g * 8 + j;
                a0 += f * sDw[k * 3];
                a1 += f * sDw[k * 3 + 1];
                a2 += f * sDw[k * 3 + 2];
            }
        }
        const float wgt = sSm[p * 4 + 3];
        float r0 = wgt / (1.f + __expf(-a0));
        float r1 = wgt / (1.f + __expf(-a1));
        float r2 = wgt / (1.f + __expf(-a2));
#pragma unroll
        for (int off = 32; off >= 1; off >>= 1) {
            r0 += __shfl_down(r0, off);
            r1 += __shfl_down(r1, off);
            r2 += __shfl_down(r2, off);
        }
        if (p == 0) {
            const float av = sAiv[0];
            out[r * 3]     = r0 + av;
            out[r * 3 + 1] = r1 + av;
            out[r * 3 + 2] = r2 + av;
        }
    }
}

// ---------------------------------------------------------------------------
extern "C" void kernel_launch(void* const* d_in, const int* in_sizes, int n_in,
                              void* d_out, int out_size, void* d_ws, size_t ws_size,
                              hipStream_t stream)
{
    const float* ray_pts    = (const float*)d_in[0];
    const float* viewdirs   = (const float*)d_in[1];
    const float* frame_time = (const float*)d_in[2];
    float*       feature    = (float*)d_in[3];          // clobbered only in small-ws path
    const float* density    = (const float*)d_in[4];
    const float* tn_w0 = (const float*)d_in[5];  const float* tn_b0 = (const float*)d_in[6];
    const float* tn_w1 = (const float*)d_in[7];  const float* tn_b1 = (const float*)d_in[8];
    const float* dt_w0 = (const float*)d_in[9];  const float* dt_b0 = (const float*)d_in[10];
    const float* dt_w1 = (const float*)d_in[11]; const float* dt_b1 = (const float*)d_in[12];
    const float* dt_wo = (const float*)d_in[13]; const float* dt_bo = (const float*)d_in[14];
    const float* fn_w0 = (const float*)d_in[15]; const float* fn_b0 = (const float*)d_in[16];
    const float* dec_wf = (const float*)d_in[17]; const float* dec_bf = (const float*)d_in[18];
    const float* dec_w0 = (const float*)d_in[19]; const float* dec_b0 = (const float*)d_in[20];
    const float* dec_w1 = (const float*)d_in[21]; const float* dec_b1 = (const float*)d_in[22];
    (void)in_sizes; (void)n_in; (void)out_size;

    char* ws = (char*)d_ws;
    const bool big = ws_size >= (size_t)57598464;

    short *G, *p2, *p4, *B1 = nullptr, *B2 = nullptr;
    float* be0; short *dt0h, *dt0l, *dt1h, *dt1l, *fnw, *dwf, *dw0;

    if (big) {
        G    = (short*)(ws + 0);            // 128^3*12 bf16 = 50331648 B
        p2   = (short*)(ws + 50331648);
        p4   = (short*)(ws + 56623104);
        be0  = (float*)(ws + 57409536);
        dt0h = (short*)(ws + 57410048);
        dt0l = (short*)(ws + 57418240);
        dt1h = (short*)(ws + 57426432);
        dt1l = (short*)(ws + 57459200);
        fnw  = (short*)(ws + 57491968);
        dwf  = (short*)(ws + 57549312);
        dw0  = (short*)(ws + 57582080);     // ends 57598464
    } else {
        G    = (short*)feature;             // in-place in feature buffer
        B1   = (short*)(ws + 0);            // 3*GV bf16
        B2   = (short*)(ws + 12582912);     // 3*GVH bf16
        p2   = (short*)(ws + 0);            // reuse after transpose
        p4   = (short*)(ws + 6291456);
        be0  = (float*)(ws + 18874368);
        dt0h = (short*)(ws + 18874880);
        dt0l = (short*)(ws + 18883072);
        dt1h = (short*)(ws + 18891264);
        dt1l = (short*)(ws + 18924032);
        fnw  = (short*)(ws + 18956800);
        dwf  = (short*)(ws + 19014144);
        dw0  = (short*)(ws + 19046912);     // ends 19063296
    }

    pack_timenet_kernel<<<289, 256, 0, stream>>>(
        dt_w0, dt_w1, fn_w0, dec_wf, dec_w0,
        frame_time, tn_w0, tn_b0, tn_w1, tn_b1, dt_b0,
        dt0h, dt0l, dt1h, dt1l, fnw, dwf, dw0, be0);

    if (big) {
        trans_pool_kernel<0><<<512, 256, 0, stream>>>(feature, nullptr, G, p2, p4);
    } else {
        compact_kernel<<<9216, 256, 0, stream>>>(feature, B1, B2);
        transpose_kernel<<<1024, 256, 0, stream>>>(feature, B1, B2, G, 0);
        transpose_kernel<<<1024, 256, 0, stream>>>(feature, B1, B2, G, 1);
        trans_pool_kernel<1><<<512, 256, 0, stream>>>(nullptr, G, nullptr, p2, p4);
    }

    fused_kernel<<<4096, 256, 0, stream>>>(ray_pts, viewdirs, be0,
                                           dt0h, dt0l, dt1h, dt1l, dt_b1,
                                           dt_wo, dt_bo, density,
                                           G, p2, p4,
                                           fnw, fn_b0, dwf, dec_bf,
                                           dw0, dec_b0, dec_w0, dec_w1, dec_b1,
                                           (float*)d_out);
}

// Round 6
// 375.144 us; speedup vs baseline: 1.0850x; 1.0850x over previous
//
#include <hip/hip_runtime.h>
#include <math.h>

// ---------------------------------------------------------------------------
// VoxelMlp forward, round 13:
//  - prep: REVERT r12's merged trans_pool (atomicAdd LDS accumulation cost
//    +30µs vs separate kernels). Back to r9/r2 chain: transpose_big 2048 +
//    pool<1> 1024 + pool<1> 128 (best measured total 376.7).
//  - fused (r9 structure, 154.5µs): + cross-barrier register prefetch of
//    weight fragments: fnw loaded during phase 2, dwf during phase 3b
//    (hidden under gather latency), dw0 during phase 4. Removes the
//    L2-latency burst at each MFMA phase entry. VGPR headroom at 3 blk/CU
//    is ~170; estimated peak ~135.
// ---------------------------------------------------------------------------

#define N_RAYS 4096
#define ACT_SHIFT_F (-4.595119850134589f)
#define LOG1EM10 (-23.025850929940457f)
#define GV 2097152            // 128^3
#define GVH 1048576           // 128^3 / 2

typedef __attribute__((ext_vector_type(8))) short bf16x8;
typedef __attribute__((ext_vector_type(4))) float f32x4;
#define MFMA16(a, b, c) __builtin_amdgcn_mfma_f32_16x16x32_bf16(a, b, c, 0, 0, 0)

__device__ __forceinline__ short bf16r(float f) {   // RNE f32 -> bf16
    unsigned int u = __float_as_uint(f);
    u += 0x7FFF + ((u >> 16) & 1);
    return (short)(u >> 16);
}
__device__ __forceinline__ float bf2f(unsigned short s) {
    return __uint_as_float(((unsigned int)s) << 16);
}
__device__ __forceinline__ uint2 pack4(float4 x) {
    const unsigned a = (unsigned short)bf16r(x.x), b = (unsigned short)bf16r(x.y);
    const unsigned c = (unsigned short)bf16r(x.z), d = (unsigned short)bf16r(x.w);
    return make_uint2(a | (b << 16), c | (d << 16));
}

// store 4 voxels x 12 bf16 channels (96 B) as 6 uint4
__device__ __forceinline__ void store_vox4(short* __restrict__ dst,
                                           const unsigned short us[4][12]) {
    unsigned w[24];
#pragma unroll
    for (int j = 0; j < 24; j++) {
        const int a = (2 * j) / 12, ca = (2 * j) % 12;
        const int b = (2 * j + 1) / 12, cb = (2 * j + 1) % 12;
        w[j] = (unsigned)us[a][ca] | ((unsigned)us[b][cb] << 16);
    }
    uint4* o = (uint4*)dst;
#pragma unroll
    for (int t = 0; t < 6; t++)
        o[t] = make_uint4(w[4 * t], w[4 * t + 1], w[4 * t + 2], w[4 * t + 3]);
}

// accumulate w * (12 bf16 channels) from channel-last grid
__device__ __forceinline__ void acc12(const short* __restrict__ g, int vox, float w,
                                      float* __restrict__ feat) {
    const ushort4* qp = (const ushort4*)(g + (size_t)vox * 12);
    const ushort4 a = qp[0], b = qp[1], c = qp[2];
    feat[0] += w * bf2f(a.x); feat[1] += w * bf2f(a.y); feat[2]  += w * bf2f(a.z); feat[3]  += w * bf2f(a.w);
    feat[4] += w * bf2f(b.x); feat[5] += w * bf2f(b.y); feat[6]  += w * bf2f(b.z); feat[7]  += w * bf2f(b.w);
    feat[8] += w * bf2f(c.x); feat[9] += w * bf2f(c.y); feat[10] += w * bf2f(c.z); feat[11] += w * bf2f(c.w);
}

// ---------------------------------------------------------------------------
// pack weights (blocks 0..287) + timenet/bias-fold (block 288).
// ---------------------------------------------------------------------------
__global__ __launch_bounds__(256) void pack_timenet_kernel(
    const float* __restrict__ dt_w0, const float* __restrict__ dt_w1,
    const float* __restrict__ fn_w0, const float* __restrict__ dec_wf,
    const float* __restrict__ dec_w0,
    const float* __restrict__ ft,
    const float* __restrict__ tw0, const float* __restrict__ tb0,
    const float* __restrict__ tw1, const float* __restrict__ tb1,
    const float* __restrict__ dt_b0,
    short* __restrict__ dt0h, short* __restrict__ dt0l,
    short* __restrict__ dt1h, short* __restrict__ dt1l,
    short* __restrict__ fnw, short* __restrict__ dwf, short* __restrict__ dw0,
    float* __restrict__ be0)
{
    const int tid = threadIdx.x;
    if (blockIdx.x == 288) {
        __shared__ float sh[128];
        __shared__ float stf[60];
        const float t = ft[0];
        float te[9];
        te[0] = t;
        float fr = 1.f;
#pragma unroll
        for (int f = 0; f < 4; f++) {
            te[1 + f] = __sinf(t * fr);
            te[5 + f] = __cosf(t * fr);
            fr *= 2.f;
        }
        if (tid < 128) {
            float acc = tb0[tid];
#pragma unroll
            for (int k = 0; k < 9; k++) acc = fmaf(te[k], tw0[k * 128 + tid], acc);
            sh[tid] = fmaxf(acc, 0.f);
        }
        __syncthreads();
        if (tid < 60) {
            float acc = tb1[tid];
            for (int k = 0; k < 128; k++) acc = fmaf(sh[k], tw1[k * 60 + tid], acc);
            stf[tid] = acc;
        }
        __syncthreads();
        if (tid < 128) {
            float acc = dt_b0[tid];
            for (int k = 0; k < 60; k++) acc = fmaf(stf[k], dt_w0[(27 + k) * 128 + tid], acc);
            be0[tid] = acc;
        }
        return;
    }
    const int id = blockIdx.x * 256 + tid;   // < 73728
    const float* W; short* dh; short* dl = nullptr; int In, KT, Out, e;
    if (id < 4096)       { W = dt_w0;  dh = dt0h; dl = dt0l; In = 27;  KT = 1; Out = 128; e = id; }
    else if (id < 20480) { W = dt_w1;  dh = dt1h; dl = dt1l; In = 128; KT = 4; Out = 128; e = id - 4096; }
    else if (id < 49152) { W = fn_w0;  dh = fnw;             In = 207; KT = 7; Out = 128; e = id - 20480; }
    else if (id < 65536) { W = dec_wf; dh = dwf;             In = 128; KT = 4; Out = 128; e = id - 49152; }
    else                 { W = dec_w0; dh = dw0;             In = 128; KT = 4; Out = 64;  e = id - 65536; }
    const int j = e & 7, lane = (e >> 3) & 63, rest = e >> 9;
    const int kt = rest % KT, nt = rest / KT;
    const int n = nt * 16 + (lane & 15);
    const int k = kt * 32 + (lane >> 4) * 8 + j;
    const float v = (k < In) ? W[k * Out + n] : 0.f;
    const short hi = bf16r(v);
    dh[e] = hi;
    if (dl) dl[e] = bf16r(v - bf2f((unsigned short)hi));
}

// ---------------------------------------------------------------------------
// BIG path: direct transpose, 4 voxels/thread
// ---------------------------------------------------------------------------
__global__ __launch_bounds__(256) void transpose_big_kernel(
    const float* __restrict__ f, short* __restrict__ G)
{
    const int v = (blockIdx.x * 256 + threadIdx.x) * 4;   // < GV
    unsigned short us[4][12];
#pragma unroll
    for (int c = 0; c < 12; c++) {
        const float4 x = *(const float4*)(f + (size_t)c * GV + v);
        us[0][c] = (unsigned short)bf16r(x.x);
        us[1][c] = (unsigned short)bf16r(x.y);
        us[2][c] = (unsigned short)bf16r(x.z);
        us[3][c] = (unsigned short)bf16r(x.w);
    }
    store_vox4(G + (size_t)v * 12, us);
}

// ---------------------------------------------------------------------------
// SMALL-ws: bounce-compact (4 elems/thread) + 2-pass in-place transpose (4/thr)
// ---------------------------------------------------------------------------
__global__ __launch_bounds__(256) void compact_kernel(
    const float* __restrict__ f, short* __restrict__ B1, short* __restrict__ B2)
{
    const int id = (blockIdx.x * 256 + threadIdx.x) * 4;   // < 9437184
    if (id < 3 * GV) {
        *(uint2*)(B1 + id) = pack4(*(const float4*)(f + id));
    } else {
        const int e = id - 3 * GV;
        const int c = e >> 20;
        const int v2 = e & (GVH - 1);
        *(uint2*)(B2 + e) = pack4(*(const float4*)(f + (size_t)(3 + c) * GV + GVH + v2));
    }
}

__global__ __launch_bounds__(256) void transpose_kernel(
    const float* __restrict__ f, const short* __restrict__ B1,
    const short* __restrict__ B2, short* __restrict__ G, int pass)
{
    const int idx = (blockIdx.x * 256 + threadIdx.x) * 4;  // < GVH
    const int v = pass * GVH + idx;
    unsigned short us[4][12];
#pragma unroll
    for (int c = 0; c < 3; c++) {
        const uint2 b = *(const uint2*)(B1 + c * GV + v);
        us[0][c] = (unsigned short)(b.x & 0xFFFF); us[1][c] = (unsigned short)(b.x >> 16);
        us[2][c] = (unsigned short)(b.y & 0xFFFF); us[3][c] = (unsigned short)(b.y >> 16);
    }
    if (pass == 0) {
#pragma unroll
        for (int c = 3; c < 12; c++) {
            const float4 x = *(const float4*)(f + (size_t)c * GV + v);
            us[0][c] = (unsigned short)bf16r(x.x);
            us[1][c] = (unsigned short)bf16r(x.y);
            us[2][c] = (unsigned short)bf16r(x.z);
            us[3][c] = (unsigned short)bf16r(x.w);
        }
    } else {
#pragma unroll
        for (int c = 3; c < 6; c++) {
            const uint2 b = *(const uint2*)(B2 + (c - 3) * GVH + idx);
            us[0][c] = (unsigned short)(b.x & 0xFFFF); us[1][c] = (unsigned short)(b.x >> 16);
            us[2][c] = (unsigned short)(b.y & 0xFFFF); us[3][c] = (unsigned short)(b.y >> 16);
        }
#pragma unroll
        for (int c = 6; c < 12; c++) {
            const float4 x = *(const float4*)(f + (size_t)c * GV + v);
            us[0][c] = (unsigned short)bf16r(x.x);
            us[1][c] = (unsigned short)bf16r(x.y);
            us[2][c] = (unsigned short)bf16r(x.z);
            us[3][c] = (unsigned short)bf16r(x.w);
        }
    }
    store_vox4(G + (size_t)v * 12, us);
}

// ---------------------------------------------------------------------------
// 2x avg-pool, channel-last bf16 -> bf16, VPER output voxels/thread.
// VPER=1 -> 1024 blocks (64^3) / 128 blocks (32^3): latency hiding via grid.
// ---------------------------------------------------------------------------
template<int VPER>
__global__ __launch_bounds__(256) void pool_kernel_t(
    const short* __restrict__ src, short* __restrict__ dst, int so)
{
    const int nout = 1 << so, nin = nout << 1;
    const int idx = (blockIdx.x * 256 + threadIdx.x) * VPER;
    const int z0 = idx & (nout - 1), y = (idx >> so) & (nout - 1), x = idx >> (2 * so);
    float acc[VPER][12];
#pragma unroll
    for (int k = 0; k < VPER; k++)
#pragma unroll
        for (int c = 0; c < 12; c++) acc[k][c] = 0.f;
#pragma unroll
    for (int i = 0; i < 2; i++)
#pragma unroll
        for (int j = 0; j < 2; j++) {
            const size_t roff = (size_t)(((2 * x + i) * nin + (2 * y + j)) * nin + 2 * z0) * 12;
            const uint4* R4 = (const uint4*)(src + roff);
            uint4 U[3 * VPER];
#pragma unroll
            for (int t = 0; t < 3 * VPER; t++) U[t] = R4[t];
            const unsigned* W = (const unsigned*)U;
#pragma unroll
            for (int k = 0; k < VPER; k++)
#pragma unroll
                for (int c = 0; c < 12; c++) {
                    const int s0 = 24 * k + c, s1 = 24 * k + 12 + c;
                    const unsigned u0 = W[s0 >> 1], u1 = W[s1 >> 1];
                    acc[k][c] += bf2f((unsigned short)((s0 & 1) ? (u0 >> 16) : (u0 & 0xFFFF)))
                               + bf2f((unsigned short)((s1 & 1) ? (u1 >> 16) : (u1 & 0xFFFF)));
                }
        }
    unsigned w[6 * VPER];
#pragma unroll
    for (int t = 0; t < 6 * VPER; t++) {
        const int e0 = 2 * t, e1 = 2 * t + 1;
        const unsigned short a = (unsigned short)bf16r(acc[e0 / 12][e0 % 12] * 0.125f);
        const unsigned short b = (unsigned short)bf16r(acc[e1 / 12][e1 % 12] * 0.125f);
        w[t] = (unsigned)a | ((unsigned)b << 16);
    }
    uint2* o = (uint2*)(dst + (size_t)idx * 12);
#pragma unroll
    for (int t = 0; t < 3 * VPER; t++)
        o[t] = make_uint2(w[2 * t], w[2 * t + 1]);
}

// ---------------------------------------------------------------------------
// fused (r9 structure + cross-barrier weight prefetch): emb -> deform L1/L2
// MFMA -> dx -> density+scan | gathers -> featurenet -> decoder MFMA ->
// composite.  Block = 1 ray, 256 thr, LDS 53760 B -> 3 blocks/CU.
// ---------------------------------------------------------------------------
__global__ __launch_bounds__(256, 3) void fused_kernel(
    const float* __restrict__ ray_pts, const float* __restrict__ viewdirs,
    const float* __restrict__ be0,
    const short* __restrict__ dt0h, const short* __restrict__ dt0l,
    const short* __restrict__ dt1h, const short* __restrict__ dt1l,
    const float* __restrict__ dt_b1,
    const float* __restrict__ dt_wo, const float* __restrict__ dt_bo,
    const float* __restrict__ density,
    const short* __restrict__ g0, const short* __restrict__ p2g, const short* __restrict__ p4g,
    const short* __restrict__ fnw, const float* __restrict__ fn_b0,
    const short* __restrict__ dwf, const float* __restrict__ dec_bf,
    const short* __restrict__ dw0, const float* __restrict__ dec_b0,
    const float* __restrict__ dec_w0, const float* __restrict__ dec_w1,
    const float* __restrict__ dec_b1,
    float* __restrict__ out)
{
    // sA: emb (stride 72) -> h2 f32 (stride 132 f32) -> X (232) -> fl (136)
    // sB: h1 (stride 132) -> hf (stride 132) -> h2dec (stride 72) + sDw stage
    __shared__ __align__(16) short sA[16896];   // 33792 B
    __shared__ __align__(16) short sB[8448];    // 16896 B
    __shared__ float sWo[387];                  // dt_wo + dt_bo
    __shared__ float sSm[256];                  // [p*4+d]: pts_d xyz, d=3: weight
    __shared__ float sBe3[64];                  // folded decoder-L0 bias
    __shared__ float sAiv[1];

    const int tid = threadIdx.x;
    const int r = blockIdx.x;
    const int p0g = r * 64;
    const int lane = tid & 63, wv = tid >> 6;
    const int l15 = lane & 15, q = lane >> 4;
    const int ntb = wv * 2;

    // cross-barrier prefetched weight fragments
    bf16x8 pf4[7][2];   // fnw   (loaded during phase 2)
    bf16x8 pf5[4][2];   // dwf   (loaded during phase 3b)
    bf16x8 pf6[4];      // dw0   (loaded during phase 4)

    // ---- phase 0: preloads + folded decoder bias + deform embedding ----
    for (int i = tid; i < 384; i += 256) sWo[i] = dt_wo[i];
    if (tid < 3) sWo[384 + tid] = dt_bo[tid];
    if (tid < 64) {   // be3[n] = dec_b0[n] + vemb . dec_w0[128:149][n]
        const float v0 = viewdirs[r * 3], v1 = viewdirs[r * 3 + 1], v2 = viewdirs[r * 3 + 2];
        const float vv[3] = { v0, v1, v2 };
        float ve[21];
        ve[0] = v0; ve[1] = v1; ve[2] = v2;
#pragma unroll
        for (int d = 0; d < 3; d++) {
            float fq = 1.f;
#pragma unroll
            for (int f = 0; f < 3; f++) {
                ve[3 + d * 3 + f]  = __sinf(vv[d] * fq);
                ve[12 + d * 3 + f] = __cosf(vv[d] * fq);
                fq *= 2.f;
            }
        }
        float acc = dec_b0[tid];
#pragma unroll
        for (int k = 0; k < 21; k++) acc = fmaf(ve[k], dec_w0[(128 + k) * 64 + tid], acc);
        sBe3[tid] = acc;
    }
    {   // deform emb: thread (p=lane, grp=wv) -> cols wv*8..wv*8+7 (hi) / +32 (lo)
        const int p = lane;
        const int gp = p0g + p;
        const float pt[3] = { ray_pts[gp * 3], ray_pts[gp * 3 + 1], ray_pts[gp * 3 + 2] };
        float vals[8];
#pragma unroll
        for (int j = 0; j < 8; j++) {
            const int c = wv * 8 + j;
            float v;
            if (c < 3)       v = pt[c];
            else if (c < 15) { const int e = c - 3;  v = __sinf(pt[e >> 2] * (float)(1 << (e & 3))); }
            else if (c < 27) { const int e = c - 15; v = __cosf(pt[e >> 2] * (float)(1 << (e & 3))); }
            else             v = 0.f;
            vals[j] = v;
        }
        bf16x8 hi, lo;
#pragma unroll
        for (int j = 0; j < 8; j++) {
            const short h = bf16r(vals[j]);
            hi[j] = h;
            lo[j] = bf16r(vals[j] - bf2f((unsigned short)h));
        }
        *(bf16x8*)(sA + p * 72 + wv * 8) = hi;
        *(bf16x8*)(sA + p * 72 + 32 + wv * 8) = lo;
    }
    __syncthreads();

    // ---- phase 1: deform L1  K=32, wave covers nt {ntb,ntb+1}, 4 m-tiles ----
    {
        f32x4 acc[4][2];
#pragma unroll
        for (int mt = 0; mt < 4; mt++)
#pragma unroll
            for (int n2 = 0; n2 < 2; n2++) acc[mt][n2] = (f32x4){0.f, 0.f, 0.f, 0.f};
        bf16x8 bh[2], bl[2];
#pragma unroll
        for (int n2 = 0; n2 < 2; n2++) {
            bh[n2] = *(const bf16x8*)(dt0h + ((ntb + n2) * 64 + lane) * 8);
            bl[n2] = *(const bf16x8*)(dt0l + ((ntb + n2) * 64 + lane) * 8);
        }
#pragma unroll
        for (int mt = 0; mt < 4; mt++) {
            const bf16x8 ah = *(const bf16x8*)(sA + (mt * 16 + l15) * 72 + q * 8);
            const bf16x8 al = *(const bf16x8*)(sA + (mt * 16 + l15) * 72 + 32 + q * 8);
#pragma unroll
            for (int n2 = 0; n2 < 2; n2++) {
                acc[mt][n2] = MFMA16(ah, bh[n2], acc[mt][n2]);
                acc[mt][n2] = MFMA16(al, bh[n2], acc[mt][n2]);
                acc[mt][n2] = MFMA16(ah, bl[n2], acc[mt][n2]);
            }
        }
#pragma unroll
        for (int n2 = 0; n2 < 2; n2++) {
            const int n0 = (ntb + n2) * 16 + l15;
            const float bv = be0[n0];
#pragma unroll
            for (int mt = 0; mt < 4; mt++)
#pragma unroll
                for (int rg = 0; rg < 4; rg++)
                    sB[(mt * 16 + q * 4 + rg) * 132 + n0] =
                        bf16r(fmaxf(acc[mt][n2][rg] + bv, 0.f));
        }
    }
    __syncthreads();

    // ---- phase 2: deform L2  K=128 (4 kt), weight-residual split; f32 -> sA;
    //      prefetch fnw fragments for phase 4 before the closing barrier ----
    {
        bf16x8 bh[4][2], bl[4][2];
#pragma unroll
        for (int kt = 0; kt < 4; kt++)
#pragma unroll
            for (int n2 = 0; n2 < 2; n2++) {
                bh[kt][n2] = *(const bf16x8*)(dt1h + (((ntb + n2) * 4 + kt) * 64 + lane) * 8);
                bl[kt][n2] = *(const bf16x8*)(dt1l + (((ntb + n2) * 4 + kt) * 64 + lane) * 8);
            }
        f32x4 acc[4][2];
#pragma unroll
        for (int mt = 0; mt < 4; mt++)
#pragma unroll
            for (int n2 = 0; n2 < 2; n2++) acc[mt][n2] = (f32x4){0.f, 0.f, 0.f, 0.f};
#pragma unroll
        for (int kt = 0; kt < 4; kt++) {
            bf16x8 a[4];
#pragma unroll
            for (int mt = 0; mt < 4; mt++)
                a[mt] = *(const bf16x8*)(sB + (mt * 16 + l15) * 132 + (kt * 4 + q) * 8);
#pragma unroll
            for (int n2 = 0; n2 < 2; n2++) {
#pragma unroll
                for (int mt = 0; mt < 4; mt++) {
                    acc[mt][n2] = MFMA16(a[mt], bh[kt][n2], acc[mt][n2]);
                    acc[mt][n2] = MFMA16(a[mt], bl[kt][n2], acc[mt][n2]);
                }
            }
        }
        // prefetch fnw (phase-4 B operand) — hidden under accumulator writeback
#pragma unroll
        for (int kt = 0; kt < 7; kt++)
#pragma unroll
            for (int n2 = 0; n2 < 2; n2++)
                pf4[kt][n2] = *(const bf16x8*)(fnw + (((ntb + n2) * 7 + kt) * 64 + lane) * 8);
        float* sF = (float*)sA;
#pragma unroll
        for (int n2 = 0; n2 < 2; n2++) {
            const int n0 = (ntb + n2) * 16 + l15;
            const float bv = dt_b1[n0];
#pragma unroll
            for (int mt = 0; mt < 4; mt++)
#pragma unroll
                for (int rg = 0; rg < 4; rg++)
                    sF[(mt * 16 + q * 4 + rg) * 132 + n0] = fmaxf(acc[mt][n2][rg] + bv, 0.f);
        }
    }
    __syncthreads();

    // ---- phase 3a: dx (192 threads: 64 pts x 3 dims) -> pts_d to sSm ----
    if (tid < 192) {
        const int p = tid & 63, d = tid >> 6;
        const float* sF = (const float*)sA;
        float a = sWo[384 + d];
        for (int k = 0; k < 128; k += 4) {
            const float4 h = *(const float4*)&sF[p * 132 + k];
            a += h.x * sWo[k * 3 + d] + h.y * sWo[(k + 1) * 3 + d]
               + h.z * sWo[(k + 2) * 3 + d] + h.w * sWo[(k + 3) * 3 + d];
        }
        sSm[p * 4 + d] = ray_pts[(p0g + p) * 3 + d] + a;
    }
    __syncthreads();

    // ---- phase 3b: wave0 = density+alpha+scan+pts-emb; waves1-3 = gathers;
    //      prefetch dwf fragments for phase 5 (hidden under gather latency) ----
    {
        const int p = lane;
        const float pd[3] = { sSm[p * 4], sSm[p * 4 + 1], sSm[p * 4 + 2] };
        if (wv == 0) {
            int i0[3]; float fr[3];
#pragma unroll
            for (int d = 0; d < 3; d++) {
                float t = (pd[d] + 1.f) * 63.5f;
                t = fminf(fmaxf(t, 0.f), 127.f - 1e-4f);
                const int i = (int)t;
                i0[d] = i; fr[d] = t - (float)i;
            }
            float dens = 0.f;
#pragma unroll
            for (int dx = 0; dx < 2; dx++)
#pragma unroll
                for (int dy = 0; dy < 2; dy++) {
                    const float wxy = (dx ? fr[0] : 1.f - fr[0]) * (dy ? fr[1] : 1.f - fr[1]);
                    const float* b = &density[((i0[0] + dx) * 128 + i0[1] + dy) * 128 + i0[2]];
                    dens += wxy * ((1.f - fr[2]) * b[0] + fr[2] * b[1]);
                }
            const float xs = dens + ACT_SHIFT_F;
            const float sp = fmaxf(xs, 0.f) + __logf(1.f + __expf(-fabsf(xs)));
            const float alpha = 1.f - __expf(-sp * 0.5f);
            const float lm = fmaxf(-sp * 0.5f, LOG1EM10);
            float v = lm;
#pragma unroll
            for (int d = 1; d < 64; d <<= 1) {
                const float o = __shfl_up(v, d);
                if (p >= d) v += o;
            }
            sSm[p * 4 + 3] = alpha * __expf(v - lm);
            if (p == 63) sAiv[0] = __expf(v);
            // pts_d embedding -> X cols 180..206, zero pad 207..223
            sA[p * 232 + 180] = bf16r(pd[0]);
            sA[p * 232 + 181] = bf16r(pd[1]);
            sA[p * 232 + 182] = bf16r(pd[2]);
#pragma unroll
            for (int d = 0; d < 3; d++) {
                float sv = __sinf(pd[d]), cv = __cosf(pd[d]);
#pragma unroll
                for (int f = 0; f < 4; f++) {
                    sA[p * 232 + 183 + d * 4 + f] = bf16r(sv);
                    sA[p * 232 + 195 + d * 4 + f] = bf16r(cv);
                    const float ns = 2.f * sv * cv;
                    cv = 1.f - 2.f * sv * sv;      // cos(2t) = 1 - 2 sin^2 t
                    sv = ns;                        // sin(2t) = 2 sin t cos t
                }
            }
            sA[p * 232 + 207] = 0;
            const bf16x8 zv = { 0, 0, 0, 0, 0, 0, 0, 0 };
            *(bf16x8*)(sA + p * 232 + 208) = zv;
            *(bf16x8*)(sA + p * 232 + 216) = zv;
        } else {
            const int s = wv - 1;
            const int n = (s == 0) ? 128 : ((s == 1) ? 64 : 32);
            const short* g = (s == 0) ? g0 : ((s == 1) ? p2g : p4g);
            const float dim = (float)(n - 1);
            int i0[3]; float fr[3];
#pragma unroll
            for (int d = 0; d < 3; d++) {
                float t = (pd[d] + 1.f) * 0.5f * dim;
                t = fminf(fmaxf(t, 0.f), dim - 1e-4f);
                const int i = (int)t;
                i0[d] = i; fr[d] = t - (float)i;
            }
            float feat[12];
#pragma unroll
            for (int c = 0; c < 12; c++) feat[c] = 0.f;
#pragma unroll
            for (int dx = 0; dx < 2; dx++)
#pragma unroll
                for (int dy = 0; dy < 2; dy++)
#pragma unroll
                    for (int dz = 0; dz < 2; dz++) {
                        const float wc = (dx ? fr[0] : 1.f - fr[0]) *
                                         (dy ? fr[1] : 1.f - fr[1]) *
                                         (dz ? fr[2] : 1.f - fr[2]);
                        const int vox = ((i0[0] + dx) * n + i0[1] + dy) * n + i0[2] + dz;
                        acc12(g, vox, wc, feat);
                    }
#pragma unroll
            for (int c = 0; c < 12; c++) {
                const float v = feat[c];
                const int j = s * 12 + c;
                sA[p * 232 + j] = bf16r(v);
                const float sv = __sinf(v), cv = __cosf(v);
                const unsigned s1 = (unsigned short)bf16r(sv);
                const unsigned s2 = (unsigned short)bf16r(2.f * sv * cv);
                const unsigned c1 = (unsigned short)bf16r(cv);
                const unsigned c2 = (unsigned short)bf16r(1.f - 2.f * sv * sv);
                *(unsigned*)(sA + p * 232 + 36 + 2 * j)  = s1 | (s2 << 16);
                *(unsigned*)(sA + p * 232 + 108 + 2 * j) = c1 | (c2 << 16);
            }
        }
        // prefetch dwf (phase-5 B operand) — all waves, uniform code
#pragma unroll
        for (int kt = 0; kt < 4; kt++)
#pragma unroll
            for (int n2 = 0; n2 < 2; n2++)
                pf5[kt][n2] = *(const bf16x8*)(dwf + (((ntb + n2) * 4 + kt) * 64 + lane) * 8);
    }
    __syncthreads();

    // ---- phase 4: featurenet  K=224 (7 kt), relu -> sB (stride 132);
    //      prefetch dw0 fragments for phase 6 ----
    {
        f32x4 acc[4][2];
#pragma unroll
        for (int mt = 0; mt < 4; mt++)
#pragma unroll
            for (int n2 = 0; n2 < 2; n2++) acc[mt][n2] = (f32x4){0.f, 0.f, 0.f, 0.f};
#pragma unroll
        for (int kt = 0; kt < 7; kt++) {
            bf16x8 a[4];
#pragma unroll
            for (int mt = 0; mt < 4; mt++)
                a[mt] = *(const bf16x8*)(sA + (mt * 16 + l15) * 232 + (kt * 4 + q) * 8);
#pragma unroll
            for (int n2 = 0; n2 < 2; n2++) {
#pragma unroll
                for (int mt = 0; mt < 4; mt++) acc[mt][n2] = MFMA16(a[mt], pf4[kt][n2], acc[mt][n2]);
            }
        }
        // prefetch dw0 (phase-6 B operand)
#pragma unroll
        for (int kt = 0; kt < 4; kt++)
            pf6[kt] = *(const bf16x8*)(dw0 + ((wv * 4 + kt) * 64 + lane) * 8);
#pragma unroll
        for (int n2 = 0; n2 < 2; n2++) {
            const int n0 = (ntb + n2) * 16 + l15;
            const float bv = fn_b0[n0];
#pragma unroll
            for (int mt = 0; mt < 4; mt++)
#pragma unroll
                for (int rg = 0; rg < 4; rg++)
                    sB[(mt * 16 + q * 4 + rg) * 132 + n0] = bf16r(fmaxf(acc[mt][n2][rg] + bv, 0.f));
        }
    }
    __syncthreads();

    // ---- phase 5: dec_wf  K=128 (4 kt), no relu -> sA (stride 136) ----
    {
        f32x4 acc[4][2];
#pragma unroll
        for (int mt = 0; mt < 4; mt++)
#pragma unroll
            for (int n2 = 0; n2 < 2; n2++) acc[mt][n2] = (f32x4){0.f, 0.f, 0.f, 0.f};
#pragma unroll
        for (int kt = 0; kt < 4; kt++) {
            bf16x8 a[4];
#pragma unroll
            for (int mt = 0; mt < 4; mt++)
                a[mt] = *(const bf16x8*)(sB + (mt * 16 + l15) * 132 + (kt * 4 + q) * 8);
#pragma unroll
            for (int n2 = 0; n2 < 2; n2++) {
#pragma unroll
                for (int mt = 0; mt < 4; mt++) acc[mt][n2] = MFMA16(a[mt], pf5[kt][n2], acc[mt][n2]);
            }
        }
#pragma unroll
        for (int n2 = 0; n2 < 2; n2++) {
            const int n0 = (ntb + n2) * 16 + l15;
            const float bv = dec_bf[n0];
#pragma unroll
            for (int mt = 0; mt < 4; mt++)
#pragma unroll
                for (int rg = 0; rg < 4; rg++)
                    sA[(mt * 16 + q * 4 + rg) * 136 + n0] = bf16r(acc[mt][n2][rg] + bv);
        }
    }
    __syncthreads();

    // ---- phase 6: dec_w0  K=128 (vemb folded in sBe3), N=64 (1 nt/wave);
    //      also stage dec_w1/dec_b1 into dead sB space [short 4608..] ----
    {
        float* sDw = (float*)sB + 2304;   // byte 9216, beyond h2dec (4608 shorts)
        for (int i = tid; i < 195; i += 256)
            sDw[i] = (i < 192) ? dec_w1[i] : dec_b1[i - 192];
        f32x4 acc[4];
#pragma unroll
        for (int mt = 0; mt < 4; mt++) acc[mt] = (f32x4){0.f, 0.f, 0.f, 0.f};
#pragma unroll
        for (int kt = 0; kt < 4; kt++) {
            bf16x8 a[4];
#pragma unroll
            for (int mt = 0; mt < 4; mt++)
                a[mt] = *(const bf16x8*)(sA + (mt * 16 + l15) * 136 + (kt * 4 + q) * 8);
#pragma unroll
            for (int mt = 0; mt < 4; mt++) acc[mt] = MFMA16(a[mt], pf6[kt], acc[mt]);
        }
        const int n0 = wv * 16 + l15;
        const float bv = sBe3[n0];
#pragma unroll
        for (int mt = 0; mt < 4; mt++)
#pragma unroll
            for (int rg = 0; rg < 4; rg++)
                sB[(mt * 16 + q * 4 + rg) * 72 + n0] = bf16r(fmaxf(acc[mt][rg] + bv, 0.f));
    }
    __syncthreads();

    // ---- phase 7: 64->3, sigmoid, weight, wave-reduce, store ----
    if (tid < 64) {
        const int p = tid;
        const float* sDw = (const float*)sB + 2304;
        float a0 = sDw[192], a1 = sDw[193], a2 = sDw[194];
#pragma unroll
        for (int g = 0; g < 8; g++) {
            const bf16x8 h = *(const bf16x8*)(sB + p * 72 + g * 8);
#pragma unroll
            for (int j = 0; j < 8; j++) {
                const float f = bf2f((unsigned short)h[j]);
                const int k = g * 8 + j;
                a0 += f * sDw[k * 3];
                a1 += f * sDw[k * 3 + 1];
                a2 += f * sDw[k * 3 + 2];
            }
        }
        const float wgt = sSm[p * 4 + 3];
        float r0 = wgt / (1.f + __expf(-a0));
        float r1 = wgt / (1.f + __expf(-a1));
        float r2 = wgt / (1.f + __expf(-a2));
#pragma unroll
        for (int off = 32; off >= 1; off >>= 1) {
            r0 += __shfl_down(r0, off);
            r1 += __shfl_down(r1, off);
            r2 += __shfl_down(r2, off);
        }
        if (p == 0) {
            const float av = sAiv[0];
            out[r * 3]     = r0 + av;
            out[r * 3 + 1] = r1 + av;
            out[r * 3 + 2] = r2 + av;
        }
    }
}

// ---------------------------------------------------------------------------
extern "C" void kernel_launch(void* const* d_in, const int* in_sizes, int n_in,
                              void* d_out, int out_size, void* d_ws, size_t ws_size,
                              hipStream_t stream)
{
    const float* ray_pts    = (const float*)d_in[0];
    const float* viewdirs   = (const float*)d_in[1];
    const float* frame_time = (const float*)d_in[2];
    float*       feature    = (float*)d_in[3];          // clobbered only in small-ws path
    const float* density    = (const float*)d_in[4];
    const float* tn_w0 = (const float*)d_in[5];  const float* tn_b0 = (const float*)d_in[6];
    const float* tn_w1 = (const float*)d_in[7];  const float* tn_b1 = (const float*)d_in[8];
    const float* dt_w0 = (const float*)d_in[9];  const float* dt_b0 = (const float*)d_in[10];
    const float* dt_w1 = (const float*)d_in[11]; const float* dt_b1 = (const float*)d_in[12];
    const float* dt_wo = (const float*)d_in[13]; const float* dt_bo = (const float*)d_in[14];
    const float* fn_w0 = (const float*)d_in[15]; const float* fn_b0 = (const float*)d_in[16];
    const float* dec_wf = (const float*)d_in[17]; const float* dec_bf = (const float*)d_in[18];
    const float* dec_w0 = (const float*)d_in[19]; const float* dec_b0 = (const float*)d_in[20];
    const float* dec_w1 = (const float*)d_in[21]; const float* dec_b1 = (const float*)d_in[22];
    (void)in_sizes; (void)n_in; (void)out_size;

    char* ws = (char*)d_ws;
    const bool big = ws_size >= (size_t)57598464;

    short *G, *p2, *p4, *B1 = nullptr, *B2 = nullptr;
    float* be0; short *dt0h, *dt0l, *dt1h, *dt1l, *fnw, *dwf, *dw0;

    if (big) {
        G    = (short*)(ws + 0);            // 128^3*12 bf16 = 50331648 B
        p2   = (short*)(ws + 50331648);
        p4   = (short*)(ws + 56623104);
        be0  = (float*)(ws + 57409536);
        dt0h = (short*)(ws + 57410048);
        dt0l = (short*)(ws + 57418240);
        dt1h = (short*)(ws + 57426432);
        dt1l = (short*)(ws + 57459200);
        fnw  = (short*)(ws + 57491968);
        dwf  = (short*)(ws + 57549312);
        dw0  = (short*)(ws + 57582080);     // ends 57598464
    } else {
        G    = (short*)feature;             // in-place in feature buffer
        B1   = (short*)(ws + 0);            // 3*GV bf16
        B2   = (short*)(ws + 12582912);     // 3*GVH bf16
        p2   = (short*)(ws + 0);            // reuse after transpose
        p4   = (short*)(ws + 6291456);
        be0  = (float*)(ws + 18874368);
        dt0h = (short*)(ws + 18874880);
        dt0l = (short*)(ws + 18883072);
        dt1h = (short*)(ws + 18891264);
        dt1l = (short*)(ws + 18924032);
        fnw  = (short*)(ws + 18956800);
        dwf  = (short*)(ws + 19014144);
        dw0  = (short*)(ws + 19046912);     // ends 19063296
    }

    pack_timenet_kernel<<<289, 256, 0, stream>>>(
        dt_w0, dt_w1, fn_w0, dec_wf, dec_w0,
        frame_time, tn_w0, tn_b0, tn_w1, tn_b1, dt_b0,
        dt0h, dt0l, dt1h, dt1l, fnw, dwf, dw0, be0);

    if (big) {
        transpose_big_kernel<<<2048, 256, 0, stream>>>(feature, G);
    } else {
        compact_kernel<<<9216, 256, 0, stream>>>(feature, B1, B2);
        transpose_kernel<<<1024, 256, 0, stream>>>(feature, B1, B2, G, 0);
        transpose_kernel<<<1024, 256, 0, stream>>>(feature, B1, B2, G, 1);
    }
    pool_kernel_t<1><<<1024, 256, 0, stream>>>(G, p2, 6);
    pool_kernel_t<1><<<128, 256, 0, stream>>>(p2, p4, 5);

    fused_kernel<<<4096, 256, 0, stream>>>(ray_pts, viewdirs, be0,
                                           dt0h, dt0l, dt1h, dt1l, dt_b1,
                                           dt_wo, dt_bo, density,
                                           G, p2, p4,
                                           fnw, fn_b0, dwf, dec_bf,
                                           dw0, dec_b0, dec_w0, dec_w1, dec_b1,
                                           (float*)d_out);
}

// Round 7
// 365.170 us; speedup vs baseline: 1.1146x; 1.0273x over previous
//
#include <hip/hip_runtime.h>
#include <math.h>

// ---------------------------------------------------------------------------
// VoxelMlp forward, round 14:
//  - r13 post-mortem: cross-barrier weight prefetch was NULL (154.5->154.2,
//    VGPR 80) -> phase-entry weight loads (L2-hot) never on critical path.
//    Prefetch removed.
//  - new single variable: phase-3b gather latency. acc12's load->use chain
//    serialized the 8 corner fetches (g0 = 50MB, L3/HBM ~600-900cyc). Now all
//    24 ushort4 loads are issued into registers up front (cr[2][2][2][3],
//    +48 VGPR, cap 170 at 3 waves/EU), then accumulated. Same hoist for the
//    8 density loads in wave0.
//  - prep unchanged (r13 config, best total 375.1).
// ---------------------------------------------------------------------------

#define N_RAYS 4096
#define ACT_SHIFT_F (-4.595119850134589f)
#define LOG1EM10 (-23.025850929940457f)
#define GV 2097152            // 128^3
#define GVH 1048576           // 128^3 / 2

typedef __attribute__((ext_vector_type(8))) short bf16x8;
typedef __attribute__((ext_vector_type(4))) float f32x4;
#define MFMA16(a, b, c) __builtin_amdgcn_mfma_f32_16x16x32_bf16(a, b, c, 0, 0, 0)

__device__ __forceinline__ short bf16r(float f) {   // RNE f32 -> bf16
    unsigned int u = __float_as_uint(f);
    u += 0x7FFF + ((u >> 16) & 1);
    return (short)(u >> 16);
}
__device__ __forceinline__ float bf2f(unsigned short s) {
    return __uint_as_float(((unsigned int)s) << 16);
}
__device__ __forceinline__ uint2 pack4(float4 x) {
    const unsigned a = (unsigned short)bf16r(x.x), b = (unsigned short)bf16r(x.y);
    const unsigned c = (unsigned short)bf16r(x.z), d = (unsigned short)bf16r(x.w);
    return make_uint2(a | (b << 16), c | (d << 16));
}

// store 4 voxels x 12 bf16 channels (96 B) as 6 uint4
__device__ __forceinline__ void store_vox4(short* __restrict__ dst,
                                           const unsigned short us[4][12]) {
    unsigned w[24];
#pragma unroll
    for (int j = 0; j < 24; j++) {
        const int a = (2 * j) / 12, ca = (2 * j) % 12;
        const int b = (2 * j + 1) / 12, cb = (2 * j + 1) % 12;
        w[j] = (unsigned)us[a][ca] | ((unsigned)us[b][cb] << 16);
    }
    uint4* o = (uint4*)dst;
#pragma unroll
    for (int t = 0; t < 6; t++)
        o[t] = make_uint4(w[4 * t], w[4 * t + 1], w[4 * t + 2], w[4 * t + 3]);
}

// ---------------------------------------------------------------------------
// pack weights (blocks 0..287) + timenet/bias-fold (block 288).
// ---------------------------------------------------------------------------
__global__ __launch_bounds__(256) void pack_timenet_kernel(
    const float* __restrict__ dt_w0, const float* __restrict__ dt_w1,
    const float* __restrict__ fn_w0, const float* __restrict__ dec_wf,
    const float* __restrict__ dec_w0,
    const float* __restrict__ ft,
    const float* __restrict__ tw0, const float* __restrict__ tb0,
    const float* __restrict__ tw1, const float* __restrict__ tb1,
    const float* __restrict__ dt_b0,
    short* __restrict__ dt0h, short* __restrict__ dt0l,
    short* __restrict__ dt1h, short* __restrict__ dt1l,
    short* __restrict__ fnw, short* __restrict__ dwf, short* __restrict__ dw0,
    float* __restrict__ be0)
{
    const int tid = threadIdx.x;
    if (blockIdx.x == 288) {
        __shared__ float sh[128];
        __shared__ float stf[60];
        const float t = ft[0];
        float te[9];
        te[0] = t;
        float fr = 1.f;
#pragma unroll
        for (int f = 0; f < 4; f++) {
            te[1 + f] = __sinf(t * fr);
            te[5 + f] = __cosf(t * fr);
            fr *= 2.f;
        }
        if (tid < 128) {
            float acc = tb0[tid];
#pragma unroll
            for (int k = 0; k < 9; k++) acc = fmaf(te[k], tw0[k * 128 + tid], acc);
            sh[tid] = fmaxf(acc, 0.f);
        }
        __syncthreads();
        if (tid < 60) {
            float acc = tb1[tid];
            for (int k = 0; k < 128; k++) acc = fmaf(sh[k], tw1[k * 60 + tid], acc);
            stf[tid] = acc;
        }
        __syncthreads();
        if (tid < 128) {
            float acc = dt_b0[tid];
            for (int k = 0; k < 60; k++) acc = fmaf(stf[k], dt_w0[(27 + k) * 128 + tid], acc);
            be0[tid] = acc;
        }
        return;
    }
    const int id = blockIdx.x * 256 + tid;   // < 73728
    const float* W; short* dh; short* dl = nullptr; int In, KT, Out, e;
    if (id < 4096)       { W = dt_w0;  dh = dt0h; dl = dt0l; In = 27;  KT = 1; Out = 128; e = id; }
    else if (id < 20480) { W = dt_w1;  dh = dt1h; dl = dt1l; In = 128; KT = 4; Out = 128; e = id - 4096; }
    else if (id < 49152) { W = fn_w0;  dh = fnw;             In = 207; KT = 7; Out = 128; e = id - 20480; }
    else if (id < 65536) { W = dec_wf; dh = dwf;             In = 128; KT = 4; Out = 128; e = id - 49152; }
    else                 { W = dec_w0; dh = dw0;             In = 128; KT = 4; Out = 64;  e = id - 65536; }
    const int j = e & 7, lane = (e >> 3) & 63, rest = e >> 9;
    const int kt = rest % KT, nt = rest / KT;
    const int n = nt * 16 + (lane & 15);
    const int k = kt * 32 + (lane >> 4) * 8 + j;
    const float v = (k < In) ? W[k * Out + n] : 0.f;
    const short hi = bf16r(v);
    dh[e] = hi;
    if (dl) dl[e] = bf16r(v - bf2f((unsigned short)hi));
}

// ---------------------------------------------------------------------------
// BIG path: direct transpose, 4 voxels/thread
// ---------------------------------------------------------------------------
__global__ __launch_bounds__(256) void transpose_big_kernel(
    const float* __restrict__ f, short* __restrict__ G)
{
    const int v = (blockIdx.x * 256 + threadIdx.x) * 4;   // < GV
    unsigned short us[4][12];
#pragma unroll
    for (int c = 0; c < 12; c++) {
        const float4 x = *(const float4*)(f + (size_t)c * GV + v);
        us[0][c] = (unsigned short)bf16r(x.x);
        us[1][c] = (unsigned short)bf16r(x.y);
        us[2][c] = (unsigned short)bf16r(x.z);
        us[3][c] = (unsigned short)bf16r(x.w);
    }
    store_vox4(G + (size_t)v * 12, us);
}

// ---------------------------------------------------------------------------
// SMALL-ws: bounce-compact (4 elems/thread) + 2-pass in-place transpose (4/thr)
// ---------------------------------------------------------------------------
__global__ __launch_bounds__(256) void compact_kernel(
    const float* __restrict__ f, short* __restrict__ B1, short* __restrict__ B2)
{
    const int id = (blockIdx.x * 256 + threadIdx.x) * 4;   // < 9437184
    if (id < 3 * GV) {
        *(uint2*)(B1 + id) = pack4(*(const float4*)(f + id));
    } else {
        const int e = id - 3 * GV;
        const int c = e >> 20;
        const int v2 = e & (GVH - 1);
        *(uint2*)(B2 + e) = pack4(*(const float4*)(f + (size_t)(3 + c) * GV + GVH + v2));
    }
}

__global__ __launch_bounds__(256) void transpose_kernel(
    const float* __restrict__ f, const short* __restrict__ B1,
    const short* __restrict__ B2, short* __restrict__ G, int pass)
{
    const int idx = (blockIdx.x * 256 + threadIdx.x) * 4;  // < GVH
    const int v = pass * GVH + idx;
    unsigned short us[4][12];
#pragma unroll
    for (int c = 0; c < 3; c++) {
        const uint2 b = *(const uint2*)(B1 + c * GV + v);
        us[0][c] = (unsigned short)(b.x & 0xFFFF); us[1][c] = (unsigned short)(b.x >> 16);
        us[2][c] = (unsigned short)(b.y & 0xFFFF); us[3][c] = (unsigned short)(b.y >> 16);
    }
    if (pass == 0) {
#pragma unroll
        for (int c = 3; c < 12; c++) {
            const float4 x = *(const float4*)(f + (size_t)c * GV + v);
            us[0][c] = (unsigned short)bf16r(x.x);
            us[1][c] = (unsigned short)bf16r(x.y);
            us[2][c] = (unsigned short)bf16r(x.z);
            us[3][c] = (unsigned short)bf16r(x.w);
        }
    } else {
#pragma unroll
        for (int c = 3; c < 6; c++) {
            const uint2 b = *(const uint2*)(B2 + (c - 3) * GVH + idx);
            us[0][c] = (unsigned short)(b.x & 0xFFFF); us[1][c] = (unsigned short)(b.x >> 16);
            us[2][c] = (unsigned short)(b.y & 0xFFFF); us[3][c] = (unsigned short)(b.y >> 16);
        }
#pragma unroll
        for (int c = 6; c < 12; c++) {
            const float4 x = *(const float4*)(f + (size_t)c * GV + v);
            us[0][c] = (unsigned short)bf16r(x.x);
            us[1][c] = (unsigned short)bf16r(x.y);
            us[2][c] = (unsigned short)bf16r(x.z);
            us[3][c] = (unsigned short)bf16r(x.w);
        }
    }
    store_vox4(G + (size_t)v * 12, us);
}

// ---------------------------------------------------------------------------
// 2x avg-pool, channel-last bf16 -> bf16, VPER output voxels/thread.
// ---------------------------------------------------------------------------
template<int VPER>
__global__ __launch_bounds__(256) void pool_kernel_t(
    const short* __restrict__ src, short* __restrict__ dst, int so)
{
    const int nout = 1 << so, nin = nout << 1;
    const int idx = (blockIdx.x * 256 + threadIdx.x) * VPER;
    const int z0 = idx & (nout - 1), y = (idx >> so) & (nout - 1), x = idx >> (2 * so);
    float acc[VPER][12];
#pragma unroll
    for (int k = 0; k < VPER; k++)
#pragma unroll
        for (int c = 0; c < 12; c++) acc[k][c] = 0.f;
#pragma unroll
    for (int i = 0; i < 2; i++)
#pragma unroll
        for (int j = 0; j < 2; j++) {
            const size_t roff = (size_t)(((2 * x + i) * nin + (2 * y + j)) * nin + 2 * z0) * 12;
            const uint4* R4 = (const uint4*)(src + roff);
            uint4 U[3 * VPER];
#pragma unroll
            for (int t = 0; t < 3 * VPER; t++) U[t] = R4[t];
            const unsigned* W = (const unsigned*)U;
#pragma unroll
            for (int k = 0; k < VPER; k++)
#pragma unroll
                for (int c = 0; c < 12; c++) {
                    const int s0 = 24 * k + c, s1 = 24 * k + 12 + c;
                    const unsigned u0 = W[s0 >> 1], u1 = W[s1 >> 1];
                    acc[k][c] += bf2f((unsigned short)((s0 & 1) ? (u0 >> 16) : (u0 & 0xFFFF)))
                               + bf2f((unsigned short)((s1 & 1) ? (u1 >> 16) : (u1 & 0xFFFF)));
                }
        }
    unsigned w[6 * VPER];
#pragma unroll
    for (int t = 0; t < 6 * VPER; t++) {
        const int e0 = 2 * t, e1 = 2 * t + 1;
        const unsigned short a = (unsigned short)bf16r(acc[e0 / 12][e0 % 12] * 0.125f);
        const unsigned short b = (unsigned short)bf16r(acc[e1 / 12][e1 % 12] * 0.125f);
        w[t] = (unsigned)a | ((unsigned)b << 16);
    }
    uint2* o = (uint2*)(dst + (size_t)idx * 12);
#pragma unroll
    for (int t = 0; t < 3 * VPER; t++)
        o[t] = make_uint2(w[2 * t], w[2 * t + 1]);
}

// ---------------------------------------------------------------------------
// fused (r9 structure + hoisted gather/density loads): emb -> deform L1/L2
// MFMA -> dx -> density+scan | gathers -> featurenet -> decoder MFMA ->
// composite.  Block = 1 ray, 256 thr, LDS 53760 B -> 3 blocks/CU.
// ---------------------------------------------------------------------------
__global__ __launch_bounds__(256, 3) void fused_kernel(
    const float* __restrict__ ray_pts, const float* __restrict__ viewdirs,
    const float* __restrict__ be0,
    const short* __restrict__ dt0h, const short* __restrict__ dt0l,
    const short* __restrict__ dt1h, const short* __restrict__ dt1l,
    const float* __restrict__ dt_b1,
    const float* __restrict__ dt_wo, const float* __restrict__ dt_bo,
    const float* __restrict__ density,
    const short* __restrict__ g0, const short* __restrict__ p2g, const short* __restrict__ p4g,
    const short* __restrict__ fnw, const float* __restrict__ fn_b0,
    const short* __restrict__ dwf, const float* __restrict__ dec_bf,
    const short* __restrict__ dw0, const float* __restrict__ dec_b0,
    const float* __restrict__ dec_w0, const float* __restrict__ dec_w1,
    const float* __restrict__ dec_b1,
    float* __restrict__ out)
{
    // sA: emb (stride 72) -> h2 f32 (stride 132 f32) -> X (232) -> fl (136)
    // sB: h1 (stride 132) -> hf (stride 132) -> h2dec (stride 72) + sDw stage
    __shared__ __align__(16) short sA[16896];   // 33792 B
    __shared__ __align__(16) short sB[8448];    // 16896 B
    __shared__ float sWo[387];                  // dt_wo + dt_bo
    __shared__ float sSm[256];                  // [p*4+d]: pts_d xyz, d=3: weight
    __shared__ float sBe3[64];                  // folded decoder-L0 bias
    __shared__ float sAiv[1];

    const int tid = threadIdx.x;
    const int r = blockIdx.x;
    const int p0g = r * 64;
    const int lane = tid & 63, wv = tid >> 6;
    const int l15 = lane & 15, q = lane >> 4;
    const int ntb = wv * 2;

    // ---- phase 0: preloads + folded decoder bias + deform embedding ----
    for (int i = tid; i < 384; i += 256) sWo[i] = dt_wo[i];
    if (tid < 3) sWo[384 + tid] = dt_bo[tid];
    if (tid < 64) {   // be3[n] = dec_b0[n] + vemb . dec_w0[128:149][n]
        const float v0 = viewdirs[r * 3], v1 = viewdirs[r * 3 + 1], v2 = viewdirs[r * 3 + 2];
        const float vv[3] = { v0, v1, v2 };
        float ve[21];
        ve[0] = v0; ve[1] = v1; ve[2] = v2;
#pragma unroll
        for (int d = 0; d < 3; d++) {
            float fq = 1.f;
#pragma unroll
            for (int f = 0; f < 3; f++) {
                ve[3 + d * 3 + f]  = __sinf(vv[d] * fq);
                ve[12 + d * 3 + f] = __cosf(vv[d] * fq);
                fq *= 2.f;
            }
        }
        float acc = dec_b0[tid];
#pragma unroll
        for (int k = 0; k < 21; k++) acc = fmaf(ve[k], dec_w0[(128 + k) * 64 + tid], acc);
        sBe3[tid] = acc;
    }
    {   // deform emb: thread (p=lane, grp=wv) -> cols wv*8..wv*8+7 (hi) / +32 (lo)
        const int p = lane;
        const int gp = p0g + p;
        const float pt[3] = { ray_pts[gp * 3], ray_pts[gp * 3 + 1], ray_pts[gp * 3 + 2] };
        float vals[8];
#pragma unroll
        for (int j = 0; j < 8; j++) {
            const int c = wv * 8 + j;
            float v;
            if (c < 3)       v = pt[c];
            else if (c < 15) { const int e = c - 3;  v = __sinf(pt[e >> 2] * (float)(1 << (e & 3))); }
            else if (c < 27) { const int e = c - 15; v = __cosf(pt[e >> 2] * (float)(1 << (e & 3))); }
            else             v = 0.f;
            vals[j] = v;
        }
        bf16x8 hi, lo;
#pragma unroll
        for (int j = 0; j < 8; j++) {
            const short h = bf16r(vals[j]);
            hi[j] = h;
            lo[j] = bf16r(vals[j] - bf2f((unsigned short)h));
        }
        *(bf16x8*)(sA + p * 72 + wv * 8) = hi;
        *(bf16x8*)(sA + p * 72 + 32 + wv * 8) = lo;
    }
    __syncthreads();

    // ---- phase 1: deform L1  K=32, wave covers nt {ntb,ntb+1}, 4 m-tiles ----
    {
        f32x4 acc[4][2];
#pragma unroll
        for (int mt = 0; mt < 4; mt++)
#pragma unroll
            for (int n2 = 0; n2 < 2; n2++) acc[mt][n2] = (f32x4){0.f, 0.f, 0.f, 0.f};
        bf16x8 bh[2], bl[2];
#pragma unroll
        for (int n2 = 0; n2 < 2; n2++) {
            bh[n2] = *(const bf16x8*)(dt0h + ((ntb + n2) * 64 + lane) * 8);
            bl[n2] = *(const bf16x8*)(dt0l + ((ntb + n2) * 64 + lane) * 8);
        }
#pragma unroll
        for (int mt = 0; mt < 4; mt++) {
            const bf16x8 ah = *(const bf16x8*)(sA + (mt * 16 + l15) * 72 + q * 8);
            const bf16x8 al = *(const bf16x8*)(sA + (mt * 16 + l15) * 72 + 32 + q * 8);
#pragma unroll
            for (int n2 = 0; n2 < 2; n2++) {
                acc[mt][n2] = MFMA16(ah, bh[n2], acc[mt][n2]);
                acc[mt][n2] = MFMA16(al, bh[n2], acc[mt][n2]);
                acc[mt][n2] = MFMA16(ah, bl[n2], acc[mt][n2]);
            }
        }
#pragma unroll
        for (int n2 = 0; n2 < 2; n2++) {
            const int n0 = (ntb + n2) * 16 + l15;
            const float bv = be0[n0];
#pragma unroll
            for (int mt = 0; mt < 4; mt++)
#pragma unroll
                for (int rg = 0; rg < 4; rg++)
                    sB[(mt * 16 + q * 4 + rg) * 132 + n0] =
                        bf16r(fmaxf(acc[mt][n2][rg] + bv, 0.f));
        }
    }
    __syncthreads();

    // ---- phase 2: deform L2  K=128 (4 kt), weight-residual split; f32 -> sA ----
    {
        bf16x8 bh[4][2], bl[4][2];
#pragma unroll
        for (int kt = 0; kt < 4; kt++)
#pragma unroll
            for (int n2 = 0; n2 < 2; n2++) {
                bh[kt][n2] = *(const bf16x8*)(dt1h + (((ntb + n2) * 4 + kt) * 64 + lane) * 8);
                bl[kt][n2] = *(const bf16x8*)(dt1l + (((ntb + n2) * 4 + kt) * 64 + lane) * 8);
            }
        f32x4 acc[4][2];
#pragma unroll
        for (int mt = 0; mt < 4; mt++)
#pragma unroll
            for (int n2 = 0; n2 < 2; n2++) acc[mt][n2] = (f32x4){0.f, 0.f, 0.f, 0.f};
#pragma unroll
        for (int kt = 0; kt < 4; kt++) {
            bf16x8 a[4];
#pragma unroll
            for (int mt = 0; mt < 4; mt++)
                a[mt] = *(const bf16x8*)(sB + (mt * 16 + l15) * 132 + (kt * 4 + q) * 8);
#pragma unroll
            for (int n2 = 0; n2 < 2; n2++) {
#pragma unroll
                for (int mt = 0; mt < 4; mt++) {
                    acc[mt][n2] = MFMA16(a[mt], bh[kt][n2], acc[mt][n2]);
                    acc[mt][n2] = MFMA16(a[mt], bl[kt][n2], acc[mt][n2]);
                }
            }
        }
        float* sF = (float*)sA;
#pragma unroll
        for (int n2 = 0; n2 < 2; n2++) {
            const int n0 = (ntb + n2) * 16 + l15;
            const float bv = dt_b1[n0];
#pragma unroll
            for (int mt = 0; mt < 4; mt++)
#pragma unroll
                for (int rg = 0; rg < 4; rg++)
                    sF[(mt * 16 + q * 4 + rg) * 132 + n0] = fmaxf(acc[mt][n2][rg] + bv, 0.f);
        }
    }
    __syncthreads();

    // ---- phase 3a: dx (192 threads: 64 pts x 3 dims) -> pts_d to sSm ----
    if (tid < 192) {
        const int p = tid & 63, d = tid >> 6;
        const float* sF = (const float*)sA;
        float a = sWo[384 + d];
        for (int k = 0; k < 128; k += 4) {
            const float4 h = *(const float4*)&sF[p * 132 + k];
            a += h.x * sWo[k * 3 + d] + h.y * sWo[(k + 1) * 3 + d]
               + h.z * sWo[(k + 2) * 3 + d] + h.w * sWo[(k + 3) * 3 + d];
        }
        sSm[p * 4 + d] = ray_pts[(p0g + p) * 3 + d] + a;
    }
    __syncthreads();

    // ---- phase 3b: wave0 = density+alpha+scan+pts-emb; waves1-3 = gathers ----
    {
        const int p = lane;
        const float pd[3] = { sSm[p * 4], sSm[p * 4 + 1], sSm[p * 4 + 2] };
        if (wv == 0) {
            int i0[3]; float fr[3];
#pragma unroll
            for (int d = 0; d < 3; d++) {
                float t = (pd[d] + 1.f) * 63.5f;
                t = fminf(fmaxf(t, 0.f), 127.f - 1e-4f);
                const int i = (int)t;
                i0[d] = i; fr[d] = t - (float)i;
            }
            // hoist all 8 density loads before any use
            float dlo[2][2], dhi[2][2];
#pragma unroll
            for (int dx = 0; dx < 2; dx++)
#pragma unroll
                for (int dy = 0; dy < 2; dy++) {
                    const float* b = &density[((i0[0] + dx) * 128 + i0[1] + dy) * 128 + i0[2]];
                    dlo[dx][dy] = b[0];
                    dhi[dx][dy] = b[1];
                }
            float dens = 0.f;
#pragma unroll
            for (int dx = 0; dx < 2; dx++)
#pragma unroll
                for (int dy = 0; dy < 2; dy++) {
                    const float wxy = (dx ? fr[0] : 1.f - fr[0]) * (dy ? fr[1] : 1.f - fr[1]);
                    dens += wxy * ((1.f - fr[2]) * dlo[dx][dy] + fr[2] * dhi[dx][dy]);
                }
            const float xs = dens + ACT_SHIFT_F;
            const float sp = fmaxf(xs, 0.f) + __logf(1.f + __expf(-fabsf(xs)));
            const float alpha = 1.f - __expf(-sp * 0.5f);
            const float lm = fmaxf(-sp * 0.5f, LOG1EM10);
            float v = lm;
#pragma unroll
            for (int d = 1; d < 64; d <<= 1) {
                const float o = __shfl_up(v, d);
                if (p >= d) v += o;
            }
            sSm[p * 4 + 3] = alpha * __expf(v - lm);
            if (p == 63) sAiv[0] = __expf(v);
            // pts_d embedding -> X cols 180..206, zero pad 207..223
            sA[p * 232 + 180] = bf16r(pd[0]);
            sA[p * 232 + 181] = bf16r(pd[1]);
            sA[p * 232 + 182] = bf16r(pd[2]);
#pragma unroll
            for (int d = 0; d < 3; d++) {
                float sv = __sinf(pd[d]), cv = __cosf(pd[d]);
#pragma unroll
                for (int f = 0; f < 4; f++) {
                    sA[p * 232 + 183 + d * 4 + f] = bf16r(sv);
                    sA[p * 232 + 195 + d * 4 + f] = bf16r(cv);
                    const float ns = 2.f * sv * cv;
                    cv = 1.f - 2.f * sv * sv;      // cos(2t) = 1 - 2 sin^2 t
                    sv = ns;                        // sin(2t) = 2 sin t cos t
                }
            }
            sA[p * 232 + 207] = 0;
            const bf16x8 zv = { 0, 0, 0, 0, 0, 0, 0, 0 };
            *(bf16x8*)(sA + p * 232 + 208) = zv;
            *(bf16x8*)(sA + p * 232 + 216) = zv;
        } else {
            const int s = wv - 1;
            const int n = (s == 0) ? 128 : ((s == 1) ? 64 : 32);
            const short* g = (s == 0) ? g0 : ((s == 1) ? p2g : p4g);
            const float dim = (float)(n - 1);
            int i0[3]; float fr[3];
#pragma unroll
            for (int d = 0; d < 3; d++) {
                float t = (pd[d] + 1.f) * 0.5f * dim;
                t = fminf(fmaxf(t, 0.f), dim - 1e-4f);
                const int i = (int)t;
                i0[d] = i; fr[d] = t - (float)i;
            }
            // issue ALL 24 corner loads first (8 corners x 3 ushort4) so the
            // fetch latencies overlap; then accumulate.
            ushort4 cr[2][2][2][3];
#pragma unroll
            for (int dx = 0; dx < 2; dx++)
#pragma unroll
                for (int dy = 0; dy < 2; dy++)
#pragma unroll
                    for (int dz = 0; dz < 2; dz++) {
                        const int vox = ((i0[0] + dx) * n + i0[1] + dy) * n + i0[2] + dz;
                        const ushort4* qp = (const ushort4*)(g + (size_t)vox * 12);
                        cr[dx][dy][dz][0] = qp[0];
                        cr[dx][dy][dz][1] = qp[1];
                        cr[dx][dy][dz][2] = qp[2];
                    }
            float feat[12];
#pragma unroll
            for (int c = 0; c < 12; c++) feat[c] = 0.f;
#pragma unroll
            for (int dx = 0; dx < 2; dx++)
#pragma unroll
                for (int dy = 0; dy < 2; dy++)
#pragma unroll
                    for (int dz = 0; dz < 2; dz++) {
                        const float wc = (dx ? fr[0] : 1.f - fr[0]) *
                                         (dy ? fr[1] : 1.f - fr[1]) *
                                         (dz ? fr[2] : 1.f - fr[2]);
                        const ushort4 a = cr[dx][dy][dz][0];
                        const ushort4 b = cr[dx][dy][dz][1];
                        const ushort4 c2 = cr[dx][dy][dz][2];
                        feat[0]  += wc * bf2f(a.x);  feat[1]  += wc * bf2f(a.y);
                        feat[2]  += wc * bf2f(a.z);  feat[3]  += wc * bf2f(a.w);
                        feat[4]  += wc * bf2f(b.x);  feat[5]  += wc * bf2f(b.y);
                        feat[6]  += wc * bf2f(b.z);  feat[7]  += wc * bf2f(b.w);
                        feat[8]  += wc * bf2f(c2.x); feat[9]  += wc * bf2f(c2.y);
                        feat[10] += wc * bf2f(c2.z); feat[11] += wc * bf2f(c2.w);
                    }
#pragma unroll
            for (int c = 0; c < 12; c++) {
                const float v = feat[c];
                const int j = s * 12 + c;
                sA[p * 232 + j] = bf16r(v);
                const float sv = __sinf(v), cv = __cosf(v);
                const unsigned s1 = (unsigned short)bf16r(sv);
                const unsigned s2 = (unsigned short)bf16r(2.f * sv * cv);
                const unsigned c1 = (unsigned short)bf16r(cv);
                const unsigned c2 = (unsigned short)bf16r(1.f - 2.f * sv * sv);
                *(unsigned*)(sA + p * 232 + 36 + 2 * j)  = s1 | (s2 << 16);
                *(unsigned*)(sA + p * 232 + 108 + 2 * j) = c1 | (c2 << 16);
            }
        }
    }
    __syncthreads();

    // ---- phase 4: featurenet  K=224 (7 kt), relu -> sB (stride 132) ----
    {
        bf16x8 b[7][2];
#pragma unroll
        for (int kt = 0; kt < 7; kt++)
#pragma unroll
            for (int n2 = 0; n2 < 2; n2++)
                b[kt][n2] = *(const bf16x8*)(fnw + (((ntb + n2) * 7 + kt) * 64 + lane) * 8);
        f32x4 acc[4][2];
#pragma unroll
        for (int mt = 0; mt < 4; mt++)
#pragma unroll
            for (int n2 = 0; n2 < 2; n2++) acc[mt][n2] = (f32x4){0.f, 0.f, 0.f, 0.f};
#pragma unroll
        for (int kt = 0; kt < 7; kt++) {
            bf16x8 a[4];
#pragma unroll
            for (int mt = 0; mt < 4; mt++)
                a[mt] = *(const bf16x8*)(sA + (mt * 16 + l15) * 232 + (kt * 4 + q) * 8);
#pragma unroll
            for (int n2 = 0; n2 < 2; n2++) {
#pragma unroll
                for (int mt = 0; mt < 4; mt++) acc[mt][n2] = MFMA16(a[mt], b[kt][n2], acc[mt][n2]);
            }
        }
#pragma unroll
        for (int n2 = 0; n2 < 2; n2++) {
            const int n0 = (ntb + n2) * 16 + l15;
            const float bv = fn_b0[n0];
#pragma unroll
            for (int mt = 0; mt < 4; mt++)
#pragma unroll
                for (int rg = 0; rg < 4; rg++)
                    sB[(mt * 16 + q * 4 + rg) * 132 + n0] = bf16r(fmaxf(acc[mt][n2][rg] + bv, 0.f));
        }
    }
    __syncthreads();

    // ---- phase 5: dec_wf  K=128 (4 kt), no relu -> sA (stride 136) ----
    {
        bf16x8 b[4][2];
#pragma unroll
        for (int kt = 0; kt < 4; kt++)
#pragma unroll
            for (int n2 = 0; n2 < 2; n2++)
                b[kt][n2] = *(const bf16x8*)(dwf + (((ntb + n2) * 4 + kt) * 64 + lane) * 8);
        f32x4 acc[4][2];
#pragma unroll
        for (int mt = 0; mt < 4; mt++)
#pragma unroll
            for (int n2 = 0; n2 < 2; n2++) acc[mt][n2] = (f32x4){0.f, 0.f, 0.f, 0.f};
#pragma unroll
        for (int kt = 0; kt < 4; kt++) {
            bf16x8 a[4];
#pragma unroll
            for (int mt = 0; mt < 4; mt++)
                a[mt] = *(const bf16x8*)(sB + (mt * 16 + l15) * 132 + (kt * 4 + q) * 8);
#pragma unroll
            for (int n2 = 0; n2 < 2; n2++) {
#pragma unroll
                for (int mt = 0; mt < 4; mt++) acc[mt][n2] = MFMA16(a[mt], b[kt][n2], acc[mt][n2]);
            }
        }
#pragma unroll
        for (int n2 = 0; n2 < 2; n2++) {
            const int n0 = (ntb + n2) * 16 + l15;
            const float bv = dec_bf[n0];
#pragma unroll
            for (int mt = 0; mt < 4; mt++)
#pragma unroll
                for (int rg = 0; rg < 4; rg++)
                    sA[(mt * 16 + q * 4 + rg) * 136 + n0] = bf16r(acc[mt][n2][rg] + bv);
        }
    }
    __syncthreads();

    // ---- phase 6: dec_w0  K=128 (vemb folded in sBe3), N=64 (1 nt/wave);
    //      also stage dec_w1/dec_b1 into dead sB space [short 4608..] ----
    {
        float* sDw = (float*)sB + 2304;   // byte 9216, beyond h2dec (4608 shorts)
        for (int i = tid; i < 195; i += 256)
            sDw[i] = (i < 192) ? dec_w1[i] : dec_b1[i - 192];
        bf16x8 b[4];
#pragma unroll
        for (int kt = 0; kt < 4; kt++)
            b[kt] = *(const bf16x8*)(dw0 + ((wv * 4 + kt) * 64 + lane) * 8);
        f32x4 acc[4];
#pragma unroll
        for (int mt = 0; mt < 4; mt++) acc[mt] = (f32x4){0.f, 0.f, 0.f, 0.f};
#pragma unroll
        for (int kt = 0; kt < 4; kt++) {
            bf16x8 a[4];
#pragma unroll
            for (int mt = 0; mt < 4; mt++)
                a[mt] = *(const bf16x8*)(sA + (mt * 16 + l15) * 136 + (kt * 4 + q) * 8);
#pragma unroll
            for (int mt = 0; mt < 4; mt++) acc[mt] = MFMA16(a[mt], b[kt], acc[mt]);
        }
        const int n0 = wv * 16 + l15;
        const float bv = sBe3[n0];
#pragma unroll
        for (int mt = 0; mt < 4; mt++)
#pragma unroll
            for (int rg = 0; rg < 4; rg++)
                sB[(mt * 16 + q * 4 + rg) * 72 + n0] = bf16r(fmaxf(acc[mt][rg] + bv, 0.f));
    }
    __syncthreads();

    // ---- phase 7: 64->3, sigmoid, weight, wave-reduce, store ----
    if (tid < 64) {
        const int p = tid;
        const float* sDw = (const float*)sB + 2304;
        float a0 = sDw[192], a1 = sDw[193], a2 = sDw[194];
#pragma unroll
        for (int g = 0; g < 8; g++) {
            const bf16x8 h = *(const bf16x8*)(sB + p * 72 + g * 8);
#pragma unroll
            for (int j = 0; j < 8; j++) {
                const float f = bf2f((unsigned short)h[j]);
                const int k = g * 8 + j;
                a0 += f * sDw[k * 3];
                a1 += f * sDw[k * 3 + 1];
                a2 += f * sDw[k * 3 + 2];
            }
        }
        const float wgt = sSm[p * 4 + 3];
        float r0 = wgt / (1.f + __expf(-a0));
        float r1 = wgt / (1.f + __expf(-a1));
        float r2 = wgt / (1.f + __expf(-a2));
#pragma unroll
        for (int off = 32; off >= 1; off >>= 1) {
            r0 += __shfl_down(r0, off);
            r1 += __shfl_down(r1, off);
            r2 += __shfl_down(r2, off);
        }
        if (p == 0) {
            const float av = sAiv[0];
            out[r * 3]     = r0 + av;
            out[r * 3 + 1] = r1 + av;
            out[r * 3 + 2] = r2 + av;
        }
    }
}

// ---------------------------------------------------------------------------
extern "C" void kernel_launch(void* const* d_in, const int* in_sizes, int n_in,
                              void* d_out, int out_size, void* d_ws, size_t ws_size,
                              hipStream_t stream)
{
    const float* ray_pts    = (const float*)d_in[0];
    const float* viewdirs   = (const float*)d_in[1];
    const float* frame_time = (const float*)d_in[2];
    float*       feature    = (float*)d_in[3];          // clobbered only in small-ws path
    const float* density    = (const float*)d_in[4];
    const float* tn_w0 = (const float*)d_in[5];  const float* tn_b0 = (const float*)d_in[6];
    const float* tn_w1 = (const float*)d_in[7];  const float* tn_b1 = (const float*)d_in[8];
    const float* dt_w0 = (const float*)d_in[9];  const float* dt_b0 = (const float*)d_in[10];
    const float* dt_w1 = (const float*)d_in[11]; const float* dt_b1 = (const float*)d_in[12];
    const float* dt_wo = (const float*)d_in[13]; const float* dt_bo = (const float*)d_in[14];
    const float* fn_w0 = (const float*)d_in[15]; const float* fn_b0 = (const float*)d_in[16];
    const float* dec_wf = (const float*)d_in[17]; const float* dec_bf = (const float*)d_in[18];
    const float* dec_w0 = (const float*)d_in[19]; const float* dec_b0 = (const float*)d_in[20];
    const float* dec_w1 = (const float*)d_in[21]; const float* dec_b1 = (const float*)d_in[22];
    (void)in_sizes; (void)n_in; (void)out_size;

    char* ws = (char*)d_ws;
    const bool big = ws_size >= (size_t)57598464;

    short *G, *p2, *p4, *B1 = nullptr, *B2 = nullptr;
    float* be0; short *dt0h, *dt0l, *dt1h, *dt1l, *fnw, *dwf, *dw0;

    if (big) {
        G    = (short*)(ws + 0);            // 128^3*12 bf16 = 50331648 B
        p2   = (short*)(ws + 50331648);
        p4   = (short*)(ws + 56623104);
        be0  = (float*)(ws + 57409536);
        dt0h = (short*)(ws + 57410048);
        dt0l = (short*)(ws + 57418240);
        dt1h = (short*)(ws + 57426432);
        dt1l = (short*)(ws + 57459200);
        fnw  = (short*)(ws + 57491968);
        dwf  = (short*)(ws + 57549312);
        dw0  = (short*)(ws + 57582080);     // ends 57598464
    } else {
        G    = (short*)feature;             // in-place in feature buffer
        B1   = (short*)(ws + 0);            // 3*GV bf16
        B2   = (short*)(ws + 12582912);     // 3*GVH bf16
        p2   = (short*)(ws + 0);            // reuse after transpose
        p4   = (short*)(ws + 6291456);
        be0  = (float*)(ws + 18874368);
        dt0h = (short*)(ws + 18874880);
        dt0l = (short*)(ws + 18883072);
        dt1h = (short*)(ws + 18891264);
        dt1l = (short*)(ws + 18924032);
        fnw  = (short*)(ws + 18956800);
        dwf  = (short*)(ws + 19014144);
        dw0  = (short*)(ws + 19046912);     // ends 19063296
    }

    pack_timenet_kernel<<<289, 256, 0, stream>>>(
        dt_w0, dt_w1, fn_w0, dec_wf, dec_w0,
        frame_time, tn_w0, tn_b0, tn_w1, tn_b1, dt_b0,
        dt0h, dt0l, dt1h, dt1l, fnw, dwf, dw0, be0);

    if (big) {
        transpose_big_kernel<<<2048, 256, 0, stream>>>(feature, G);
    } else {
        compact_kernel<<<9216, 256, 0, stream>>>(feature, B1, B2);
        transpose_kernel<<<1024, 256, 0, stream>>>(feature, B1, B2, G, 0);
        transpose_kernel<<<1024, 256, 0, stream>>>(feature, B1, B2, G, 1);
    }
    pool_kernel_t<1><<<1024, 256, 0, stream>>>(G, p2, 6);
    pool_kernel_t<1><<<128, 256, 0, stream>>>(p2, p4, 5);

    fused_kernel<<<4096, 256, 0, stream>>>(ray_pts, viewdirs, be0,
                                           dt0h, dt0l, dt1h, dt1l, dt_b1,
                                           dt_wo, dt_bo, density,
                                           G, p2, p4,
                                           fnw, fn_b0, dwf, dec_bf,
                                           dw0, dec_b0, dec_w0, dec_w1, dec_b1,
                                           (float*)d_out);
}

// Round 8
// 363.044 us; speedup vs baseline: 1.1211x; 1.0059x over previous
//
#include <hip/hip_runtime.h>
#include <math.h>

// ---------------------------------------------------------------------------
// VoxelMlp forward, round 15:
//  - fused: OPERAND SWAP in all MFMA phases. Compute D = W^T * X^T
//    (weights as A-operand, activations as B-operand). The packed weight
//    B-fragment layout is bit-identical to the A-fragment layout of W^T, and
//    the activation A-read is bit-identical to the B-read of X^T, so only the
//    MFMA argument order changes. Payoff: lane now holds col=point, rows
//    n=q*4+{0..3} (consecutive) -> epilogues write ONE ds_write_b64 (4 bf16,
//    same RNE bf16r, bit-exact) / ds_write_b128 (f32 phase 2) instead of 4
//    scalar b16/b32 stores; biases load as float4. Cuts the per-epilogue LDS
//    write count 4x (32 scalar -> 8 vector per wave) + address VALU.
//  - keeps r14's hoisted gather/density loads; prep unchanged.
// ---------------------------------------------------------------------------

#define N_RAYS 4096
#define ACT_SHIFT_F (-4.595119850134589f)
#define LOG1EM10 (-23.025850929940457f)
#define GV 2097152            // 128^3
#define GVH 1048576           // 128^3 / 2

typedef __attribute__((ext_vector_type(8))) short bf16x8;
typedef __attribute__((ext_vector_type(4))) float f32x4;
#define MFMA16(a, b, c) __builtin_amdgcn_mfma_f32_16x16x32_bf16(a, b, c, 0, 0, 0)

__device__ __forceinline__ short bf16r(float f) {   // RNE f32 -> bf16
    unsigned int u = __float_as_uint(f);
    u += 0x7FFF + ((u >> 16) & 1);
    return (short)(u >> 16);
}
__device__ __forceinline__ float bf2f(unsigned short s) {
    return __uint_as_float(((unsigned int)s) << 16);
}
__device__ __forceinline__ uint2 pack4(float4 x) {
    const unsigned a = (unsigned short)bf16r(x.x), b = (unsigned short)bf16r(x.y);
    const unsigned c = (unsigned short)bf16r(x.z), d = (unsigned short)bf16r(x.w);
    return make_uint2(a | (b << 16), c | (d << 16));
}
// pack f32x4 accumulator (+bias, optional relu) -> 4 bf16 in uint2
__device__ __forceinline__ uint2 packacc(f32x4 a, float4 bv, bool relu) {
    float v0 = a[0] + bv.x, v1 = a[1] + bv.y, v2 = a[2] + bv.z, v3 = a[3] + bv.w;
    if (relu) {
        v0 = fmaxf(v0, 0.f); v1 = fmaxf(v1, 0.f);
        v2 = fmaxf(v2, 0.f); v3 = fmaxf(v3, 0.f);
    }
    const unsigned a0 = (unsigned short)bf16r(v0), a1 = (unsigned short)bf16r(v1);
    const unsigned a2 = (unsigned short)bf16r(v2), a3 = (unsigned short)bf16r(v3);
    return make_uint2(a0 | (a1 << 16), a2 | (a3 << 16));
}

// store 4 voxels x 12 bf16 channels (96 B) as 6 uint4
__device__ __forceinline__ void store_vox4(short* __restrict__ dst,
                                           const unsigned short us[4][12]) {
    unsigned w[24];
#pragma unroll
    for (int j = 0; j < 24; j++) {
        const int a = (2 * j) / 12, ca = (2 * j) % 12;
        const int b = (2 * j + 1) / 12, cb = (2 * j + 1) % 12;
        w[j] = (unsigned)us[a][ca] | ((unsigned)us[b][cb] << 16);
    }
    uint4* o = (uint4*)dst;
#pragma unroll
    for (int t = 0; t < 6; t++)
        o[t] = make_uint4(w[4 * t], w[4 * t + 1], w[4 * t + 2], w[4 * t + 3]);
}

// ---------------------------------------------------------------------------
// pack weights (blocks 0..287) + timenet/bias-fold (block 288).
// ---------------------------------------------------------------------------
__global__ __launch_bounds__(256) void pack_timenet_kernel(
    const float* __restrict__ dt_w0, const float* __restrict__ dt_w1,
    const float* __restrict__ fn_w0, const float* __restrict__ dec_wf,
    const float* __restrict__ dec_w0,
    const float* __restrict__ ft,
    const float* __restrict__ tw0, const float* __restrict__ tb0,
    const float* __restrict__ tw1, const float* __restrict__ tb1,
    const float* __restrict__ dt_b0,
    short* __restrict__ dt0h, short* __restrict__ dt0l,
    short* __restrict__ dt1h, short* __restrict__ dt1l,
    short* __restrict__ fnw, short* __restrict__ dwf, short* __restrict__ dw0,
    float* __restrict__ be0)
{
    const int tid = threadIdx.x;
    if (blockIdx.x == 288) {
        __shared__ float sh[128];
        __shared__ float stf[60];
        const float t = ft[0];
        float te[9];
        te[0] = t;
        float fr = 1.f;
#pragma unroll
        for (int f = 0; f < 4; f++) {
            te[1 + f] = __sinf(t * fr);
            te[5 + f] = __cosf(t * fr);
            fr *= 2.f;
        }
        if (tid < 128) {
            float acc = tb0[tid];
#pragma unroll
            for (int k = 0; k < 9; k++) acc = fmaf(te[k], tw0[k * 128 + tid], acc);
            sh[tid] = fmaxf(acc, 0.f);
        }
        __syncthreads();
        if (tid < 60) {
            float acc = tb1[tid];
            for (int k = 0; k < 128; k++) acc = fmaf(sh[k], tw1[k * 60 + tid], acc);
            stf[tid] = acc;
        }
        __syncthreads();
        if (tid < 128) {
            float acc = dt_b0[tid];
            for (int k = 0; k < 60; k++) acc = fmaf(stf[k], dt_w0[(27 + k) * 128 + tid], acc);
            be0[tid] = acc;
        }
        return;
    }
    const int id = blockIdx.x * 256 + tid;   // < 73728
    const float* W; short* dh; short* dl = nullptr; int In, KT, Out, e;
    if (id < 4096)       { W = dt_w0;  dh = dt0h; dl = dt0l; In = 27;  KT = 1; Out = 128; e = id; }
    else if (id < 20480) { W = dt_w1;  dh = dt1h; dl = dt1l; In = 128; KT = 4; Out = 128; e = id - 4096; }
    else if (id < 49152) { W = fn_w0;  dh = fnw;             In = 207; KT = 7; Out = 128; e = id - 20480; }
    else if (id < 65536) { W = dec_wf; dh = dwf;             In = 128; KT = 4; Out = 128; e = id - 49152; }
    else                 { W = dec_w0; dh = dw0;             In = 128; KT = 4; Out = 64;  e = id - 65536; }
    const int j = e & 7, lane = (e >> 3) & 63, rest = e >> 9;
    const int kt = rest % KT, nt = rest / KT;
    const int n = nt * 16 + (lane & 15);
    const int k = kt * 32 + (lane >> 4) * 8 + j;
    const float v = (k < In) ? W[k * Out + n] : 0.f;
    const short hi = bf16r(v);
    dh[e] = hi;
    if (dl) dl[e] = bf16r(v - bf2f((unsigned short)hi));
}

// ---------------------------------------------------------------------------
// BIG path: direct transpose, 4 voxels/thread
// ---------------------------------------------------------------------------
__global__ __launch_bounds__(256) void transpose_big_kernel(
    const float* __restrict__ f, short* __restrict__ G)
{
    const int v = (blockIdx.x * 256 + threadIdx.x) * 4;   // < GV
    unsigned short us[4][12];
#pragma unroll
    for (int c = 0; c < 12; c++) {
        const float4 x = *(const float4*)(f + (size_t)c * GV + v);
        us[0][c] = (unsigned short)bf16r(x.x);
        us[1][c] = (unsigned short)bf16r(x.y);
        us[2][c] = (unsigned short)bf16r(x.z);
        us[3][c] = (unsigned short)bf16r(x.w);
    }
    store_vox4(G + (size_t)v * 12, us);
}

// ---------------------------------------------------------------------------
// SMALL-ws: bounce-compact (4 elems/thread) + 2-pass in-place transpose (4/thr)
// ---------------------------------------------------------------------------
__global__ __launch_bounds__(256) void compact_kernel(
    const float* __restrict__ f, short* __restrict__ B1, short* __restrict__ B2)
{
    const int id = (blockIdx.x * 256 + threadIdx.x) * 4;   // < 9437184
    if (id < 3 * GV) {
        *(uint2*)(B1 + id) = pack4(*(const float4*)(f + id));
    } else {
        const int e = id - 3 * GV;
        const int c = e >> 20;
        const int v2 = e & (GVH - 1);
        *(uint2*)(B2 + e) = pack4(*(const float4*)(f + (size_t)(3 + c) * GV + GVH + v2));
    }
}

__global__ __launch_bounds__(256) void transpose_kernel(
    const float* __restrict__ f, const short* __restrict__ B1,
    const short* __restrict__ B2, short* __restrict__ G, int pass)
{
    const int idx = (blockIdx.x * 256 + threadIdx.x) * 4;  // < GVH
    const int v = pass * GVH + idx;
    unsigned short us[4][12];
#pragma unroll
    for (int c = 0; c < 3; c++) {
        const uint2 b = *(const uint2*)(B1 + c * GV + v);
        us[0][c] = (unsigned short)(b.x & 0xFFFF); us[1][c] = (unsigned short)(b.x >> 16);
        us[2][c] = (unsigned short)(b.y & 0xFFFF); us[3][c] = (unsigned short)(b.y >> 16);
    }
    if (pass == 0) {
#pragma unroll
        for (int c = 3; c < 12; c++) {
            const float4 x = *(const float4*)(f + (size_t)c * GV + v);
            us[0][c] = (unsigned short)bf16r(x.x);
            us[1][c] = (unsigned short)bf16r(x.y);
            us[2][c] = (unsigned short)bf16r(x.z);
            us[3][c] = (unsigned short)bf16r(x.w);
        }
    } else {
#pragma unroll
        for (int c = 3; c < 6; c++) {
            const uint2 b = *(const uint2*)(B2 + (c - 3) * GVH + idx);
            us[0][c] = (unsigned short)(b.x & 0xFFFF); us[1][c] = (unsigned short)(b.x >> 16);
            us[2][c] = (unsigned short)(b.y & 0xFFFF); us[3][c] = (unsigned short)(b.y >> 16);
        }
#pragma unroll
        for (int c = 6; c < 12; c++) {
            const float4 x = *(const float4*)(f + (size_t)c * GV + v);
            us[0][c] = (unsigned short)bf16r(x.x);
            us[1][c] = (unsigned short)bf16r(x.y);
            us[2][c] = (unsigned short)bf16r(x.z);
            us[3][c] = (unsigned short)bf16r(x.w);
        }
    }
    store_vox4(G + (size_t)v * 12, us);
}

// ---------------------------------------------------------------------------
// 2x avg-pool, channel-last bf16 -> bf16, VPER output voxels/thread.
// ---------------------------------------------------------------------------
template<int VPER>
__global__ __launch_bounds__(256) void pool_kernel_t(
    const short* __restrict__ src, short* __restrict__ dst, int so)
{
    const int nout = 1 << so, nin = nout << 1;
    const int idx = (blockIdx.x * 256 + threadIdx.x) * VPER;
    const int z0 = idx & (nout - 1), y = (idx >> so) & (nout - 1), x = idx >> (2 * so);
    float acc[VPER][12];
#pragma unroll
    for (int k = 0; k < VPER; k++)
#pragma unroll
        for (int c = 0; c < 12; c++) acc[k][c] = 0.f;
#pragma unroll
    for (int i = 0; i < 2; i++)
#pragma unroll
        for (int j = 0; j < 2; j++) {
            const size_t roff = (size_t)(((2 * x + i) * nin + (2 * y + j)) * nin + 2 * z0) * 12;
            const uint4* R4 = (const uint4*)(src + roff);
            uint4 U[3 * VPER];
#pragma unroll
            for (int t = 0; t < 3 * VPER; t++) U[t] = R4[t];
            const unsigned* W = (const unsigned*)U;
#pragma unroll
            for (int k = 0; k < VPER; k++)
#pragma unroll
                for (int c = 0; c < 12; c++) {
                    const int s0 = 24 * k + c, s1 = 24 * k + 12 + c;
                    const unsigned u0 = W[s0 >> 1], u1 = W[s1 >> 1];
                    acc[k][c] += bf2f((unsigned short)((s0 & 1) ? (u0 >> 16) : (u0 & 0xFFFF)))
                               + bf2f((unsigned short)((s1 & 1) ? (u1 >> 16) : (u1 & 0xFFFF)));
                }
        }
    unsigned w[6 * VPER];
#pragma unroll
    for (int t = 0; t < 6 * VPER; t++) {
        const int e0 = 2 * t, e1 = 2 * t + 1;
        const unsigned short a = (unsigned short)bf16r(acc[e0 / 12][e0 % 12] * 0.125f);
        const unsigned short b = (unsigned short)bf16r(acc[e1 / 12][e1 % 12] * 0.125f);
        w[t] = (unsigned)a | ((unsigned)b << 16);
    }
    uint2* o = (uint2*)(dst + (size_t)idx * 12);
#pragma unroll
    for (int t = 0; t < 3 * VPER; t++)
        o[t] = make_uint2(w[2 * t], w[2 * t + 1]);
}

// ---------------------------------------------------------------------------
// fused (r9 structure + r14 hoisted gathers + operand-swapped MFMA):
// all layers computed as D = W^T X^T so the accumulator's 4 regs map to 4
// CONSECUTIVE output features of one point -> vectorized LDS epilogues.
// Block = 1 ray, 256 thr, LDS 53760 B -> 3 blocks/CU.
// ---------------------------------------------------------------------------
__global__ __launch_bounds__(256, 3) void fused_kernel(
    const float* __restrict__ ray_pts, const float* __restrict__ viewdirs,
    const float* __restrict__ be0,
    const short* __restrict__ dt0h, const short* __restrict__ dt0l,
    const short* __restrict__ dt1h, const short* __restrict__ dt1l,
    const float* __restrict__ dt_b1,
    const float* __restrict__ dt_wo, const float* __restrict__ dt_bo,
    const float* __restrict__ density,
    const short* __restrict__ g0, const short* __restrict__ p2g, const short* __restrict__ p4g,
    const short* __restrict__ fnw, const float* __restrict__ fn_b0,
    const short* __restrict__ dwf, const float* __restrict__ dec_bf,
    const short* __restrict__ dw0, const float* __restrict__ dec_b0,
    const float* __restrict__ dec_w0, const float* __restrict__ dec_w1,
    const float* __restrict__ dec_b1,
    float* __restrict__ out)
{
    // sA: emb (stride 72) -> h2 f32 (stride 132 f32) -> X (232) -> fl (136)
    // sB: h1 (stride 132) -> hf (stride 132) -> h2dec (stride 72) + sDw stage
    __shared__ __align__(16) short sA[16896];   // 33792 B
    __shared__ __align__(16) short sB[8448];    // 16896 B
    __shared__ __align__(16) float sWo[388];    // dt_wo + dt_bo
    __shared__ __align__(16) float sSm[256];    // [p*4+d]: pts_d xyz, d=3: weight
    __shared__ __align__(16) float sBe3[64];    // folded decoder-L0 bias
    __shared__ float sAiv[1];

    const int tid = threadIdx.x;
    const int r = blockIdx.x;
    const int p0g = r * 64;
    const int lane = tid & 63, wv = tid >> 6;
    const int l15 = lane & 15, q = lane >> 4;
    const int ntb = wv * 2;

    // ---- phase 0: preloads + folded decoder bias + deform embedding ----
    for (int i = tid; i < 384; i += 256) sWo[i] = dt_wo[i];
    if (tid < 3) sWo[384 + tid] = dt_bo[tid];
    if (tid < 64) {   // be3[n] = dec_b0[n] + vemb . dec_w0[128:149][n]
        const float v0 = viewdirs[r * 3], v1 = viewdirs[r * 3 + 1], v2 = viewdirs[r * 3 + 2];
        const float vv[3] = { v0, v1, v2 };
        float ve[21];
        ve[0] = v0; ve[1] = v1; ve[2] = v2;
#pragma unroll
        for (int d = 0; d < 3; d++) {
            float fq = 1.f;
#pragma unroll
            for (int f = 0; f < 3; f++) {
                ve[3 + d * 3 + f]  = __sinf(vv[d] * fq);
                ve[12 + d * 3 + f] = __cosf(vv[d] * fq);
                fq *= 2.f;
            }
        }
        float acc = dec_b0[tid];
#pragma unroll
        for (int k = 0; k < 21; k++) acc = fmaf(ve[k], dec_w0[(128 + k) * 64 + tid], acc);
        sBe3[tid] = acc;
    }
    {   // deform emb: thread (p=lane, grp=wv) -> cols wv*8..wv*8+7 (hi) / +32 (lo)
        const int p = lane;
        const int gp = p0g + p;
        const float pt[3] = { ray_pts[gp * 3], ray_pts[gp * 3 + 1], ray_pts[gp * 3 + 2] };
        float vals[8];
#pragma unroll
        for (int j = 0; j < 8; j++) {
            const int c = wv * 8 + j;
            float v;
            if (c < 3)       v = pt[c];
            else if (c < 15) { const int e = c - 3;  v = __sinf(pt[e >> 2] * (float)(1 << (e & 3))); }
            else if (c < 27) { const int e = c - 15; v = __cosf(pt[e >> 2] * (float)(1 << (e & 3))); }
            else             v = 0.f;
            vals[j] = v;
        }
        bf16x8 hi, lo;
#pragma unroll
        for (int j = 0; j < 8; j++) {
            const short h = bf16r(vals[j]);
            hi[j] = h;
            lo[j] = bf16r(vals[j] - bf2f((unsigned short)h));
        }
        *(bf16x8*)(sA + p * 72 + wv * 8) = hi;
        *(bf16x8*)(sA + p * 72 + 32 + wv * 8) = lo;
    }
    __syncthreads();

    // ---- phase 1: deform L1  K=32 (swapped: W^T as A, emb^T as B) ----
    {
        f32x4 acc[2][4];   // [wt][pt]
#pragma unroll
        for (int wt = 0; wt < 2; wt++)
#pragma unroll
            for (int pt = 0; pt < 4; pt++) acc[wt][pt] = (f32x4){0.f, 0.f, 0.f, 0.f};
        bf16x8 wh[2], wl[2];
#pragma unroll
        for (int wt = 0; wt < 2; wt++) {
            wh[wt] = *(const bf16x8*)(dt0h + ((ntb + wt) * 64 + lane) * 8);
            wl[wt] = *(const bf16x8*)(dt0l + ((ntb + wt) * 64 + lane) * 8);
        }
#pragma unroll
        for (int pt = 0; pt < 4; pt++) {
            const bf16x8 ah = *(const bf16x8*)(sA + (pt * 16 + l15) * 72 + q * 8);
            const bf16x8 al = *(const bf16x8*)(sA + (pt * 16 + l15) * 72 + 32 + q * 8);
#pragma unroll
            for (int wt = 0; wt < 2; wt++) {
                acc[wt][pt] = MFMA16(wh[wt], ah, acc[wt][pt]);
                acc[wt][pt] = MFMA16(wh[wt], al, acc[wt][pt]);
                acc[wt][pt] = MFMA16(wl[wt], ah, acc[wt][pt]);
            }
        }
#pragma unroll
        for (int wt = 0; wt < 2; wt++) {
            const int n0 = (ntb + wt) * 16 + q * 4;
            const float4 bv = *(const float4*)(be0 + n0);
#pragma unroll
            for (int pt = 0; pt < 4; pt++)
                *(uint2*)(sB + (pt * 16 + l15) * 132 + n0) = packacc(acc[wt][pt], bv, true);
        }
    }
    __syncthreads();

    // ---- phase 2: deform L2  K=128 (swapped), f32 float4 stores -> sA ----
    {
        bf16x8 wh[4][2], wl[4][2];
#pragma unroll
        for (int kt = 0; kt < 4; kt++)
#pragma unroll
            for (int wt = 0; wt < 2; wt++) {
                wh[kt][wt] = *(const bf16x8*)(dt1h + (((ntb + wt) * 4 + kt) * 64 + lane) * 8);
                wl[kt][wt] = *(const bf16x8*)(dt1l + (((ntb + wt) * 4 + kt) * 64 + lane) * 8);
            }
        f32x4 acc[2][4];
#pragma unroll
        for (int wt = 0; wt < 2; wt++)
#pragma unroll
            for (int pt = 0; pt < 4; pt++) acc[wt][pt] = (f32x4){0.f, 0.f, 0.f, 0.f};
#pragma unroll
        for (int kt = 0; kt < 4; kt++) {
            bf16x8 a[4];
#pragma unroll
            for (int pt = 0; pt < 4; pt++)
                a[pt] = *(const bf16x8*)(sB + (pt * 16 + l15) * 132 + (kt * 4 + q) * 8);
#pragma unroll
            for (int wt = 0; wt < 2; wt++) {
#pragma unroll
                for (int pt = 0; pt < 4; pt++) {
                    acc[wt][pt] = MFMA16(wh[kt][wt], a[pt], acc[wt][pt]);
                    acc[wt][pt] = MFMA16(wl[kt][wt], a[pt], acc[wt][pt]);
                }
            }
        }
        float* sF = (float*)sA;
#pragma unroll
        for (int wt = 0; wt < 2; wt++) {
            const int n0 = (ntb + wt) * 16 + q * 4;
            const float4 bv = *(const float4*)(dt_b1 + n0);
#pragma unroll
            for (int pt = 0; pt < 4; pt++) {
                float4 o;
                o.x = fmaxf(acc[wt][pt][0] + bv.x, 0.f);
                o.y = fmaxf(acc[wt][pt][1] + bv.y, 0.f);
                o.z = fmaxf(acc[wt][pt][2] + bv.z, 0.f);
                o.w = fmaxf(acc[wt][pt][3] + bv.w, 0.f);
                *(float4*)&sF[(pt * 16 + l15) * 132 + n0] = o;
            }
        }
    }
    __syncthreads();

    // ---- phase 3a: dx (192 threads: 64 pts x 3 dims) -> pts_d to sSm ----
    if (tid < 192) {
        const int p = tid & 63, d = tid >> 6;
        const float* sF = (const float*)sA;
        float a = sWo[384 + d];
        for (int k = 0; k < 128; k += 4) {
            const float4 h = *(const float4*)&sF[p * 132 + k];
            a += h.x * sWo[k * 3 + d] + h.y * sWo[(k + 1) * 3 + d]
               + h.z * sWo[(k + 2) * 3 + d] + h.w * sWo[(k + 3) * 3 + d];
        }
        sSm[p * 4 + d] = ray_pts[(p0g + p) * 3 + d] + a;
    }
    __syncthreads();

    // ---- phase 3b: wave0 = density+alpha+scan+pts-emb; waves1-3 = gathers ----
    {
        const int p = lane;
        const float pd[3] = { sSm[p * 4], sSm[p * 4 + 1], sSm[p * 4 + 2] };
        if (wv == 0) {
            int i0[3]; float fr[3];
#pragma unroll
            for (int d = 0; d < 3; d++) {
                float t = (pd[d] + 1.f) * 63.5f;
                t = fminf(fmaxf(t, 0.f), 127.f - 1e-4f);
                const int i = (int)t;
                i0[d] = i; fr[d] = t - (float)i;
            }
            // hoist all 8 density loads before any use
            float dlo[2][2], dhi[2][2];
#pragma unroll
            for (int dx = 0; dx < 2; dx++)
#pragma unroll
                for (int dy = 0; dy < 2; dy++) {
                    const float* b = &density[((i0[0] + dx) * 128 + i0[1] + dy) * 128 + i0[2]];
                    dlo[dx][dy] = b[0];
                    dhi[dx][dy] = b[1];
                }
            float dens = 0.f;
#pragma unroll
            for (int dx = 0; dx < 2; dx++)
#pragma unroll
                for (int dy = 0; dy < 2; dy++) {
                    const float wxy = (dx ? fr[0] : 1.f - fr[0]) * (dy ? fr[1] : 1.f - fr[1]);
                    dens += wxy * ((1.f - fr[2]) * dlo[dx][dy] + fr[2] * dhi[dx][dy]);
                }
            const float xs = dens + ACT_SHIFT_F;
            const float sp = fmaxf(xs, 0.f) + __logf(1.f + __expf(-fabsf(xs)));
            const float alpha = 1.f - __expf(-sp * 0.5f);
            const float lm = fmaxf(-sp * 0.5f, LOG1EM10);
            float v = lm;
#pragma unroll
            for (int d = 1; d < 64; d <<= 1) {
                const float o = __shfl_up(v, d);
                if (p >= d) v += o;
            }
            sSm[p * 4 + 3] = alpha * __expf(v - lm);
            if (p == 63) sAiv[0] = __expf(v);
            // pts_d embedding -> X cols 180..206, zero pad 207..223
            sA[p * 232 + 180] = bf16r(pd[0]);
            sA[p * 232 + 181] = bf16r(pd[1]);
            sA[p * 232 + 182] = bf16r(pd[2]);
#pragma unroll
            for (int d = 0; d < 3; d++) {
                float sv = __sinf(pd[d]), cv = __cosf(pd[d]);
#pragma unroll
                for (int f = 0; f < 4; f++) {
                    sA[p * 232 + 183 + d * 4 + f] = bf16r(sv);
                    sA[p * 232 + 195 + d * 4 + f] = bf16r(cv);
                    const float ns = 2.f * sv * cv;
                    cv = 1.f - 2.f * sv * sv;      // cos(2t) = 1 - 2 sin^2 t
                    sv = ns;                        // sin(2t) = 2 sin t cos t
                }
            }
            sA[p * 232 + 207] = 0;
            const bf16x8 zv = { 0, 0, 0, 0, 0, 0, 0, 0 };
            *(bf16x8*)(sA + p * 232 + 208) = zv;
            *(bf16x8*)(sA + p * 232 + 216) = zv;
        } else {
            const int s = wv - 1;
            const int n = (s == 0) ? 128 : ((s == 1) ? 64 : 32);
            const short* g = (s == 0) ? g0 : ((s == 1) ? p2g : p4g);
            const float dim = (float)(n - 1);
            int i0[3]; float fr[3];
#pragma unroll
            for (int d = 0; d < 3; d++) {
                float t = (pd[d] + 1.f) * 0.5f * dim;
                t = fminf(fmaxf(t, 0.f), dim - 1e-4f);
                const int i = (int)t;
                i0[d] = i; fr[d] = t - (float)i;
            }
            // issue ALL 24 corner loads first (8 corners x 3 ushort4) so the
            // fetch latencies overlap; then accumulate.
            ushort4 cr[2][2][2][3];
#pragma unroll
            for (int dx = 0; dx < 2; dx++)
#pragma unroll
                for (int dy = 0; dy < 2; dy++)
#pragma unroll
                    for (int dz = 0; dz < 2; dz++) {
                        const int vox = ((i0[0] + dx) * n + i0[1] + dy) * n + i0[2] + dz;
                        const ushort4* qp = (const ushort4*)(g + (size_t)vox * 12);
                        cr[dx][dy][dz][0] = qp[0];
                        cr[dx][dy][dz][1] = qp[1];
                        cr[dx][dy][dz][2] = qp[2];
                    }
            float feat[12];
#pragma unroll
            for (int c = 0; c < 12; c++) feat[c] = 0.f;
#pragma unroll
            for (int dx = 0; dx < 2; dx++)
#pragma unroll
                for (int dy = 0; dy < 2; dy++)
#pragma unroll
                    for (int dz = 0; dz < 2; dz++) {
                        const float wc = (dx ? fr[0] : 1.f - fr[0]) *
                                         (dy ? fr[1] : 1.f - fr[1]) *
                                         (dz ? fr[2] : 1.f - fr[2]);
                        const ushort4 a = cr[dx][dy][dz][0];
                        const ushort4 b = cr[dx][dy][dz][1];
                        const ushort4 c2 = cr[dx][dy][dz][2];
                        feat[0]  += wc * bf2f(a.x);  feat[1]  += wc * bf2f(a.y);
                        feat[2]  += wc * bf2f(a.z);  feat[3]  += wc * bf2f(a.w);
                        feat[4]  += wc * bf2f(b.x);  feat[5]  += wc * bf2f(b.y);
                        feat[6]  += wc * bf2f(b.z);  feat[7]  += wc * bf2f(b.w);
                        feat[8]  += wc * bf2f(c2.x); feat[9]  += wc * bf2f(c2.y);
                        feat[10] += wc * bf2f(c2.z); feat[11] += wc * bf2f(c2.w);
                    }
#pragma unroll
            for (int c = 0; c < 12; c++) {
                const float v = feat[c];
                const int j = s * 12 + c;
                sA[p * 232 + j] = bf16r(v);
                const float sv = __sinf(v), cv = __cosf(v);
                const unsigned s1 = (unsigned short)bf16r(sv);
                const unsigned s2 = (unsigned short)bf16r(2.f * sv * cv);
                const unsigned c1 = (unsigned short)bf16r(cv);
                const unsigned c2 = (unsigned short)bf16r(1.f - 2.f * sv * sv);
                *(unsigned*)(sA + p * 232 + 36 + 2 * j)  = s1 | (s2 << 16);
                *(unsigned*)(sA + p * 232 + 108 + 2 * j) = c1 | (c2 << 16);
            }
        }
    }
    __syncthreads();

    // ---- phase 4: featurenet  K=224 (swapped), relu -> sB (stride 132) ----
    {
        bf16x8 w[7][2];
#pragma unroll
        for (int kt = 0; kt < 7; kt++)
#pragma unroll
            for (int wt = 0; wt < 2; wt++)
                w[kt][wt] = *(const bf16x8*)(fnw + (((ntb + wt) * 7 + kt) * 64 + lane) * 8);
        f32x4 acc[2][4];
#pragma unroll
        for (int wt = 0; wt < 2; wt++)
#pragma unroll
            for (int pt = 0; pt < 4; pt++) acc[wt][pt] = (f32x4){0.f, 0.f, 0.f, 0.f};
#pragma unroll
        for (int kt = 0; kt < 7; kt++) {
            bf16x8 a[4];
#pragma unroll
            for (int pt = 0; pt < 4; pt++)
                a[pt] = *(const bf16x8*)(sA + (pt * 16 + l15) * 232 + (kt * 4 + q) * 8);
#pragma unroll
            for (int wt = 0; wt < 2; wt++) {
#pragma unroll
                for (int pt = 0; pt < 4; pt++) acc[wt][pt] = MFMA16(w[kt][wt], a[pt], acc[wt][pt]);
            }
        }
#pragma unroll
        for (int wt = 0; wt < 2; wt++) {
            const int n0 = (ntb + wt) * 16 + q * 4;
            const float4 bv = *(const float4*)(fn_b0 + n0);
#pragma unroll
            for (int pt = 0; pt < 4; pt++)
                *(uint2*)(sB + (pt * 16 + l15) * 132 + n0) = packacc(acc[wt][pt], bv, true);
        }
    }
    __syncthreads();

    // ---- phase 5: dec_wf  K=128 (swapped), no relu -> sA (stride 136) ----
    {
        bf16x8 w[4][2];
#pragma unroll
        for (int kt = 0; kt < 4; kt++)
#pragma unroll
            for (int wt = 0; wt < 2; wt++)
                w[kt][wt] = *(const bf16x8*)(dwf + (((ntb + wt) * 4 + kt) * 64 + lane) * 8);
        f32x4 acc[2][4];
#pragma unroll
        for (int wt = 0; wt < 2; wt++)
#pragma unroll
            for (int pt = 0; pt < 4; pt++) acc[wt][pt] = (f32x4){0.f, 0.f, 0.f, 0.f};
#pragma unroll
        for (int kt = 0; kt < 4; kt++) {
            bf16x8 a[4];
#pragma unroll
            for (int pt = 0; pt < 4; pt++)
                a[pt] = *(const bf16x8*)(sB + (pt * 16 + l15) * 132 + (kt * 4 + q) * 8);
#pragma unroll
            for (int wt = 0; wt < 2; wt++) {
#pragma unroll
                for (int pt = 0; pt < 4; pt++) acc[wt][pt] = MFMA16(w[kt][wt], a[pt], acc[wt][pt]);
            }
        }
#pragma unroll
        for (int wt = 0; wt < 2; wt++) {
            const int n0 = (ntb + wt) * 16 + q * 4;
            const float4 bv = *(const float4*)(dec_bf + n0);
#pragma unroll
            for (int pt = 0; pt < 4; pt++)
                *(uint2*)(sA + (pt * 16 + l15) * 136 + n0) = packacc(acc[wt][pt], bv, false);
        }
    }
    __syncthreads();

    // ---- phase 6: dec_w0  K=128 (swapped; vemb folded in sBe3), N=64;
    //      also stage dec_w1/dec_b1 into dead sB space [short 4608..] ----
    {
        float* sDw = (float*)sB + 2304;   // byte 9216, beyond h2dec (4608 shorts)
        for (int i = tid; i < 195; i += 256)
            sDw[i] = (i < 192) ? dec_w1[i] : dec_b1[i - 192];
        bf16x8 w[4];
#pragma unroll
        for (int kt = 0; kt < 4; kt++)
            w[kt] = *(const bf16x8*)(dw0 + ((wv * 4 + kt) * 64 + lane) * 8);
        f32x4 acc[4];
#pragma unroll
        for (int pt = 0; pt < 4; pt++) acc[pt] = (f32x4){0.f, 0.f, 0.f, 0.f};
#pragma unroll
        for (int kt = 0; kt < 4; kt++) {
            bf16x8 a[4];
#pragma unroll
            for (int pt = 0; pt < 4; pt++)
                a[pt] = *(const bf16x8*)(sA + (pt * 16 + l15) * 136 + (kt * 4 + q) * 8);
#pragma unroll
            for (int pt = 0; pt < 4; pt++) acc[pt] = MFMA16(w[kt], a[pt], acc[pt]);
        }
        const int n0 = wv * 16 + q * 4;
        const float4 bv = *(const float4*)(sBe3 + n0);
#pragma unroll
        for (int pt = 0; pt < 4; pt++)
            *(uint2*)(sB + (pt * 16 + l15) * 72 + n0) = packacc(acc[pt], bv, true);
    }
    __syncthreads();

    // ---- phase 7: 64->3, sigmoid, weight, wave-reduce, store ----
    if (tid < 64) {
        const int p = tid;
        const float* sDw = (const float*)sB + 2304;
        float a0 = sDw[192], a1 = sDw[193], a2 = sDw[194];
#pragma unroll
        for (int g = 0; g < 8; g++) {
            const bf16x8 h = *(const bf16x8*)(sB + p * 72 + g * 8);
#pragma unroll
            for (int j = 0; j < 8; j++) {
                const float f = bf2f((unsigned short)h[j]);
                const int k = g * 8 + j;
                a0 += f * sDw[k * 3];
                a1 += f * sDw[k * 3 + 1];
                a2 += f * sDw[k * 3 + 2];
            }
        }
        const float wgt = sSm[p * 4 + 3];
        float r0 = wgt / (1.f + __expf(-a0));
        float r1 = wgt / (1.f + __expf(-a1));
        float r2 = wgt / (1.f + __expf(-a2));
#pragma unroll
        for (int off = 32; off >= 1; off >>= 1) {
            r0 += __shfl_down(r0, off);
            r1 += __shfl_down(r1, off);
            r2 += __shfl_down(r2, off);
        }
        if (p == 0) {
            const float av = sAiv[0];
            out[r * 3]     = r0 + av;
            out[r * 3 + 1] = r1 + av;
            out[r * 3 + 2] = r2 + av;
        }
    }
}

// ---------------------------------------------------------------------------
extern "C" void kernel_launch(void* const* d_in, const int* in_sizes, int n_in,
                              void* d_out, int out_size, void* d_ws, size_t ws_size,
                              hipStream_t stream)
{
    const float* ray_pts    = (const float*)d_in[0];
    const float* viewdirs   = (const float*)d_in[1];
    const float* frame_time = (const float*)d_in[2];
    float*       feature    = (float*)d_in[3];          // clobbered only in small-ws path
    const float* density    = (const float*)d_in[4];
    const float* tn_w0 = (const float*)d_in[5];  const float* tn_b0 = (const float*)d_in[6];
    const float* tn_w1 = (const float*)d_in[7];  const float* tn_b1 = (const float*)d_in[8];
    const float* dt_w0 = (const float*)d_in[9];  const float* dt_b0 = (const float*)d_in[10];
    const float* dt_w1 = (const float*)d_in[11]; const float* dt_b1 = (const float*)d_in[12];
    const float* dt_wo = (const float*)d_in[13]; const float* dt_bo = (const float*)d_in[14];
    const float* fn_w0 = (const float*)d_in[15]; const float* fn_b0 = (const float*)d_in[16];
    const float* dec_wf = (const float*)d_in[17]; const float* dec_bf = (const float*)d_in[18];
    const float* dec_w0 = (const float*)d_in[19]; const float* dec_b0 = (const float*)d_in[20];
    const float* dec_w1 = (const float*)d_in[21]; const float* dec_b1 = (const float*)d_in[22];
    (void)in_sizes; (void)n_in; (void)out_size;

    char* ws = (char*)d_ws;
    const bool big = ws_size >= (size_t)57598464;

    short *G, *p2, *p4, *B1 = nullptr, *B2 = nullptr;
    float* be0; short *dt0h, *dt0l, *dt1h, *dt1l, *fnw, *dwf, *dw0;

    if (big) {
        G    = (short*)(ws + 0);            // 128^3*12 bf16 = 50331648 B
        p2   = (short*)(ws + 50331648);
        p4   = (short*)(ws + 56623104);
        be0  = (float*)(ws + 57409536);
        dt0h = (short*)(ws + 57410048);
        dt0l = (short*)(ws + 57418240);
        dt1h = (short*)(ws + 57426432);
        dt1l = (short*)(ws + 57459200);
        fnw  = (short*)(ws + 57491968);
        dwf  = (short*)(ws + 57549312);
        dw0  = (short*)(ws + 57582080);     // ends 57598464
    } else {
        G    = (short*)feature;             // in-place in feature buffer
        B1   = (short*)(ws + 0);            // 3*GV bf16
        B2   = (short*)(ws + 12582912);     // 3*GVH bf16
        p2   = (short*)(ws + 0);            // reuse after transpose
        p4   = (short*)(ws + 6291456);
        be0  = (float*)(ws + 18874368);
        dt0h = (short*)(ws + 18874880);
        dt0l = (short*)(ws + 18883072);
        dt1h = (short*)(ws + 18891264);
        dt1l = (short*)(ws + 18924032);
        fnw  = (short*)(ws + 18956800);
        dwf  = (short*)(ws + 19014144);
        dw0  = (short*)(ws + 19046912);     // ends 19063296
    }

    pack_timenet_kernel<<<289, 256, 0, stream>>>(
        dt_w0, dt_w1, fn_w0, dec_wf, dec_w0,
        frame_time, tn_w0, tn_b0, tn_w1, tn_b1, dt_b0,
        dt0h, dt0l, dt1h, dt1l, fnw, dwf, dw0, be0);

    if (big) {
        transpose_big_kernel<<<2048, 256, 0, stream>>>(feature, G);
    } else {
        compact_kernel<<<9216, 256, 0, stream>>>(feature, B1, B2);
        transpose_kernel<<<1024, 256, 0, stream>>>(feature, B1, B2, G, 0);
        transpose_kernel<<<1024, 256, 0, stream>>>(feature, B1, B2, G, 1);
    }
    pool_kernel_t<1><<<1024, 256, 0, stream>>>(G, p2, 6);
    pool_kernel_t<1><<<128, 256, 0, stream>>>(p2, p4, 5);

    fused_kernel<<<4096, 256, 0, stream>>>(ray_pts, viewdirs, be0,
                                           dt0h, dt0l, dt1h, dt1l, dt_b1,
                                           dt_wo, dt_bo, density,
                                           G, p2, p4,
                                           fnw, fn_b0, dwf, dec_bf,
                                           dw0, dec_b0, dec_w0, dec_w1, dec_b1,
                                           (float*)d_out);
}

// Round 9
// 360.775 us; speedup vs baseline: 1.1282x; 1.0063x over previous
//
#include <hip/hip_runtime.h>
#include <math.h>

// ---------------------------------------------------------------------------
// VoxelMlp forward, round 16:
//  - fused unchanged (r15: operand-swap + hoisted gathers, 142µs best).
//  - prep (big path): transpose + pool1 + pool2 merged into ONE
//    transpose_pool_kernel WITHOUT atomics (r12's failure mode). Block =
//    8x8x64 voxels; thread owns a 2x2x4 brick -> exclusively owns 2 p2 cells
//    (register accumulation, own LDS slots), 64 threads reduce LDS -> p4.
//    Reads keep float4 (256B segments), G writes keep store_vox4 (96B x 16
//    lanes contiguous). Kills pool1's 50MB G re-read + pool2 re-read + 2
//    launch gaps. Pool sums in pre-round f32 (closer to reference; r12
//    verified numerics pass).
//  - small-ws path unchanged.
// ---------------------------------------------------------------------------

#define N_RAYS 4096
#define ACT_SHIFT_F (-4.595119850134589f)
#define LOG1EM10 (-23.025850929940457f)
#define GV 2097152            // 128^3
#define GVH 1048576           // 128^3 / 2

typedef __attribute__((ext_vector_type(8))) short bf16x8;
typedef __attribute__((ext_vector_type(4))) float f32x4;
#define MFMA16(a, b, c) __builtin_amdgcn_mfma_f32_16x16x32_bf16(a, b, c, 0, 0, 0)

__device__ __forceinline__ short bf16r(float f) {   // RNE f32 -> bf16
    unsigned int u = __float_as_uint(f);
    u += 0x7FFF + ((u >> 16) & 1);
    return (short)(u >> 16);
}
__device__ __forceinline__ float bf2f(unsigned short s) {
    return __uint_as_float(((unsigned int)s) << 16);
}
__device__ __forceinline__ uint2 pack4(float4 x) {
    const unsigned a = (unsigned short)bf16r(x.x), b = (unsigned short)bf16r(x.y);
    const unsigned c = (unsigned short)bf16r(x.z), d = (unsigned short)bf16r(x.w);
    return make_uint2(a | (b << 16), c | (d << 16));
}
// pack f32x4 accumulator (+bias, optional relu) -> 4 bf16 in uint2
__device__ __forceinline__ uint2 packacc(f32x4 a, float4 bv, bool relu) {
    float v0 = a[0] + bv.x, v1 = a[1] + bv.y, v2 = a[2] + bv.z, v3 = a[3] + bv.w;
    if (relu) {
        v0 = fmaxf(v0, 0.f); v1 = fmaxf(v1, 0.f);
        v2 = fmaxf(v2, 0.f); v3 = fmaxf(v3, 0.f);
    }
    const unsigned a0 = (unsigned short)bf16r(v0), a1 = (unsigned short)bf16r(v1);
    const unsigned a2 = (unsigned short)bf16r(v2), a3 = (unsigned short)bf16r(v3);
    return make_uint2(a0 | (a1 << 16), a2 | (a3 << 16));
}

// store 4 voxels x 12 bf16 channels (96 B) as 6 uint4
__device__ __forceinline__ void store_vox4(short* __restrict__ dst,
                                           const unsigned short us[4][12]) {
    unsigned w[24];
#pragma unroll
    for (int j = 0; j < 24; j++) {
        const int a = (2 * j) / 12, ca = (2 * j) % 12;
        const int b = (2 * j + 1) / 12, cb = (2 * j + 1) % 12;
        w[j] = (unsigned)us[a][ca] | ((unsigned)us[b][cb] << 16);
    }
    uint4* o = (uint4*)dst;
#pragma unroll
    for (int t = 0; t < 6; t++)
        o[t] = make_uint4(w[4 * t], w[4 * t + 1], w[4 * t + 2], w[4 * t + 3]);
}

// ---------------------------------------------------------------------------
// pack weights (blocks 0..287) + timenet/bias-fold (block 288).
// ---------------------------------------------------------------------------
__global__ __launch_bounds__(256) void pack_timenet_kernel(
    const float* __restrict__ dt_w0, const float* __restrict__ dt_w1,
    const float* __restrict__ fn_w0, const float* __restrict__ dec_wf,
    const float* __restrict__ dec_w0,
    const float* __restrict__ ft,
    const float* __restrict__ tw0, const float* __restrict__ tb0,
    const float* __restrict__ tw1, const float* __restrict__ tb1,
    const float* __restrict__ dt_b0,
    short* __restrict__ dt0h, short* __restrict__ dt0l,
    short* __restrict__ dt1h, short* __restrict__ dt1l,
    short* __restrict__ fnw, short* __restrict__ dwf, short* __restrict__ dw0,
    float* __restrict__ be0)
{
    const int tid = threadIdx.x;
    if (blockIdx.x == 288) {
        __shared__ float sh[128];
        __shared__ float stf[60];
        const float t = ft[0];
        float te[9];
        te[0] = t;
        float fr = 1.f;
#pragma unroll
        for (int f = 0; f < 4; f++) {
            te[1 + f] = __sinf(t * fr);
            te[5 + f] = __cosf(t * fr);
            fr *= 2.f;
        }
        if (tid < 128) {
            float acc = tb0[tid];
#pragma unroll
            for (int k = 0; k < 9; k++) acc = fmaf(te[k], tw0[k * 128 + tid], acc);
            sh[tid] = fmaxf(acc, 0.f);
        }
        __syncthreads();
        if (tid < 60) {
            float acc = tb1[tid];
            for (int k = 0; k < 128; k++) acc = fmaf(sh[k], tw1[k * 60 + tid], acc);
            stf[tid] = acc;
        }
        __syncthreads();
        if (tid < 128) {
            float acc = dt_b0[tid];
            for (int k = 0; k < 60; k++) acc = fmaf(stf[k], dt_w0[(27 + k) * 128 + tid], acc);
            be0[tid] = acc;
        }
        return;
    }
    const int id = blockIdx.x * 256 + tid;   // < 73728
    const float* W; short* dh; short* dl = nullptr; int In, KT, Out, e;
    if (id < 4096)       { W = dt_w0;  dh = dt0h; dl = dt0l; In = 27;  KT = 1; Out = 128; e = id; }
    else if (id < 20480) { W = dt_w1;  dh = dt1h; dl = dt1l; In = 128; KT = 4; Out = 128; e = id - 4096; }
    else if (id < 49152) { W = fn_w0;  dh = fnw;             In = 207; KT = 7; Out = 128; e = id - 20480; }
    else if (id < 65536) { W = dec_wf; dh = dwf;             In = 128; KT = 4; Out = 128; e = id - 49152; }
    else                 { W = dec_w0; dh = dw0;             In = 128; KT = 4; Out = 64;  e = id - 65536; }
    const int j = e & 7, lane = (e >> 3) & 63, rest = e >> 9;
    const int kt = rest % KT, nt = rest / KT;
    const int n = nt * 16 + (lane & 15);
    const int k = kt * 32 + (lane >> 4) * 8 + j;
    const float v = (k < In) ? W[k * Out + n] : 0.f;
    const short hi = bf16r(v);
    dh[e] = hi;
    if (dl) dl[e] = bf16r(v - bf2f((unsigned short)hi));
}

// ---------------------------------------------------------------------------
// BIG path: merged transpose + pool1 + pool2, NO atomics.
// 512 blocks, block = 8x8x64 voxels; thread owns a 2x2x4 brick ->
// 2 exclusively-owned p2 cells; 64 threads reduce LDS -> p4.
// ---------------------------------------------------------------------------
__global__ __launch_bounds__(256) void transpose_pool_kernel(
    const float* __restrict__ f, short* __restrict__ G,
    short* __restrict__ p2, short* __restrict__ p4)
{
    __shared__ float sP2[512 * 12];   // 24576 B
    const int tid = threadIdx.x;
    const int b = blockIdx.x;         // 512 = 16(x) * 16(y) * 2(z)
    const int bz = b & 1, by = (b >> 1) & 15, bx = b >> 5;
    const int tz = tid & 15, ty = (tid >> 4) & 3, tx = tid >> 6;
    const int gx = bx * 8 + tx * 2, gy = by * 8 + ty * 2, gz = bz * 64 + tz * 4;

    float pa[2][12];                  // 2 p2 cells (z-pair), pre-round f32 sums
#pragma unroll
    for (int k = 0; k < 2; k++)
#pragma unroll
        for (int c = 0; c < 12; c++) pa[k][c] = 0.f;

#pragma unroll
    for (int i = 0; i < 2; i++)
#pragma unroll
        for (int j = 0; j < 2; j++) {
            const int v = ((gx + i) * 128 + (gy + j)) * 128 + gz;
            unsigned short us[4][12];
#pragma unroll
            for (int c = 0; c < 12; c++) {
                const float4 w = *(const float4*)(f + (size_t)c * GV + v);
                us[0][c] = (unsigned short)bf16r(w.x);
                us[1][c] = (unsigned short)bf16r(w.y);
                us[2][c] = (unsigned short)bf16r(w.z);
                us[3][c] = (unsigned short)bf16r(w.w);
                pa[0][c] += w.x + w.y;
                pa[1][c] += w.z + w.w;
            }
            store_vox4(G + (size_t)v * 12, us);
        }

    // p2: own cells -> global (bf16) + LDS (f32, for p4)
    const int px = bx * 4 + tx, py = by * 4 + ty;
    const int pz0 = bz * 32 + tz * 2;
#pragma unroll
    for (int k = 0; k < 2; k++) {
        float vals[12];
#pragma unroll
        for (int c = 0; c < 12; c++) vals[c] = pa[k][c] * 0.125f;
        const int gp = (px * 64 + py) * 64 + pz0 + k;
        unsigned w6[6];
#pragma unroll
        for (int t = 0; t < 6; t++)
            w6[t] = (unsigned)(unsigned short)bf16r(vals[2 * t]) |
                    ((unsigned)(unsigned short)bf16r(vals[2 * t + 1]) << 16);
        uint2* o = (uint2*)(p2 + (size_t)gp * 12);
        o[0] = make_uint2(w6[0], w6[1]);
        o[1] = make_uint2(w6[2], w6[3]);
        o[2] = make_uint2(w6[4], w6[5]);
        const int lc = (tx * 4 + ty) * 32 + tz * 2 + k;
#pragma unroll
        for (int c = 0; c < 12; c++) sP2[lc * 12 + c] = vals[c];
    }
    __syncthreads();

    // p4: 2x2x16 = 64 cells, each the mean of 2x2x2 p2 cells (all in-block)
    if (tid < 64) {
        const int qz = tid & 15, qy = (tid >> 4) & 1, qx = tid >> 5;
        float acc[12];
#pragma unroll
        for (int c = 0; c < 12; c++) acc[c] = 0.f;
#pragma unroll
        for (int i = 0; i < 2; i++)
#pragma unroll
            for (int j = 0; j < 2; j++)
#pragma unroll
                for (int k = 0; k < 2; k++) {
                    const int lc = ((qx * 2 + i) * 4 + (qy * 2 + j)) * 32 + qz * 2 + k;
#pragma unroll
                    for (int c = 0; c < 12; c++) acc[c] += sP2[lc * 12 + c];
                }
        const int gp = ((bx * 2 + qx) * 32 + by * 2 + qy) * 32 + bz * 16 + qz;
        unsigned w6[6];
#pragma unroll
        for (int t = 0; t < 6; t++) {
            const float a = acc[2 * t] * 0.125f;
            const float b2 = acc[2 * t + 1] * 0.125f;
            w6[t] = (unsigned)(unsigned short)bf16r(a) |
                    ((unsigned)(unsigned short)bf16r(b2) << 16);
        }
        uint2* o = (uint2*)(p4 + (size_t)gp * 12);
        o[0] = make_uint2(w6[0], w6[1]);
        o[1] = make_uint2(w6[2], w6[3]);
        o[2] = make_uint2(w6[4], w6[5]);
    }
}

// ---------------------------------------------------------------------------
// SMALL-ws: bounce-compact (4 elems/thread) + 2-pass in-place transpose (4/thr)
// ---------------------------------------------------------------------------
__global__ __launch_bounds__(256) void compact_kernel(
    const float* __restrict__ f, short* __restrict__ B1, short* __restrict__ B2)
{
    const int id = (blockIdx.x * 256 + threadIdx.x) * 4;   // < 9437184
    if (id < 3 * GV) {
        *(uint2*)(B1 + id) = pack4(*(const float4*)(f + id));
    } else {
        const int e = id - 3 * GV;
        const int c = e >> 20;
        const int v2 = e & (GVH - 1);
        *(uint2*)(B2 + e) = pack4(*(const float4*)(f + (size_t)(3 + c) * GV + GVH + v2));
    }
}

__global__ __launch_bounds__(256) void transpose_kernel(
    const float* __restrict__ f, const short* __restrict__ B1,
    const short* __restrict__ B2, short* __restrict__ G, int pass)
{
    const int idx = (blockIdx.x * 256 + threadIdx.x) * 4;  // < GVH
    const int v = pass * GVH + idx;
    unsigned short us[4][12];
#pragma unroll
    for (int c = 0; c < 3; c++) {
        const uint2 b = *(const uint2*)(B1 + c * GV + v);
        us[0][c] = (unsigned short)(b.x & 0xFFFF); us[1][c] = (unsigned short)(b.x >> 16);
        us[2][c] = (unsigned short)(b.y & 0xFFFF); us[3][c] = (unsigned short)(b.y >> 16);
    }
    if (pass == 0) {
#pragma unroll
        for (int c = 3; c < 12; c++) {
            const float4 x = *(const float4*)(f + (size_t)c * GV + v);
            us[0][c] = (unsigned short)bf16r(x.x);
            us[1][c] = (unsigned short)bf16r(x.y);
            us[2][c] = (unsigned short)bf16r(x.z);
            us[3][c] = (unsigned short)bf16r(x.w);
        }
    } else {
#pragma unroll
        for (int c = 3; c < 6; c++) {
            const uint2 b = *(const uint2*)(B2 + (c - 3) * GVH + idx);
            us[0][c] = (unsigned short)(b.x & 0xFFFF); us[1][c] = (unsigned short)(b.x >> 16);
            us[2][c] = (unsigned short)(b.y & 0xFFFF); us[3][c] = (unsigned short)(b.y >> 16);
        }
#pragma unroll
        for (int c = 6; c < 12; c++) {
            const float4 x = *(const float4*)(f + (size_t)c * GV + v);
            us[0][c] = (unsigned short)bf16r(x.x);
            us[1][c] = (unsigned short)bf16r(x.y);
            us[2][c] = (unsigned short)bf16r(x.z);
            us[3][c] = (unsigned short)bf16r(x.w);
        }
    }
    store_vox4(G + (size_t)v * 12, us);
}

// ---------------------------------------------------------------------------
// 2x avg-pool, channel-last bf16 -> bf16, VPER output voxels/thread.
// (small-ws path only)
// ---------------------------------------------------------------------------
template<int VPER>
__global__ __launch_bounds__(256) void pool_kernel_t(
    const short* __restrict__ src, short* __restrict__ dst, int so)
{
    const int nout = 1 << so, nin = nout << 1;
    const int idx = (blockIdx.x * 256 + threadIdx.x) * VPER;
    const int z0 = idx & (nout - 1), y = (idx >> so) & (nout - 1), x = idx >> (2 * so);
    float acc[VPER][12];
#pragma unroll
    for (int k = 0; k < VPER; k++)
#pragma unroll
        for (int c = 0; c < 12; c++) acc[k][c] = 0.f;
#pragma unroll
    for (int i = 0; i < 2; i++)
#pragma unroll
        for (int j = 0; j < 2; j++) {
            const size_t roff = (size_t)(((2 * x + i) * nin + (2 * y + j)) * nin + 2 * z0) * 12;
            const uint4* R4 = (const uint4*)(src + roff);
            uint4 U[3 * VPER];
#pragma unroll
            for (int t = 0; t < 3 * VPER; t++) U[t] = R4[t];
            const unsigned* W = (const unsigned*)U;
#pragma unroll
            for (int k = 0; k < VPER; k++)
#pragma unroll
                for (int c = 0; c < 12; c++) {
                    const int s0 = 24 * k + c, s1 = 24 * k + 12 + c;
                    const unsigned u0 = W[s0 >> 1], u1 = W[s1 >> 1];
                    acc[k][c] += bf2f((unsigned short)((s0 & 1) ? (u0 >> 16) : (u0 & 0xFFFF)))
                               + bf2f((unsigned short)((s1 & 1) ? (u1 >> 16) : (u1 & 0xFFFF)));
                }
        }
    unsigned w[6 * VPER];
#pragma unroll
    for (int t = 0; t < 6 * VPER; t++) {
        const int e0 = 2 * t, e1 = 2 * t + 1;
        const unsigned short a = (unsigned short)bf16r(acc[e0 / 12][e0 % 12] * 0.125f);
        const unsigned short b = (unsigned short)bf16r(acc[e1 / 12][e1 % 12] * 0.125f);
        w[t] = (unsigned)a | ((unsigned)b << 16);
    }
    uint2* o = (uint2*)(dst + (size_t)idx * 12);
#pragma unroll
    for (int t = 0; t < 3 * VPER; t++)
        o[t] = make_uint2(w[2 * t], w[2 * t + 1]);
}

// ---------------------------------------------------------------------------
// fused (r15: r9 structure + hoisted gathers + operand-swapped MFMA):
// Block = 1 ray, 256 thr, LDS 53760 B -> 3 blocks/CU.
// ---------------------------------------------------------------------------
__global__ __launch_bounds__(256, 3) void fused_kernel(
    const float* __restrict__ ray_pts, const float* __restrict__ viewdirs,
    const float* __restrict__ be0,
    const short* __restrict__ dt0h, const short* __restrict__ dt0l,
    const short* __restrict__ dt1h, const short* __restrict__ dt1l,
    const float* __restrict__ dt_b1,
    const float* __restrict__ dt_wo, const float* __restrict__ dt_bo,
    const float* __restrict__ density,
    const short* __restrict__ g0, const short* __restrict__ p2g, const short* __restrict__ p4g,
    const short* __restrict__ fnw, const float* __restrict__ fn_b0,
    const short* __restrict__ dwf, const float* __restrict__ dec_bf,
    const short* __restrict__ dw0, const float* __restrict__ dec_b0,
    const float* __restrict__ dec_w0, const float* __restrict__ dec_w1,
    const float* __restrict__ dec_b1,
    float* __restrict__ out)
{
    // sA: emb (stride 72) -> h2 f32 (stride 132 f32) -> X (232) -> fl (136)
    // sB: h1 (stride 132) -> hf (stride 132) -> h2dec (stride 72) + sDw stage
    __shared__ __align__(16) short sA[16896];   // 33792 B
    __shared__ __align__(16) short sB[8448];    // 16896 B
    __shared__ __align__(16) float sWo[388];    // dt_wo + dt_bo
    __shared__ __align__(16) float sSm[256];    // [p*4+d]: pts_d xyz, d=3: weight
    __shared__ __align__(16) float sBe3[64];    // folded decoder-L0 bias
    __shared__ float sAiv[1];

    const int tid = threadIdx.x;
    const int r = blockIdx.x;
    const int p0g = r * 64;
    const int lane = tid & 63, wv = tid >> 6;
    const int l15 = lane & 15, q = lane >> 4;
    const int ntb = wv * 2;

    // ---- phase 0: preloads + folded decoder bias + deform embedding ----
    for (int i = tid; i < 384; i += 256) sWo[i] = dt_wo[i];
    if (tid < 3) sWo[384 + tid] = dt_bo[tid];
    if (tid < 64) {   // be3[n] = dec_b0[n] + vemb . dec_w0[128:149][n]
        const float v0 = viewdirs[r * 3], v1 = viewdirs[r * 3 + 1], v2 = viewdirs[r * 3 + 2];
        const float vv[3] = { v0, v1, v2 };
        float ve[21];
        ve[0] = v0; ve[1] = v1; ve[2] = v2;
#pragma unroll
        for (int d = 0; d < 3; d++) {
            float fq = 1.f;
#pragma unroll
            for (int f = 0; f < 3; f++) {
                ve[3 + d * 3 + f]  = __sinf(vv[d] * fq);
                ve[12 + d * 3 + f] = __cosf(vv[d] * fq);
                fq *= 2.f;
            }
        }
        float acc = dec_b0[tid];
#pragma unroll
        for (int k = 0; k < 21; k++) acc = fmaf(ve[k], dec_w0[(128 + k) * 64 + tid], acc);
        sBe3[tid] = acc;
    }
    {   // deform emb: thread (p=lane, grp=wv) -> cols wv*8..wv*8+7 (hi) / +32 (lo)
        const int p = lane;
        const int gp = p0g + p;
        const float pt[3] = { ray_pts[gp * 3], ray_pts[gp * 3 + 1], ray_pts[gp * 3 + 2] };
        float vals[8];
#pragma unroll
        for (int j = 0; j < 8; j++) {
            const int c = wv * 8 + j;
            float v;
            if (c < 3)       v = pt[c];
            else if (c < 15) { const int e = c - 3;  v = __sinf(pt[e >> 2] * (float)(1 << (e & 3))); }
            else if (c < 27) { const int e = c - 15; v = __cosf(pt[e >> 2] * (float)(1 << (e & 3))); }
            else             v = 0.f;
            vals[j] = v;
        }
        bf16x8 hi, lo;
#pragma unroll
        for (int j = 0; j < 8; j++) {
            const short h = bf16r(vals[j]);
            hi[j] = h;
            lo[j] = bf16r(vals[j] - bf2f((unsigned short)h));
        }
        *(bf16x8*)(sA + p * 72 + wv * 8) = hi;
        *(bf16x8*)(sA + p * 72 + 32 + wv * 8) = lo;
    }
    __syncthreads();

    // ---- phase 1: deform L1  K=32 (swapped: W^T as A, emb^T as B) ----
    {
        f32x4 acc[2][4];   // [wt][pt]
#pragma unroll
        for (int wt = 0; wt < 2; wt++)
#pragma unroll
            for (int pt = 0; pt < 4; pt++) acc[wt][pt] = (f32x4){0.f, 0.f, 0.f, 0.f};
        bf16x8 wh[2], wl[2];
#pragma unroll
        for (int wt = 0; wt < 2; wt++) {
            wh[wt] = *(const bf16x8*)(dt0h + ((ntb + wt) * 64 + lane) * 8);
            wl[wt] = *(const bf16x8*)(dt0l + ((ntb + wt) * 64 + lane) * 8);
        }
#pragma unroll
        for (int pt = 0; pt < 4; pt++) {
            const bf16x8 ah = *(const bf16x8*)(sA + (pt * 16 + l15) * 72 + q * 8);
            const bf16x8 al = *(const bf16x8*)(sA + (pt * 16 + l15) * 72 + 32 + q * 8);
#pragma unroll
            for (int wt = 0; wt < 2; wt++) {
                acc[wt][pt] = MFMA16(wh[wt], ah, acc[wt][pt]);
                acc[wt][pt] = MFMA16(wh[wt], al, acc[wt][pt]);
                acc[wt][pt] = MFMA16(wl[wt], ah, acc[wt][pt]);
            }
        }
#pragma unroll
        for (int wt = 0; wt < 2; wt++) {
            const int n0 = (ntb + wt) * 16 + q * 4;
            const float4 bv = *(const float4*)(be0 + n0);
#pragma unroll
            for (int pt = 0; pt < 4; pt++)
                *(uint2*)(sB + (pt * 16 + l15) * 132 + n0) = packacc(acc[wt][pt], bv, true);
        }
    }
    __syncthreads();

    // ---- phase 2: deform L2  K=128 (swapped), f32 float4 stores -> sA ----
    {
        bf16x8 wh[4][2], wl[4][2];
#pragma unroll
        for (int kt = 0; kt < 4; kt++)
#pragma unroll
            for (int wt = 0; wt < 2; wt++) {
                wh[kt][wt] = *(const bf16x8*)(dt1h + (((ntb + wt) * 4 + kt) * 64 + lane) * 8);
                wl[kt][wt] = *(const bf16x8*)(dt1l + (((ntb + wt) * 4 + kt) * 64 + lane) * 8);
            }
        f32x4 acc[2][4];
#pragma unroll
        for (int wt = 0; wt < 2; wt++)
#pragma unroll
            for (int pt = 0; pt < 4; pt++) acc[wt][pt] = (f32x4){0.f, 0.f, 0.f, 0.f};
#pragma unroll
        for (int kt = 0; kt < 4; kt++) {
            bf16x8 a[4];
#pragma unroll
            for (int pt = 0; pt < 4; pt++)
                a[pt] = *(const bf16x8*)(sB + (pt * 16 + l15) * 132 + (kt * 4 + q) * 8);
#pragma unroll
            for (int wt = 0; wt < 2; wt++) {
#pragma unroll
                for (int pt = 0; pt < 4; pt++) {
                    acc[wt][pt] = MFMA16(wh[kt][wt], a[pt], acc[wt][pt]);
                    acc[wt][pt] = MFMA16(wl[kt][wt], a[pt], acc[wt][pt]);
                }
            }
        }
        float* sF = (float*)sA;
#pragma unroll
        for (int wt = 0; wt < 2; wt++) {
            const int n0 = (ntb + wt) * 16 + q * 4;
            const float4 bv = *(const float4*)(dt_b1 + n0);
#pragma unroll
            for (int pt = 0; pt < 4; pt++) {
                float4 o;
                o.x = fmaxf(acc[wt][pt][0] + bv.x, 0.f);
                o.y = fmaxf(acc[wt][pt][1] + bv.y, 0.f);
                o.z = fmaxf(acc[wt][pt][2] + bv.z, 0.f);
                o.w = fmaxf(acc[wt][pt][3] + bv.w, 0.f);
                *(float4*)&sF[(pt * 16 + l15) * 132 + n0] = o;
            }
        }
    }
    __syncthreads();

    // ---- phase 3a: dx (192 threads: 64 pts x 3 dims) -> pts_d to sSm ----
    if (tid < 192) {
        const int p = tid & 63, d = tid >> 6;
        const float* sF = (const float*)sA;
        float a = sWo[384 + d];
        for (int k = 0; k < 128; k += 4) {
            const float4 h = *(const float4*)&sF[p * 132 + k];
            a += h.x * sWo[k * 3 + d] + h.y * sWo[(k + 1) * 3 + d]
               + h.z * sWo[(k + 2) * 3 + d] + h.w * sWo[(k + 3) * 3 + d];
        }
        sSm[p * 4 + d] = ray_pts[(p0g + p) * 3 + d] + a;
    }
    __syncthreads();

    // ---- phase 3b: wave0 = density+alpha+scan+pts-emb; waves1-3 = gathers ----
    {
        const int p = lane;
        const float pd[3] = { sSm[p * 4], sSm[p * 4 + 1], sSm[p * 4 + 2] };
        if (wv == 0) {
            int i0[3]; float fr[3];
#pragma unroll
            for (int d = 0; d < 3; d++) {
                float t = (pd[d] + 1.f) * 63.5f;
                t = fminf(fmaxf(t, 0.f), 127.f - 1e-4f);
                const int i = (int)t;
                i0[d] = i; fr[d] = t - (float)i;
            }
            // hoist all 8 density loads before any use
            float dlo[2][2], dhi[2][2];
#pragma unroll
            for (int dx = 0; dx < 2; dx++)
#pragma unroll
                for (int dy = 0; dy < 2; dy++) {
                    const float* b = &density[((i0[0] + dx) * 128 + i0[1] + dy) * 128 + i0[2]];
                    dlo[dx][dy] = b[0];
                    dhi[dx][dy] = b[1];
                }
            float dens = 0.f;
#pragma unroll
            for (int dx = 0; dx < 2; dx++)
#pragma unroll
                for (int dy = 0; dy < 2; dy++) {
                    const float wxy = (dx ? fr[0] : 1.f - fr[0]) * (dy ? fr[1] : 1.f - fr[1]);
                    dens += wxy * ((1.f - fr[2]) * dlo[dx][dy] + fr[2] * dhi[dx][dy]);
                }
            const float xs = dens + ACT_SHIFT_F;
            const float sp = fmaxf(xs, 0.f) + __logf(1.f + __expf(-fabsf(xs)));
            const float alpha = 1.f - __expf(-sp * 0.5f);
            const float lm = fmaxf(-sp * 0.5f, LOG1EM10);
            float v = lm;
#pragma unroll
            for (int d = 1; d < 64; d <<= 1) {
                const float o = __shfl_up(v, d);
                if (p >= d) v += o;
            }
            sSm[p * 4 + 3] = alpha * __expf(v - lm);
            if (p == 63) sAiv[0] = __expf(v);
            // pts_d embedding -> X cols 180..206, zero pad 207..223
            sA[p * 232 + 180] = bf16r(pd[0]);
            sA[p * 232 + 181] = bf16r(pd[1]);
            sA[p * 232 + 182] = bf16r(pd[2]);
#pragma unroll
            for (int d = 0; d < 3; d++) {
                float sv = __sinf(pd[d]), cv = __cosf(pd[d]);
#pragma unroll
                for (int f = 0; f < 4; f++) {
                    sA[p * 232 + 183 + d * 4 + f] = bf16r(sv);
                    sA[p * 232 + 195 + d * 4 + f] = bf16r(cv);
                    const float ns = 2.f * sv * cv;
                    cv = 1.f - 2.f * sv * sv;      // cos(2t) = 1 - 2 sin^2 t
                    sv = ns;                        // sin(2t) = 2 sin t cos t
                }
            }
            sA[p * 232 + 207] = 0;
            const bf16x8 zv = { 0, 0, 0, 0, 0, 0, 0, 0 };
            *(bf16x8*)(sA + p * 232 + 208) = zv;
            *(bf16x8*)(sA + p * 232 + 216) = zv;
        } else {
            const int s = wv - 1;
            const int n = (s == 0) ? 128 : ((s == 1) ? 64 : 32);
            const short* g = (s == 0) ? g0 : ((s == 1) ? p2g : p4g);
            const float dim = (float)(n - 1);
            int i0[3]; float fr[3];
#pragma unroll
            for (int d = 0; d < 3; d++) {
                float t = (pd[d] + 1.f) * 0.5f * dim;
                t = fminf(fmaxf(t, 0.f), dim - 1e-4f);
                const int i = (int)t;
                i0[d] = i; fr[d] = t - (float)i;
            }
            // issue ALL 24 corner loads first (8 corners x 3 ushort4) so the
            // fetch latencies overlap; then accumulate.
            ushort4 cr[2][2][2][3];
#pragma unroll
            for (int dx = 0; dx < 2; dx++)
#pragma unroll
                for (int dy = 0; dy < 2; dy++)
#pragma unroll
                    for (int dz = 0; dz < 2; dz++) {
                        const int vox = ((i0[0] + dx) * n + i0[1] + dy) * n + i0[2] + dz;
                        const ushort4* qp = (const ushort4*)(g + (size_t)vox * 12);
                        cr[dx][dy][dz][0] = qp[0];
                        cr[dx][dy][dz][1] = qp[1];
                        cr[dx][dy][dz][2] = qp[2];
                    }
            float feat[12];
#pragma unroll
            for (int c = 0; c < 12; c++) feat[c] = 0.f;
#pragma unroll
            for (int dx = 0; dx < 2; dx++)
#pragma unroll
                for (int dy = 0; dy < 2; dy++)
#pragma unroll
                    for (int dz = 0; dz < 2; dz++) {
                        const float wc = (dx ? fr[0] : 1.f - fr[0]) *
                                         (dy ? fr[1] : 1.f - fr[1]) *
                                         (dz ? fr[2] : 1.f - fr[2]);
                        const ushort4 a = cr[dx][dy][dz][0];
                        const ushort4 b = cr[dx][dy][dz][1];
                        const ushort4 c2 = cr[dx][dy][dz][2];
                        feat[0]  += wc * bf2f(a.x);  feat[1]  += wc * bf2f(a.y);
                        feat[2]  += wc * bf2f(a.z);  feat[3]  += wc * bf2f(a.w);
                        feat[4]  += wc * bf2f(b.x);  feat[5]  += wc * bf2f(b.y);
                        feat[6]  += wc * bf2f(b.z);  feat[7]  += wc * bf2f(b.w);
                        feat[8]  += wc * bf2f(c2.x); feat[9]  += wc * bf2f(c2.y);
                        feat[10] += wc * bf2f(c2.z); feat[11] += wc * bf2f(c2.w);
                    }
#pragma unroll
            for (int c = 0; c < 12; c++) {
                const float v = feat[c];
                const int j = s * 12 + c;
                sA[p * 232 + j] = bf16r(v);
                const float sv = __sinf(v), cv = __cosf(v);
                const unsigned s1 = (unsigned short)bf16r(sv);
                const unsigned s2 = (unsigned short)bf16r(2.f * sv * cv);
                const unsigned c1 = (unsigned short)bf16r(cv);
                const unsigned c2 = (unsigned short)bf16r(1.f - 2.f * sv * sv);
                *(unsigned*)(sA + p * 232 + 36 + 2 * j)  = s1 | (s2 << 16);
                *(unsigned*)(sA + p * 232 + 108 + 2 * j) = c1 | (c2 << 16);
            }
        }
    }
    __syncthreads();

    // ---- phase 4: featurenet  K=224 (swapped), relu -> sB (stride 132) ----
    {
        bf16x8 w[7][2];
#pragma unroll
        for (int kt = 0; kt < 7; kt++)
#pragma unroll
            for (int wt = 0; wt < 2; wt++)
                w[kt][wt] = *(const bf16x8*)(fnw + (((ntb + wt) * 7 + kt) * 64 + lane) * 8);
        f32x4 acc[2][4];
#pragma unroll
        for (int wt = 0; wt < 2; wt++)
#pragma unroll
            for (int pt = 0; pt < 4; pt++) acc[wt][pt] = (f32x4){0.f, 0.f, 0.f, 0.f};
#pragma unroll
        for (int kt = 0; kt < 7; kt++) {
            bf16x8 a[4];
#pragma unroll
            for (int pt = 0; pt < 4; pt++)
                a[pt] = *(const bf16x8*)(sA + (pt * 16 + l15) * 232 + (kt * 4 + q) * 8);
#pragma unroll
            for (int wt = 0; wt < 2; wt++) {
#pragma unroll
                for (int pt = 0; pt < 4; pt++) acc[wt][pt] = MFMA16(w[kt][wt], a[pt], acc[wt][pt]);
            }
        }
#pragma unroll
        for (int wt = 0; wt < 2; wt++) {
            const int n0 = (ntb + wt) * 16 + q * 4;
            const float4 bv = *(const float4*)(fn_b0 + n0);
#pragma unroll
            for (int pt = 0; pt < 4; pt++)
                *(uint2*)(sB + (pt * 16 + l15) * 132 + n0) = packacc(acc[wt][pt], bv, true);
        }
    }
    __syncthreads();

    // ---- phase 5: dec_wf  K=128 (swapped), no relu -> sA (stride 136) ----
    {
        bf16x8 w[4][2];
#pragma unroll
        for (int kt = 0; kt < 4; kt++)
#pragma unroll
            for (int wt = 0; wt < 2; wt++)
                w[kt][wt] = *(const bf16x8*)(dwf + (((ntb + wt) * 4 + kt) * 64 + lane) * 8);
        f32x4 acc[2][4];
#pragma unroll
        for (int wt = 0; wt < 2; wt++)
#pragma unroll
            for (int pt = 0; pt < 4; pt++) acc[wt][pt] = (f32x4){0.f, 0.f, 0.f, 0.f};
#pragma unroll
        for (int kt = 0; kt < 4; kt++) {
            bf16x8 a[4];
#pragma unroll
            for (int pt = 0; pt < 4; pt++)
                a[pt] = *(const bf16x8*)(sB + (pt * 16 + l15) * 132 + (kt * 4 + q) * 8);
#pragma unroll
            for (int wt = 0; wt < 2; wt++) {
#pragma unroll
                for (int pt = 0; pt < 4; pt++) acc[wt][pt] = MFMA16(w[kt][wt], a[pt], acc[wt][pt]);
            }
        }
#pragma unroll
        for (int wt = 0; wt < 2; wt++) {
            const int n0 = (ntb + wt) * 16 + q * 4;
            const float4 bv = *(const float4*)(dec_bf + n0);
#pragma unroll
            for (int pt = 0; pt < 4; pt++)
                *(uint2*)(sA + (pt * 16 + l15) * 136 + n0) = packacc(acc[wt][pt], bv, false);
        }
    }
    __syncthreads();

    // ---- phase 6: dec_w0  K=128 (swapped; vemb folded in sBe3), N=64;
    //      also stage dec_w1/dec_b1 into dead sB space [short 4608..] ----
    {
        float* sDw = (float*)sB + 2304;   // byte 9216, beyond h2dec (4608 shorts)
        for (int i = tid; i < 195; i += 256)
            sDw[i] = (i < 192) ? dec_w1[i] : dec_b1[i - 192];
        bf16x8 w[4];
#pragma unroll
        for (int kt = 0; kt < 4; kt++)
            w[kt] = *(const bf16x8*)(dw0 + ((wv * 4 + kt) * 64 + lane) * 8);
        f32x4 acc[4];
#pragma unroll
        for (int pt = 0; pt < 4; pt++) acc[pt] = (f32x4){0.f, 0.f, 0.f, 0.f};
#pragma unroll
        for (int kt = 0; kt < 4; kt++) {
            bf16x8 a[4];
#pragma unroll
            for (int pt = 0; pt < 4; pt++)
                a[pt] = *(const bf16x8*)(sA + (pt * 16 + l15) * 136 + (kt * 4 + q) * 8);
#pragma unroll
            for (int pt = 0; pt < 4; pt++) acc[pt] = MFMA16(w[kt], a[pt], acc[pt]);
        }
        const int n0 = wv * 16 + q * 4;
        const float4 bv = *(const float4*)(sBe3 + n0);
#pragma unroll
        for (int pt = 0; pt < 4; pt++)
            *(uint2*)(sB + (pt * 16 + l15) * 72 + n0) = packacc(acc[pt], bv, true);
    }
    __syncthreads();

    // ---- phase 7: 64->3, sigmoid, weight, wave-reduce, store ----
    if (tid < 64) {
        const int p = tid;
        const float* sDw = (const float*)sB + 2304;
        float a0 = sDw[192], a1 = sDw[193], a2 = sDw[194];
#pragma unroll
        for (int g = 0; g < 8; g++) {
            const bf16x8 h = *(const bf16x8*)(sB + p * 72 + g * 8);
#pragma unroll
            for (int j = 0; j < 8; j++) {
                const float f = bf2f((unsigned short)h[j]);
                const int k = g * 8 + j;
                a0 += f * sDw[k * 3];
                a1 += f * sDw[k * 3 + 1];
                a2 += f * sDw[k * 3 + 2];
            }
        }
        const float wgt = sSm[p * 4 + 3];
        float r0 = wgt / (1.f + __expf(-a0));
        float r1 = wgt / (1.f + __expf(-a1));
        float r2 = wgt / (1.f + __expf(-a2));
#pragma unroll
        for (int off = 32; off >= 1; off >>= 1) {
            r0 += __shfl_down(r0, off);
            r1 += __shfl_down(r1, off);
            r2 += __shfl_down(r2, off);
        }
        if (p == 0) {
            const float av = sAiv[0];
            out[r * 3]     = r0 + av;
            out[r * 3 + 1] = r1 + av;
            out[r * 3 + 2] = r2 + av;
        }
    }
}

// ---------------------------------------------------------------------------
extern "C" void kernel_launch(void* const* d_in, const int* in_sizes, int n_in,
                              void* d_out, int out_size, void* d_ws, size_t ws_size,
                              hipStream_t stream)
{
    const float* ray_pts    = (const float*)d_in[0];
    const float* viewdirs   = (const float*)d_in[1];
    const float* frame_time = (const float*)d_in[2];
    float*       feature    = (float*)d_in[3];          // clobbered only in small-ws path
    const float* density    = (const float*)d_in[4];
    const float* tn_w0 = (const float*)d_in[5];  const float* tn_b0 = (const float*)d_in[6];
    const float* tn_w1 = (const float*)d_in[7];  const float* tn_b1 = (const float*)d_in[8];
    const float* dt_w0 = (const float*)d_in[9];  const float* dt_b0 = (const float*)d_in[10];
    const float* dt_w1 = (const float*)d_in[11]; const float* dt_b1 = (const float*)d_in[12];
    const float* dt_wo = (const float*)d_in[13]; const float* dt_bo = (const float*)d_in[14];
    const float* fn_w0 = (const float*)d_in[15]; const float* fn_b0 = (const float*)d_in[16];
    const float* dec_wf = (const float*)d_in[17]; const float* dec_bf = (const float*)d_in[18];
    const float* dec_w0 = (const float*)d_in[19]; const float* dec_b0 = (const float*)d_in[20];
    const float* dec_w1 = (const float*)d_in[21]; const float* dec_b1 = (const float*)d_in[22];
    (void)in_sizes; (void)n_in; (void)out_size;

    char* ws = (char*)d_ws;
    const bool big = ws_size >= (size_t)57598464;

    short *G, *p2, *p4, *B1 = nullptr, *B2 = nullptr;
    float* be0; short *dt0h, *dt0l, *dt1h, *dt1l, *fnw, *dwf, *dw0;

    if (big) {
        G    = (short*)(ws + 0);            // 128^3*12 bf16 = 50331648 B
        p2   = (short*)(ws + 50331648);
        p4   = (short*)(ws + 56623104);
        be0  = (float*)(ws + 57409536);
        dt0h = (short*)(ws + 57410048);
        dt0l = (short*)(ws + 57418240);
        dt1h = (short*)(ws + 57426432);
        dt1l = (short*)(ws + 57459200);
        fnw  = (short*)(ws + 57491968);
        dwf  = (short*)(ws + 57549312);
        dw0  = (short*)(ws + 57582080);     // ends 57598464
    } else {
        G    = (short*)feature;             // in-place in feature buffer
        B1   = (short*)(ws + 0);            // 3*GV bf16
        B2   = (short*)(ws + 12582912);     // 3*GVH bf16
        p2   = (short*)(ws + 0);            // reuse after transpose
        p4   = (short*)(ws + 6291456);
        be0  = (float*)(ws + 18874368);
        dt0h = (short*)(ws + 18874880);
        dt0l = (short*)(ws + 18883072);
        dt1h = (short*)(ws + 18891264);
        dt1l = (short*)(ws + 18924032);
        fnw  = (short*)(ws + 18956800);
        dwf  = (short*)(ws + 19014144);
        dw0  = (short*)(ws + 19046912);     // ends 19063296
    }

    pack_timenet_kernel<<<289, 256, 0, stream>>>(
        dt_w0, dt_w1, fn_w0, dec_wf, dec_w0,
        frame_time, tn_w0, tn_b0, tn_w1, tn_b1, dt_b0,
        dt0h, dt0l, dt1h, dt1l, fnw, dwf, dw0, be0);

    if (big) {
        transpose_pool_kernel<<<512, 256, 0, stream>>>(feature, G, p2, p4);
    } else {
        compact_kernel<<<9216, 256, 0, stream>>>(feature, B1, B2);
        transpose_kernel<<<1024, 256, 0, stream>>>(feature, B1, B2, G, 0);
        transpose_kernel<<<1024, 256, 0, stream>>>(feature, B1, B2, G, 1);
        pool_kernel_t<1><<<1024, 256, 0, stream>>>(G, p2, 6);
        pool_kernel_t<1><<<128, 256, 0, stream>>>(p2, p4, 5);
    }

    fused_kernel<<<4096, 256, 0, stream>>>(ray_pts, viewdirs, be0,
                                           dt0h, dt0l, dt1h, dt1l, dt_b1,
                                           dt_wo, dt_bo, density,
                                           G, p2, p4,
                                           fnw, fn_b0, dwf, dec_bf,
                                           dw0, dec_b0, dec_w0, dec_w1, dec_b1,
                                           (float*)d_out);
}

// Round 10
// 346.532 us; speedup vs baseline: 1.1746x; 1.0411x over previous
//
#include <hip/hip_runtime.h>
#include <math.h>

// ---------------------------------------------------------------------------
// VoxelMlp forward, round 17:
//  - fused: single 33792-B LDS buffer (live-range merge of emb/h1/h2/X/hf/fl/
//    h2dec with mid-phase barriers; accs stay in registers across the
//    barrier). LDS 53760 -> 36864 => 4 blocks/CU (was 3). Unlike r10/r11 this
//    keeps phase-3a dx (no in-register shuffle dx) and r15's operand-swap +
//    r14's hoisted gathers — ONE variable: buffer merge + occupancy.
//    __launch_bounds__(256,4): VGPR cap 128, r15 used 68 -> no spill.
//  - prep unchanged (r16 merged transpose_pool, best total 360.8).
// ---------------------------------------------------------------------------

#define N_RAYS 4096
#define ACT_SHIFT_F (-4.595119850134589f)
#define LOG1EM10 (-23.025850929940457f)
#define GV 2097152            // 128^3
#define GVH 1048576           // 128^3 / 2

typedef __attribute__((ext_vector_type(8))) short bf16x8;
typedef __attribute__((ext_vector_type(4))) float f32x4;
#define MFMA16(a, b, c) __builtin_amdgcn_mfma_f32_16x16x32_bf16(a, b, c, 0, 0, 0)

__device__ __forceinline__ short bf16r(float f) {   // RNE f32 -> bf16
    unsigned int u = __float_as_uint(f);
    u += 0x7FFF + ((u >> 16) & 1);
    return (short)(u >> 16);
}
__device__ __forceinline__ float bf2f(unsigned short s) {
    return __uint_as_float(((unsigned int)s) << 16);
}
__device__ __forceinline__ uint2 pack4(float4 x) {
    const unsigned a = (unsigned short)bf16r(x.x), b = (unsigned short)bf16r(x.y);
    const unsigned c = (unsigned short)bf16r(x.z), d = (unsigned short)bf16r(x.w);
    return make_uint2(a | (b << 16), c | (d << 16));
}
// pack f32x4 accumulator (+bias, optional relu) -> 4 bf16 in uint2
__device__ __forceinline__ uint2 packacc(f32x4 a, float4 bv, bool relu) {
    float v0 = a[0] + bv.x, v1 = a[1] + bv.y, v2 = a[2] + bv.z, v3 = a[3] + bv.w;
    if (relu) {
        v0 = fmaxf(v0, 0.f); v1 = fmaxf(v1, 0.f);
        v2 = fmaxf(v2, 0.f); v3 = fmaxf(v3, 0.f);
    }
    const unsigned a0 = (unsigned short)bf16r(v0), a1 = (unsigned short)bf16r(v1);
    const unsigned a2 = (unsigned short)bf16r(v2), a3 = (unsigned short)bf16r(v3);
    return make_uint2(a0 | (a1 << 16), a2 | (a3 << 16));
}

// store 4 voxels x 12 bf16 channels (96 B) as 6 uint4
__device__ __forceinline__ void store_vox4(short* __restrict__ dst,
                                           const unsigned short us[4][12]) {
    unsigned w[24];
#pragma unroll
    for (int j = 0; j < 24; j++) {
        const int a = (2 * j) / 12, ca = (2 * j) % 12;
        const int b = (2 * j + 1) / 12, cb = (2 * j + 1) % 12;
        w[j] = (unsigned)us[a][ca] | ((unsigned)us[b][cb] << 16);
    }
    uint4* o = (uint4*)dst;
#pragma unroll
    for (int t = 0; t < 6; t++)
        o[t] = make_uint4(w[4 * t], w[4 * t + 1], w[4 * t + 2], w[4 * t + 3]);
}

// ---------------------------------------------------------------------------
// pack weights (blocks 0..287) + timenet/bias-fold (block 288).
// ---------------------------------------------------------------------------
__global__ __launch_bounds__(256) void pack_timenet_kernel(
    const float* __restrict__ dt_w0, const float* __restrict__ dt_w1,
    const float* __restrict__ fn_w0, const float* __restrict__ dec_wf,
    const float* __restrict__ dec_w0,
    const float* __restrict__ ft,
    const float* __restrict__ tw0, const float* __restrict__ tb0,
    const float* __restrict__ tw1, const float* __restrict__ tb1,
    const float* __restrict__ dt_b0,
    short* __restrict__ dt0h, short* __restrict__ dt0l,
    short* __restrict__ dt1h, short* __restrict__ dt1l,
    short* __restrict__ fnw, short* __restrict__ dwf, short* __restrict__ dw0,
    float* __restrict__ be0)
{
    const int tid = threadIdx.x;
    if (blockIdx.x == 288) {
        __shared__ float sh[128];
        __shared__ float stf[60];
        const float t = ft[0];
        float te[9];
        te[0] = t;
        float fr = 1.f;
#pragma unroll
        for (int f = 0; f < 4; f++) {
            te[1 + f] = __sinf(t * fr);
            te[5 + f] = __cosf(t * fr);
            fr *= 2.f;
        }
        if (tid < 128) {
            float acc = tb0[tid];
#pragma unroll
            for (int k = 0; k < 9; k++) acc = fmaf(te[k], tw0[k * 128 + tid], acc);
            sh[tid] = fmaxf(acc, 0.f);
        }
        __syncthreads();
        if (tid < 60) {
            float acc = tb1[tid];
            for (int k = 0; k < 128; k++) acc = fmaf(sh[k], tw1[k * 60 + tid], acc);
            stf[tid] = acc;
        }
        __syncthreads();
        if (tid < 128) {
            float acc = dt_b0[tid];
            for (int k = 0; k < 60; k++) acc = fmaf(stf[k], dt_w0[(27 + k) * 128 + tid], acc);
            be0[tid] = acc;
        }
        return;
    }
    const int id = blockIdx.x * 256 + tid;   // < 73728
    const float* W; short* dh; short* dl = nullptr; int In, KT, Out, e;
    if (id < 4096)       { W = dt_w0;  dh = dt0h; dl = dt0l; In = 27;  KT = 1; Out = 128; e = id; }
    else if (id < 20480) { W = dt_w1;  dh = dt1h; dl = dt1l; In = 128; KT = 4; Out = 128; e = id - 4096; }
    else if (id < 49152) { W = fn_w0;  dh = fnw;             In = 207; KT = 7; Out = 128; e = id - 20480; }
    else if (id < 65536) { W = dec_wf; dh = dwf;             In = 128; KT = 4; Out = 128; e = id - 49152; }
    else                 { W = dec_w0; dh = dw0;             In = 128; KT = 4; Out = 64;  e = id - 65536; }
    const int j = e & 7, lane = (e >> 3) & 63, rest = e >> 9;
    const int kt = rest % KT, nt = rest / KT;
    const int n = nt * 16 + (lane & 15);
    const int k = kt * 32 + (lane >> 4) * 8 + j;
    const float v = (k < In) ? W[k * Out + n] : 0.f;
    const short hi = bf16r(v);
    dh[e] = hi;
    if (dl) dl[e] = bf16r(v - bf2f((unsigned short)hi));
}

// ---------------------------------------------------------------------------
// BIG path: merged transpose + pool1 + pool2, NO atomics.
// ---------------------------------------------------------------------------
__global__ __launch_bounds__(256) void transpose_pool_kernel(
    const float* __restrict__ f, short* __restrict__ G,
    short* __restrict__ p2, short* __restrict__ p4)
{
    __shared__ float sP2[512 * 12];   // 24576 B
    const int tid = threadIdx.x;
    const int b = blockIdx.x;         // 512 = 16(x) * 16(y) * 2(z)
    const int bz = b & 1, by = (b >> 1) & 15, bx = b >> 5;
    const int tz = tid & 15, ty = (tid >> 4) & 3, tx = tid >> 6;
    const int gx = bx * 8 + tx * 2, gy = by * 8 + ty * 2, gz = bz * 64 + tz * 4;

    float pa[2][12];                  // 2 p2 cells (z-pair), pre-round f32 sums
#pragma unroll
    for (int k = 0; k < 2; k++)
#pragma unroll
        for (int c = 0; c < 12; c++) pa[k][c] = 0.f;

#pragma unroll
    for (int i = 0; i < 2; i++)
#pragma unroll
        for (int j = 0; j < 2; j++) {
            const int v = ((gx + i) * 128 + (gy + j)) * 128 + gz;
            unsigned short us[4][12];
#pragma unroll
            for (int c = 0; c < 12; c++) {
                const float4 w = *(const float4*)(f + (size_t)c * GV + v);
                us[0][c] = (unsigned short)bf16r(w.x);
                us[1][c] = (unsigned short)bf16r(w.y);
                us[2][c] = (unsigned short)bf16r(w.z);
                us[3][c] = (unsigned short)bf16r(w.w);
                pa[0][c] += w.x + w.y;
                pa[1][c] += w.z + w.w;
            }
            store_vox4(G + (size_t)v * 12, us);
        }

    // p2: own cells -> global (bf16) + LDS (f32, for p4)
    const int px = bx * 4 + tx, py = by * 4 + ty;
    const int pz0 = bz * 32 + tz * 2;
#pragma unroll
    for (int k = 0; k < 2; k++) {
        float vals[12];
#pragma unroll
        for (int c = 0; c < 12; c++) vals[c] = pa[k][c] * 0.125f;
        const int gp = (px * 64 + py) * 64 + pz0 + k;
        unsigned w6[6];
#pragma unroll
        for (int t = 0; t < 6; t++)
            w6[t] = (unsigned)(unsigned short)bf16r(vals[2 * t]) |
                    ((unsigned)(unsigned short)bf16r(vals[2 * t + 1]) << 16);
        uint2* o = (uint2*)(p2 + (size_t)gp * 12);
        o[0] = make_uint2(w6[0], w6[1]);
        o[1] = make_uint2(w6[2], w6[3]);
        o[2] = make_uint2(w6[4], w6[5]);
        const int lc = (tx * 4 + ty) * 32 + tz * 2 + k;
#pragma unroll
        for (int c = 0; c < 12; c++) sP2[lc * 12 + c] = vals[c];
    }
    __syncthreads();

    // p4: 2x2x16 = 64 cells, each the mean of 2x2x2 p2 cells (all in-block)
    if (tid < 64) {
        const int qz = tid & 15, qy = (tid >> 4) & 1, qx = tid >> 5;
        float acc[12];
#pragma unroll
        for (int c = 0; c < 12; c++) acc[c] = 0.f;
#pragma unroll
        for (int i = 0; i < 2; i++)
#pragma unroll
            for (int j = 0; j < 2; j++)
#pragma unroll
                for (int k = 0; k < 2; k++) {
                    const int lc = ((qx * 2 + i) * 4 + (qy * 2 + j)) * 32 + qz * 2 + k;
#pragma unroll
                    for (int c = 0; c < 12; c++) acc[c] += sP2[lc * 12 + c];
                }
        const int gp = ((bx * 2 + qx) * 32 + by * 2 + qy) * 32 + bz * 16 + qz;
        unsigned w6[6];
#pragma unroll
        for (int t = 0; t < 6; t++) {
            const float a = acc[2 * t] * 0.125f;
            const float b2 = acc[2 * t + 1] * 0.125f;
            w6[t] = (unsigned)(unsigned short)bf16r(a) |
                    ((unsigned)(unsigned short)bf16r(b2) << 16);
        }
        uint2* o = (uint2*)(p4 + (size_t)gp * 12);
        o[0] = make_uint2(w6[0], w6[1]);
        o[1] = make_uint2(w6[2], w6[3]);
        o[2] = make_uint2(w6[4], w6[5]);
    }
}

// ---------------------------------------------------------------------------
// SMALL-ws: bounce-compact (4 elems/thread) + 2-pass in-place transpose (4/thr)
// ---------------------------------------------------------------------------
__global__ __launch_bounds__(256) void compact_kernel(
    const float* __restrict__ f, short* __restrict__ B1, short* __restrict__ B2)
{
    const int id = (blockIdx.x * 256 + threadIdx.x) * 4;   // < 9437184
    if (id < 3 * GV) {
        *(uint2*)(B1 + id) = pack4(*(const float4*)(f + id));
    } else {
        const int e = id - 3 * GV;
        const int c = e >> 20;
        const int v2 = e & (GVH - 1);
        *(uint2*)(B2 + e) = pack4(*(const float4*)(f + (size_t)(3 + c) * GV + GVH + v2));
    }
}

__global__ __launch_bounds__(256) void transpose_kernel(
    const float* __restrict__ f, const short* __restrict__ B1,
    const short* __restrict__ B2, short* __restrict__ G, int pass)
{
    const int idx = (blockIdx.x * 256 + threadIdx.x) * 4;  // < GVH
    const int v = pass * GVH + idx;
    unsigned short us[4][12];
#pragma unroll
    for (int c = 0; c < 3; c++) {
        const uint2 b = *(const uint2*)(B1 + c * GV + v);
        us[0][c] = (unsigned short)(b.x & 0xFFFF); us[1][c] = (unsigned short)(b.x >> 16);
        us[2][c] = (unsigned short)(b.y & 0xFFFF); us[3][c] = (unsigned short)(b.y >> 16);
    }
    if (pass == 0) {
#pragma unroll
        for (int c = 3; c < 12; c++) {
            const float4 x = *(const float4*)(f + (size_t)c * GV + v);
            us[0][c] = (unsigned short)bf16r(x.x);
            us[1][c] = (unsigned short)bf16r(x.y);
            us[2][c] = (unsigned short)bf16r(x.z);
            us[3][c] = (unsigned short)bf16r(x.w);
        }
    } else {
#pragma unroll
        for (int c = 3; c < 6; c++) {
            const uint2 b = *(const uint2*)(B2 + (c - 3) * GVH + idx);
            us[0][c] = (unsigned short)(b.x & 0xFFFF); us[1][c] = (unsigned short)(b.x >> 16);
            us[2][c] = (unsigned short)(b.y & 0xFFFF); us[3][c] = (unsigned short)(b.y >> 16);
        }
#pragma unroll
        for (int c = 6; c < 12; c++) {
            const float4 x = *(const float4*)(f + (size_t)c * GV + v);
            us[0][c] = (unsigned short)bf16r(x.x);
            us[1][c] = (unsigned short)bf16r(x.y);
            us[2][c] = (unsigned short)bf16r(x.z);
            us[3][c] = (unsigned short)bf16r(x.w);
        }
    }
    store_vox4(G + (size_t)v * 12, us);
}

// ---------------------------------------------------------------------------
// 2x avg-pool, channel-last bf16 -> bf16 (small-ws path only)
// ---------------------------------------------------------------------------
template<int VPER>
__global__ __launch_bounds__(256) void pool_kernel_t(
    const short* __restrict__ src, short* __restrict__ dst, int so)
{
    const int nout = 1 << so, nin = nout << 1;
    const int idx = (blockIdx.x * 256 + threadIdx.x) * VPER;
    const int z0 = idx & (nout - 1), y = (idx >> so) & (nout - 1), x = idx >> (2 * so);
    float acc[VPER][12];
#pragma unroll
    for (int k = 0; k < VPER; k++)
#pragma unroll
        for (int c = 0; c < 12; c++) acc[k][c] = 0.f;
#pragma unroll
    for (int i = 0; i < 2; i++)
#pragma unroll
        for (int j = 0; j < 2; j++) {
            const size_t roff = (size_t)(((2 * x + i) * nin + (2 * y + j)) * nin + 2 * z0) * 12;
            const uint4* R4 = (const uint4*)(src + roff);
            uint4 U[3 * VPER];
#pragma unroll
            for (int t = 0; t < 3 * VPER; t++) U[t] = R4[t];
            const unsigned* W = (const unsigned*)U;
#pragma unroll
            for (int k = 0; k < VPER; k++)
#pragma unroll
                for (int c = 0; c < 12; c++) {
                    const int s0 = 24 * k + c, s1 = 24 * k + 12 + c;
                    const unsigned u0 = W[s0 >> 1], u1 = W[s1 >> 1];
                    acc[k][c] += bf2f((unsigned short)((s0 & 1) ? (u0 >> 16) : (u0 & 0xFFFF)))
                               + bf2f((unsigned short)((s1 & 1) ? (u1 >> 16) : (u1 & 0xFFFF)));
                }
        }
    unsigned w[6 * VPER];
#pragma unroll
    for (int t = 0; t < 6 * VPER; t++) {
        const int e0 = 2 * t, e1 = 2 * t + 1;
        const unsigned short a = (unsigned short)bf16r(acc[e0 / 12][e0 % 12] * 0.125f);
        const unsigned short b = (unsigned short)bf16r(acc[e1 / 12][e1 % 12] * 0.125f);
        w[t] = (unsigned)a | ((unsigned)b << 16);
    }
    uint2* o = (uint2*)(dst + (size_t)idx * 12);
#pragma unroll
    for (int t = 0; t < 3 * VPER; t++)
        o[t] = make_uint2(w[2 * t], w[2 * t + 1]);
}

// ---------------------------------------------------------------------------
// fused: single 33792-B buffer sU rotates emb(72)->h1(132)->h2f32(132f)->
// X(232)->hf(132)->fl(136)->h2dec(72), mid-phase barriers where a phase
// overwrites its input (accs live in registers across the barrier).
// LDS ~36.6KB -> 4 blocks/CU. Operand-swapped MFMA + hoisted gathers (r15).
// ---------------------------------------------------------------------------
__global__ __launch_bounds__(256, 4) void fused_kernel(
    const float* __restrict__ ray_pts, const float* __restrict__ viewdirs,
    const float* __restrict__ be0,
    const short* __restrict__ dt0h, const short* __restrict__ dt0l,
    const short* __restrict__ dt1h, const short* __restrict__ dt1l,
    const float* __restrict__ dt_b1,
    const float* __restrict__ dt_wo, const float* __restrict__ dt_bo,
    const float* __restrict__ density,
    const short* __restrict__ g0, const short* __restrict__ p2g, const short* __restrict__ p4g,
    const short* __restrict__ fnw, const float* __restrict__ fn_b0,
    const short* __restrict__ dwf, const float* __restrict__ dec_bf,
    const short* __restrict__ dw0, const float* __restrict__ dec_b0,
    const float* __restrict__ dec_w0, const float* __restrict__ dec_w1,
    const float* __restrict__ dec_b1,
    float* __restrict__ out)
{
    __shared__ __align__(16) short sU[16896];   // 33792 B, phase-rotated
    __shared__ __align__(16) float sWo[388];    // dt_wo + dt_bo
    __shared__ __align__(16) float sSm[256];    // [p*4+d]: pts_d xyz, d=3: weight
    __shared__ __align__(16) float sBe3[64];    // folded decoder-L0 bias
    __shared__ float sAiv[1];

    const int tid = threadIdx.x;
    const int r = blockIdx.x;
    const int p0g = r * 64;
    const int lane = tid & 63, wv = tid >> 6;
    const int l15 = lane & 15, q = lane >> 4;
    const int ntb = wv * 2;
    float* sDw = (float*)(sU + 8704);           // byte 17408: beyond fl & h2dec

    // ---- phase 0: preloads + folded decoder bias + deform embedding ----
    for (int i = tid; i < 384; i += 256) sWo[i] = dt_wo[i];
    if (tid < 3) sWo[384 + tid] = dt_bo[tid];
    if (tid < 64) {   // be3[n] = dec_b0[n] + vemb . dec_w0[128:149][n]
        const float v0 = viewdirs[r * 3], v1 = viewdirs[r * 3 + 1], v2 = viewdirs[r * 3 + 2];
        const float vv[3] = { v0, v1, v2 };
        float ve[21];
        ve[0] = v0; ve[1] = v1; ve[2] = v2;
#pragma unroll
        for (int d = 0; d < 3; d++) {
            float fq = 1.f;
#pragma unroll
            for (int f = 0; f < 3; f++) {
                ve[3 + d * 3 + f]  = __sinf(vv[d] * fq);
                ve[12 + d * 3 + f] = __cosf(vv[d] * fq);
                fq *= 2.f;
            }
        }
        float acc = dec_b0[tid];
#pragma unroll
        for (int k = 0; k < 21; k++) acc = fmaf(ve[k], dec_w0[(128 + k) * 64 + tid], acc);
        sBe3[tid] = acc;
    }
    {   // deform emb: thread (p=lane, grp=wv) -> cols wv*8..wv*8+7 (hi) / +32 (lo)
        const int p = lane;
        const int gp = p0g + p;
        const float pt[3] = { ray_pts[gp * 3], ray_pts[gp * 3 + 1], ray_pts[gp * 3 + 2] };
        float vals[8];
#pragma unroll
        for (int j = 0; j < 8; j++) {
            const int c = wv * 8 + j;
            float v;
            if (c < 3)       v = pt[c];
            else if (c < 15) { const int e = c - 3;  v = __sinf(pt[e >> 2] * (float)(1 << (e & 3))); }
            else if (c < 27) { const int e = c - 15; v = __cosf(pt[e >> 2] * (float)(1 << (e & 3))); }
            else             v = 0.f;
            vals[j] = v;
        }
        bf16x8 hi, lo;
#pragma unroll
        for (int j = 0; j < 8; j++) {
            const short h = bf16r(vals[j]);
            hi[j] = h;
            lo[j] = bf16r(vals[j] - bf2f((unsigned short)h));
        }
        *(bf16x8*)(sU + p * 72 + wv * 8) = hi;
        *(bf16x8*)(sU + p * 72 + 32 + wv * 8) = lo;
    }
    __syncthreads();

    // ---- phase 1: deform L1  K=32 (swapped); reads emb, writes h1 in place ----
    {
        f32x4 acc[2][4];   // [wt][pt]
#pragma unroll
        for (int wt = 0; wt < 2; wt++)
#pragma unroll
            for (int pt = 0; pt < 4; pt++) acc[wt][pt] = (f32x4){0.f, 0.f, 0.f, 0.f};
        bf16x8 wh[2], wl[2];
#pragma unroll
        for (int wt = 0; wt < 2; wt++) {
            wh[wt] = *(const bf16x8*)(dt0h + ((ntb + wt) * 64 + lane) * 8);
            wl[wt] = *(const bf16x8*)(dt0l + ((ntb + wt) * 64 + lane) * 8);
        }
#pragma unroll
        for (int pt = 0; pt < 4; pt++) {
            const bf16x8 ah = *(const bf16x8*)(sU + (pt * 16 + l15) * 72 + q * 8);
            const bf16x8 al = *(const bf16x8*)(sU + (pt * 16 + l15) * 72 + 32 + q * 8);
#pragma unroll
            for (int wt = 0; wt < 2; wt++) {
                acc[wt][pt] = MFMA16(wh[wt], ah, acc[wt][pt]);
                acc[wt][pt] = MFMA16(wh[wt], al, acc[wt][pt]);
                acc[wt][pt] = MFMA16(wl[wt], ah, acc[wt][pt]);
            }
        }
        __syncthreads();   // all emb reads complete before overwrite
#pragma unroll
        for (int wt = 0; wt < 2; wt++) {
            const int n0 = (ntb + wt) * 16 + q * 4;
            const float4 bv = *(const float4*)(be0 + n0);
#pragma unroll
            for (int pt = 0; pt < 4; pt++)
                *(uint2*)(sU + (pt * 16 + l15) * 132 + n0) = packacc(acc[wt][pt], bv, true);
        }
    }
    __syncthreads();

    // ---- phase 2: deform L2  K=128 (swapped); reads h1, writes h2 f32 in place ----
    {
        bf16x8 wh[4][2], wl[4][2];
#pragma unroll
        for (int kt = 0; kt < 4; kt++)
#pragma unroll
            for (int wt = 0; wt < 2; wt++) {
                wh[kt][wt] = *(const bf16x8*)(dt1h + (((ntb + wt) * 4 + kt) * 64 + lane) * 8);
                wl[kt][wt] = *(const bf16x8*)(dt1l + (((ntb + wt) * 4 + kt) * 64 + lane) * 8);
            }
        f32x4 acc[2][4];
#pragma unroll
        for (int wt = 0; wt < 2; wt++)
#pragma unroll
            for (int pt = 0; pt < 4; pt++) acc[wt][pt] = (f32x4){0.f, 0.f, 0.f, 0.f};
#pragma unroll
        for (int kt = 0; kt < 4; kt++) {
            bf16x8 a[4];
#pragma unroll
            for (int pt = 0; pt < 4; pt++)
                a[pt] = *(const bf16x8*)(sU + (pt * 16 + l15) * 132 + (kt * 4 + q) * 8);
#pragma unroll
            for (int wt = 0; wt < 2; wt++) {
#pragma unroll
                for (int pt = 0; pt < 4; pt++) {
                    acc[wt][pt] = MFMA16(wh[kt][wt], a[pt], acc[wt][pt]);
                    acc[wt][pt] = MFMA16(wl[kt][wt], a[pt], acc[wt][pt]);
                }
            }
        }
        __syncthreads();   // all h1 reads complete before overwrite
        float* sF = (float*)sU;
#pragma unroll
        for (int wt = 0; wt < 2; wt++) {
            const int n0 = (ntb + wt) * 16 + q * 4;
            const float4 bv = *(const float4*)(dt_b1 + n0);
#pragma unroll
            for (int pt = 0; pt < 4; pt++) {
                float4 o;
                o.x = fmaxf(acc[wt][pt][0] + bv.x, 0.f);
                o.y = fmaxf(acc[wt][pt][1] + bv.y, 0.f);
                o.z = fmaxf(acc[wt][pt][2] + bv.z, 0.f);
                o.w = fmaxf(acc[wt][pt][3] + bv.w, 0.f);
                *(float4*)&sF[(pt * 16 + l15) * 132 + n0] = o;
            }
        }
    }
    __syncthreads();

    // ---- phase 3a: dx (192 threads: 64 pts x 3 dims) -> pts_d to sSm ----
    if (tid < 192) {
        const int p = tid & 63, d = tid >> 6;
        const float* sF = (const float*)sU;
        float a = sWo[384 + d];
        for (int k = 0; k < 128; k += 4) {
            const float4 h = *(const float4*)&sF[p * 132 + k];
            a += h.x * sWo[k * 3 + d] + h.y * sWo[(k + 1) * 3 + d]
               + h.z * sWo[(k + 2) * 3 + d] + h.w * sWo[(k + 3) * 3 + d];
        }
        sSm[p * 4 + d] = ray_pts[(p0g + p) * 3 + d] + a;
    }
    __syncthreads();

    // ---- phase 3b: wave0 = density+alpha+scan+pts-emb; waves1-3 = gathers.
    //      writes X (stride 232) over dead h2 ----
    {
        const int p = lane;
        const float pd[3] = { sSm[p * 4], sSm[p * 4 + 1], sSm[p * 4 + 2] };
        if (wv == 0) {
            int i0[3]; float fr[3];
#pragma unroll
            for (int d = 0; d < 3; d++) {
                float t = (pd[d] + 1.f) * 63.5f;
                t = fminf(fmaxf(t, 0.f), 127.f - 1e-4f);
                const int i = (int)t;
                i0[d] = i; fr[d] = t - (float)i;
            }
            // hoist all 8 density loads before any use
            float dlo[2][2], dhi[2][2];
#pragma unroll
            for (int dx = 0; dx < 2; dx++)
#pragma unroll
                for (int dy = 0; dy < 2; dy++) {
                    const float* b = &density[((i0[0] + dx) * 128 + i0[1] + dy) * 128 + i0[2]];
                    dlo[dx][dy] = b[0];
                    dhi[dx][dy] = b[1];
                }
            float dens = 0.f;
#pragma unroll
            for (int dx = 0; dx < 2; dx++)
#pragma unroll
                for (int dy = 0; dy < 2; dy++) {
                    const float wxy = (dx ? fr[0] : 1.f - fr[0]) * (dy ? fr[1] : 1.f - fr[1]);
                    dens += wxy * ((1.f - fr[2]) * dlo[dx][dy] + fr[2] * dhi[dx][dy]);
                }
            const float xs = dens + ACT_SHIFT_F;
            const float sp = fmaxf(xs, 0.f) + __logf(1.f + __expf(-fabsf(xs)));
            const float alpha = 1.f - __expf(-sp * 0.5f);
            const float lm = fmaxf(-sp * 0.5f, LOG1EM10);
            float v = lm;
#pragma unroll
            for (int d = 1; d < 64; d <<= 1) {
                const float o = __shfl_up(v, d);
                if (p >= d) v += o;
            }
            sSm[p * 4 + 3] = alpha * __expf(v - lm);
            if (p == 63) sAiv[0] = __expf(v);
            // pts_d embedding -> X cols 180..206, zero pad 207..223
            sU[p * 232 + 180] = bf16r(pd[0]);
            sU[p * 232 + 181] = bf16r(pd[1]);
            sU[p * 232 + 182] = bf16r(pd[2]);
#pragma unroll
            for (int d = 0; d < 3; d++) {
                float sv = __sinf(pd[d]), cv = __cosf(pd[d]);
#pragma unroll
                for (int f = 0; f < 4; f++) {
                    sU[p * 232 + 183 + d * 4 + f] = bf16r(sv);
                    sU[p * 232 + 195 + d * 4 + f] = bf16r(cv);
                    const float ns = 2.f * sv * cv;
                    cv = 1.f - 2.f * sv * sv;      // cos(2t) = 1 - 2 sin^2 t
                    sv = ns;                        // sin(2t) = 2 sin t cos t
                }
            }
            sU[p * 232 + 207] = 0;
            const bf16x8 zv = { 0, 0, 0, 0, 0, 0, 0, 0 };
            *(bf16x8*)(sU + p * 232 + 208) = zv;
            *(bf16x8*)(sU + p * 232 + 216) = zv;
        } else {
            const int s = wv - 1;
            const int n = (s == 0) ? 128 : ((s == 1) ? 64 : 32);
            const short* g = (s == 0) ? g0 : ((s == 1) ? p2g : p4g);
            const float dim = (float)(n - 1);
            int i0[3]; float fr[3];
#pragma unroll
            for (int d = 0; d < 3; d++) {
                float t = (pd[d] + 1.f) * 0.5f * dim;
                t = fminf(fmaxf(t, 0.f), dim - 1e-4f);
                const int i = (int)t;
                i0[d] = i; fr[d] = t - (float)i;
            }
            // issue ALL 24 corner loads first (8 corners x 3 ushort4)
            ushort4 cr[2][2][2][3];
#pragma unroll
            for (int dx = 0; dx < 2; dx++)
#pragma unroll
                for (int dy = 0; dy < 2; dy++)
#pragma unroll
                    for (int dz = 0; dz < 2; dz++) {
                        const int vox = ((i0[0] + dx) * n + i0[1] + dy) * n + i0[2] + dz;
                        const ushort4* qp = (const ushort4*)(g + (size_t)vox * 12);
                        cr[dx][dy][dz][0] = qp[0];
                        cr[dx][dy][dz][1] = qp[1];
                        cr[dx][dy][dz][2] = qp[2];
                    }
            float feat[12];
#pragma unroll
            for (int c = 0; c < 12; c++) feat[c] = 0.f;
#pragma unroll
            for (int dx = 0; dx < 2; dx++)
#pragma unroll
                for (int dy = 0; dy < 2; dy++)
#pragma unroll
                    for (int dz = 0; dz < 2; dz++) {
                        const float wc = (dx ? fr[0] : 1.f - fr[0]) *
                                         (dy ? fr[1] : 1.f - fr[1]) *
                                         (dz ? fr[2] : 1.f - fr[2]);
                        const ushort4 a = cr[dx][dy][dz][0];
                        const ushort4 b = cr[dx][dy][dz][1];
                        const ushort4 c2 = cr[dx][dy][dz][2];
                        feat[0]  += wc * bf2f(a.x);  feat[1]  += wc * bf2f(a.y);
                        feat[2]  += wc * bf2f(a.z);  feat[3]  += wc * bf2f(a.w);
                        feat[4]  += wc * bf2f(b.x);  feat[5]  += wc * bf2f(b.y);
                        feat[6]  += wc * bf2f(b.z);  feat[7]  += wc * bf2f(b.w);
                        feat[8]  += wc * bf2f(c2.x); feat[9]  += wc * bf2f(c2.y);
                        feat[10] += wc * bf2f(c2.z); feat[11] += wc * bf2f(c2.w);
                    }
#pragma unroll
            for (int c = 0; c < 12; c++) {
                const float v = feat[c];
                const int j = s * 12 + c;
                sU[p * 232 + j] = bf16r(v);
                const float sv = __sinf(v), cv = __cosf(v);
                const unsigned s1 = (unsigned short)bf16r(sv);
                const unsigned s2 = (unsigned short)bf16r(2.f * sv * cv);
                const unsigned c1 = (unsigned short)bf16r(cv);
                const unsigned c2 = (unsigned short)bf16r(1.f - 2.f * sv * sv);
                *(unsigned*)(sU + p * 232 + 36 + 2 * j)  = s1 | (s2 << 16);
                *(unsigned*)(sU + p * 232 + 108 + 2 * j) = c1 | (c2 << 16);
            }
        }
    }
    __syncthreads();

    // ---- phase 4: featurenet  K=224 (swapped); reads X, writes hf in place ----
    {
        bf16x8 w[7][2];
#pragma unroll
        for (int kt = 0; kt < 7; kt++)
#pragma unroll
            for (int wt = 0; wt < 2; wt++)
                w[kt][wt] = *(const bf16x8*)(fnw + (((ntb + wt) * 7 + kt) * 64 + lane) * 8);
        f32x4 acc[2][4];
#pragma unroll
        for (int wt = 0; wt < 2; wt++)
#pragma unroll
            for (int pt = 0; pt < 4; pt++) acc[wt][pt] = (f32x4){0.f, 0.f, 0.f, 0.f};
#pragma unroll
        for (int kt = 0; kt < 7; kt++) {
            bf16x8 a[4];
#pragma unroll
            for (int pt = 0; pt < 4; pt++)
                a[pt] = *(const bf16x8*)(sU + (pt * 16 + l15) * 232 + (kt * 4 + q) * 8);
#pragma unroll
            for (int wt = 0; wt < 2; wt++) {
#pragma unroll
                for (int pt = 0; pt < 4; pt++) acc[wt][pt] = MFMA16(w[kt][wt], a[pt], acc[wt][pt]);
            }
        }
        __syncthreads();   // all X reads complete before overwrite
#pragma unroll
        for (int wt = 0; wt < 2; wt++) {
            const int n0 = (ntb + wt) * 16 + q * 4;
            const float4 bv = *(const float4*)(fn_b0 + n0);
#pragma unroll
            for (int pt = 0; pt < 4; pt++)
                *(uint2*)(sU + (pt * 16 + l15) * 132 + n0) = packacc(acc[wt][pt], bv, true);
        }
    }
    __syncthreads();

    // ---- phase 5: dec_wf  K=128 (swapped), no relu; reads hf, writes fl ----
    {
        bf16x8 w[4][2];
#pragma unroll
        for (int kt = 0; kt < 4; kt++)
#pragma unroll
            for (int wt = 0; wt < 2; wt++)
                w[kt][wt] = *(const bf16x8*)(dwf + (((ntb + wt) * 4 + kt) * 64 + lane) * 8);
        f32x4 acc[2][4];
#pragma unroll
        for (int wt = 0; wt < 2; wt++)
#pragma unroll
            for (int pt = 0; pt < 4; pt++) acc[wt][pt] = (f32x4){0.f, 0.f, 0.f, 0.f};
#pragma unroll
        for (int kt = 0; kt < 4; kt++) {
            bf16x8 a[4];
#pragma unroll
            for (int pt = 0; pt < 4; pt++)
                a[pt] = *(const bf16x8*)(sU + (pt * 16 + l15) * 132 + (kt * 4 + q) * 8);
#pragma unroll
            for (int wt = 0; wt < 2; wt++) {
#pragma unroll
                for (int pt = 0; pt < 4; pt++) acc[wt][pt] = MFMA16(w[kt][wt], a[pt], acc[wt][pt]);
            }
        }
        __syncthreads();   // all hf reads complete before overwrite
#pragma unroll
        for (int wt = 0; wt < 2; wt++) {
            const int n0 = (ntb + wt) * 16 + q * 4;
            const float4 bv = *(const float4*)(dec_bf + n0);
#pragma unroll
            for (int pt = 0; pt < 4; pt++)
                *(uint2*)(sU + (pt * 16 + l15) * 136 + n0) = packacc(acc[wt][pt], bv, false);
        }
    }
    __syncthreads();

    // ---- phase 6: dec_w0  K=128 (swapped; vemb folded in sBe3), N=64;
    //      reads fl, writes h2dec; stages dec_w1/b1 into sDw (disjoint) ----
    {
        for (int i = tid; i < 195; i += 256)
            sDw[i] = (i < 192) ? dec_w1[i] : dec_b1[i - 192];
        bf16x8 w[4];
#pragma unroll
        for (int kt = 0; kt < 4; kt++)
            w[kt] = *(const bf16x8*)(dw0 + ((wv * 4 + kt) * 64 + lane) * 8);
        f32x4 acc[4];
#pragma unroll
        for (int pt = 0; pt < 4; pt++) acc[pt] = (f32x4){0.f, 0.f, 0.f, 0.f};
#pragma unroll
        for (int kt = 0; kt < 4; kt++) {
            bf16x8 a[4];
#pragma unroll
            for (int pt = 0; pt < 4; pt++)
                a[pt] = *(const bf16x8*)(sU + (pt * 16 + l15) * 136 + (kt * 4 + q) * 8);
#pragma unroll
            for (int pt = 0; pt < 4; pt++) acc[pt] = MFMA16(w[kt], a[pt], acc[pt]);
        }
        __syncthreads();   // all fl reads complete before overwrite
        const int n0 = wv * 16 + q * 4;
        const float4 bv = *(const float4*)(sBe3 + n0);
#pragma unroll
        for (int pt = 0; pt < 4; pt++)
            *(uint2*)(sU + (pt * 16 + l15) * 72 + n0) = packacc(acc[pt], bv, true);
    }
    __syncthreads();

    // ---- phase 7: 64->3, sigmoid, weight, wave-reduce, store ----
    if (tid < 64) {
        const int p = tid;
        float a0 = sDw[192], a1 = sDw[193], a2 = sDw[194];
#pragma unroll
        for (int g = 0; g < 8; g++) {
            const bf16x8 h = *(const bf16x8*)(sU + p * 72 + g * 8);
#pragma unroll
            for (int j = 0; j < 8; j++) {
                const float f = bf2f((unsigned short)h[j]);
                const int k = g * 8 + j;
                a0 += f * sDw[k * 3];
                a1 += f * sDw[k * 3 + 1];
                a2 += f * sDw[k * 3 + 2];
            }
        }
        const float wgt = sSm[p * 4 + 3];
        float r0 = wgt / (1.f + __expf(-a0));
        float r1 = wgt / (1.f + __expf(-a1));
        float r2 = wgt / (1.f + __expf(-a2));
#pragma unroll
        for (int off = 32; off >= 1; off >>= 1) {
            r0 += __shfl_down(r0, off);
            r1 += __shfl_down(r1, off);
            r2 += __shfl_down(r2, off);
        }
        if (p == 0) {
            const float av = sAiv[0];
            out[r * 3]     = r0 + av;
            out[r * 3 + 1] = r1 + av;
            out[r * 3 + 2] = r2 + av;
        }
    }
}

// ---------------------------------------------------------------------------
extern "C" void kernel_launch(void* const* d_in, const int* in_sizes, int n_in,
                              void* d_out, int out_size, void* d_ws, size_t ws_size,
                              hipStream_t stream)
{
    const float* ray_pts    = (const float*)d_in[0];
    const float* viewdirs   = (const float*)d_in[1];
    const float* frame_time = (const float*)d_in[2];
    float*       feature    = (float*)d_in[3];          // clobbered only in small-ws path
    const float* density    = (const float*)d_in[4];
    const float* tn_w0 = (const float*)d_in[5];  const float* tn_b0 = (const float*)d_in[6];
    const float* tn_w1 = (const float*)d_in[7];  const float* tn_b1 = (const float*)d_in[8];
    const float* dt_w0 = (const float*)d_in[9];  const float* dt_b0 = (const float*)d_in[10];
    const float* dt_w1 = (const float*)d_in[11]; const float* dt_b1 = (const float*)d_in[12];
    const float* dt_wo = (const float*)d_in[13]; const float* dt_bo = (const float*)d_in[14];
    const float* fn_w0 = (const float*)d_in[15]; const float* fn_b0 = (const float*)d_in[16];
    const float* dec_wf = (const float*)d_in[17]; const float* dec_bf = (const float*)d_in[18];
    const float* dec_w0 = (const float*)d_in[19]; const float* dec_b0 = (const float*)d_in[20];
    const float* dec_w1 = (const float*)d_in[21]; const float* dec_b1 = (const float*)d_in[22];
    (void)in_sizes; (void)n_in; (void)out_size;

    char* ws = (char*)d_ws;
    const bool big = ws_size >= (size_t)57598464;

    short *G, *p2, *p4, *B1 = nullptr, *B2 = nullptr;
    float* be0; short *dt0h, *dt0l, *dt1h, *dt1l, *fnw, *dwf, *dw0;

    if (big) {
        G    = (short*)(ws + 0);            // 128^3*12 bf16 = 50331648 B
        p2   = (short*)(ws + 50331648);
        p4   = (short*)(ws + 56623104);
        be0  = (float*)(ws + 57409536);
        dt0h = (short*)(ws + 57410048);
        dt0l = (short*)(ws + 57418240);
        dt1h = (short*)(ws + 57426432);
        dt1l = (short*)(ws + 57459200);
        fnw  = (short*)(ws + 57491968);
        dwf  = (short*)(ws + 57549312);
        dw0  = (short*)(ws + 57582080);     // ends 57598464
    } else {
        G    = (short*)feature;             // in-place in feature buffer
        B1   = (short*)(ws + 0);            // 3*GV bf16
        B2   = (short*)(ws + 12582912);     // 3*GVH bf16
        p2   = (short*)(ws + 0);            // reuse after transpose
        p4   = (short*)(ws + 6291456);
        be0  = (float*)(ws + 18874368);
        dt0h = (short*)(ws + 18874880);
        dt0l = (short*)(ws + 18883072);
        dt1h = (short*)(ws + 18891264);
        dt1l = (short*)(ws + 18924032);
        fnw  = (short*)(ws + 18956800);
        dwf  = (short*)(ws + 19014144);
        dw0  = (short*)(ws + 19046912);     // ends 19063296
    }

    pack_timenet_kernel<<<289, 256, 0, stream>>>(
        dt_w0, dt_w1, fn_w0, dec_wf, dec_w0,
        frame_time, tn_w0, tn_b0, tn_w1, tn_b1, dt_b0,
        dt0h, dt0l, dt1h, dt1l, fnw, dwf, dw0, be0);

    if (big) {
        transpose_pool_kernel<<<512, 256, 0, stream>>>(feature, G, p2, p4);
    } else {
        compact_kernel<<<9216, 256, 0, stream>>>(feature, B1, B2);
        transpose_kernel<<<1024, 256, 0, stream>>>(feature, B1, B2, G, 0);
        transpose_kernel<<<1024, 256, 0, stream>>>(feature, B1, B2, G, 1);
        pool_kernel_t<1><<<1024, 256, 0, stream>>>(G, p2, 6);
        pool_kernel_t<1><<<128, 256, 0, stream>>>(p2, p4, 5);
    }

    fused_kernel<<<4096, 256, 0, stream>>>(ray_pts, viewdirs, be0,
                                           dt0h, dt0l, dt1h, dt1l, dt_b1,
                                           dt_wo, dt_bo, density,
                                           G, p2, p4,
                                           fnw, fn_b0, dwf, dec_bf,
                                           dw0, dec_b0, dec_w0, dec_w1, dec_b1,
                                           (float*)d_out);
}